// Round 1
// baseline (803.289 us; speedup 1.0000x reference)
//
#include <hip/hip_runtime.h>
#include <math.h>

#define HID 128
#define HEADS 4
#define CH 32
#define NEG_SLOPE 0.2f
#define LN_EPS 1e-5f

__device__ __forceinline__ float lrelu(float v) { return v > 0.f ? v : NEG_SLOPE * v; }

// ---------------- CSR build ----------------
__global__ __launch_bounds__(256) void count_k(const int* __restrict__ dst, int* __restrict__ cnt, int E) {
    int i = blockIdx.x * 256 + threadIdx.x;
    if (i < E) atomicAdd(&cnt[dst[i]], 1);
}

__global__ __launch_bounds__(256) void scan_k(const int* __restrict__ cnt, int* __restrict__ off,
                                              int* __restrict__ cur, int Nn) {
    __shared__ int part[256];
    int t = threadIdx.x;
    int chunk = (Nn + 255) / 256;
    int b0 = t * chunk;
    int b1 = b0 + chunk; if (b1 > Nn) b1 = Nn; if (b0 > Nn) b0 = Nn;
    int s = 0;
    for (int i = b0; i < b1; ++i) s += cnt[i];
    part[t] = s;
    __syncthreads();
    for (int ofs = 1; ofs < 256; ofs <<= 1) {
        int v = (t >= ofs) ? part[t - ofs] : 0;
        __syncthreads();
        part[t] += v;
        __syncthreads();
    }
    int run = part[t] - s;  // exclusive prefix of this chunk
    for (int i = b0; i < b1; ++i) {
        int c = cnt[i];
        off[i] = run;
        cur[i] = run;
        run += c;
    }
    if (t == 255) off[Nn] = part[255];
}

__global__ __launch_bounds__(256) void scatter_k(const int* __restrict__ src, const int* __restrict__ dst,
                                                 int* __restrict__ cur, int* __restrict__ csr, int E) {
    int i = blockIdx.x * 256 + threadIdx.x;
    if (i < E) {
        int p = atomicAdd(&cur[dst[i]], 1);
        csr[p] = src[i];
    }
}

// ---------------- GEMM: C[M,128] = A[M,K] @ W[K,128] (+bias) ----------------
template <int K>
__global__ __launch_bounds__(256) void gemm_k(const float* __restrict__ A, const float* __restrict__ W,
                                              const float* __restrict__ bias, float* __restrict__ C, int M) {
    __shared__ float Ws[32 * HID];   // 16 KB
    __shared__ float As[32 * 36];    // 4.5 KB, stride 36 keeps b128 alignment + spreads banks
    int t = threadIdx.x;
    int row0 = blockIdx.x * 32;
    int r0 = (t >> 5) << 2;          // 0..28
    int c0 = (t & 31) << 2;          // 0..124
    float acc[4][4] = {};
    for (int k0 = 0; k0 < K; k0 += 32) {
        #pragma unroll
        for (int i = 0; i < 4; ++i) {
            int fid = t + i * 256;             // 1024 float4s of the 32x128 W tile
            int kk = fid >> 5;
            int c = (fid & 31) << 2;
            *(float4*)&Ws[kk * HID + c] = *(const float4*)&W[(k0 + kk) * HID + c];
        }
        {
            int r = t >> 3;                    // 0..31
            int kk0 = (t & 7) << 2;            // 0..28
            float4 a4 = make_float4(0.f, 0.f, 0.f, 0.f);
            if (row0 + r < M) a4 = *(const float4*)&A[(size_t)(row0 + r) * K + k0 + kk0];
            As[(kk0 + 0) * 36 + r] = a4.x;
            As[(kk0 + 1) * 36 + r] = a4.y;
            As[(kk0 + 2) * 36 + r] = a4.z;
            As[(kk0 + 3) * 36 + r] = a4.w;
        }
        __syncthreads();
        #pragma unroll
        for (int kk = 0; kk < 32; ++kk) {
            float4 a4 = *(const float4*)&As[kk * 36 + r0];
            float4 w4 = *(const float4*)&Ws[kk * HID + c0];
            float av[4] = {a4.x, a4.y, a4.z, a4.w};
            float wv[4] = {w4.x, w4.y, w4.z, w4.w};
            #pragma unroll
            for (int i = 0; i < 4; ++i)
                #pragma unroll
                for (int j = 0; j < 4; ++j)
                    acc[i][j] = fmaf(av[i], wv[j], acc[i][j]);
        }
        __syncthreads();
    }
    float4 b4 = make_float4(0.f, 0.f, 0.f, 0.f);
    if (bias) b4 = *(const float4*)&bias[c0];
    #pragma unroll
    for (int i = 0; i < 4; ++i) {
        int r = row0 + r0 + i;
        if (r < M) {
            float4 o;
            o.x = acc[i][0] + b4.x;
            o.y = acc[i][1] + b4.y;
            o.z = acc[i][2] + b4.z;
            o.w = acc[i][3] + b4.w;
            *(float4*)&C[(size_t)r * HID + c0] = o;
        }
    }
}

// ---------------- attention dot products: als/ald[n,h] = xl[n,h,:]·a[h,:] ----------------
__global__ __launch_bounds__(256) void attn_dots(const float* __restrict__ xl, const float* __restrict__ a_s,
                                                 const float* __restrict__ a_d, float* __restrict__ als,
                                                 float* __restrict__ ald, int Nn) {
    int gid = blockIdx.x * 256 + threadIdx.x;
    int wid = gid >> 6, lane = threadIdx.x & 63;
    if (wid >= Nn) return;
    int h = lane >> 4;
    float2 v = *(const float2*)&xl[(size_t)wid * HID + 2 * lane];
    float2 vs = *(const float2*)&a_s[2 * lane];   // a_s is [4][32] contiguous = 128 floats
    float2 vd = *(const float2*)&a_d[2 * lane];
    float ps = v.x * vs.x + v.y * vs.y;
    float pd = v.x * vd.x + v.y * vd.y;
    #pragma unroll
    for (int m = 1; m < 16; m <<= 1) {
        ps += __shfl_xor(ps, m, 64);
        pd += __shfl_xor(pd, m, 64);
    }
    if ((lane & 15) == 0) {
        als[wid * HEADS + h] = ps;
        ald[wid * HEADS + h] = pd;
    }
}

// ---------------- GAT aggregation (H=4, C=32), one wave per dst node ----------------
__global__ __launch_bounds__(256) void gat_agg(const float* __restrict__ xl, const float* __restrict__ als,
                                               const float* __restrict__ ald, const int* __restrict__ off,
                                               const int* __restrict__ csr, const float* __restrict__ bias,
                                               float* __restrict__ out, int Nn) {
    int gid = blockIdx.x * 256 + threadIdx.x;
    int wid = gid >> 6, lane = threadIdx.x & 63;
    if (wid >= Nn) return;
    int h = lane >> 4;
    float aldn = ald[wid * HEADS + h];
    float alsn = als[wid * HEADS + h];
    float eself = lrelu(alsn + aldn);
    int b = off[wid], e = off[wid + 1];
    float m = eself;
    for (int j = b; j < e; ++j) {
        int s = csr[j];
        m = fmaxf(m, lrelu(als[s * HEADS + h] + aldn));
    }
    float ws = __expf(eself - m);
    float denom = ws;
    float2 xv = *(const float2*)&xl[(size_t)wid * HID + 2 * lane];
    float acc0 = ws * xv.x, acc1 = ws * xv.y;
    for (int j = b; j < e; ++j) {
        int s = csr[j];
        float w = __expf(lrelu(als[s * HEADS + h] + aldn) - m);
        denom += w;
        float2 sv = *(const float2*)&xl[(size_t)s * HID + 2 * lane];
        acc0 += w * sv.x;
        acc1 += w * sv.y;
    }
    float inv = 1.0f / (denom + 1e-16f);
    float2 o;
    o.x = acc0 * inv + bias[2 * lane];
    o.y = acc1 * inv + bias[2 * lane + 1];
    *(float2*)&out[(size_t)wid * HID + 2 * lane] = o;
}

// ---------------- LayerNorm + ReLU + residual (in-place residual buffer) ----------------
__global__ __launch_bounds__(256) void ln_relu_res(const float* __restrict__ gin, const float* __restrict__ g,
                                                   const float* __restrict__ be, float* __restrict__ hres, int Nn) {
    int gid = blockIdx.x * 256 + threadIdx.x;
    int wid = gid >> 6, lane = threadIdx.x & 63;
    if (wid >= Nn) return;
    float2 v = *(const float2*)&gin[(size_t)wid * HID + 2 * lane];
    float s = v.x + v.y;
    #pragma unroll
    for (int m = 1; m < 64; m <<= 1) s += __shfl_xor(s, m, 64);
    float mu = s * (1.0f / HID);
    float dx = v.x - mu, dy = v.y - mu;
    float q = dx * dx + dy * dy;
    #pragma unroll
    for (int m = 1; m < 64; m <<= 1) q += __shfl_xor(q, m, 64);
    float rs = rsqrtf(q * (1.0f / HID) + LN_EPS);
    float2 gg = *(const float2*)&g[2 * lane];
    float2 bb = *(const float2*)&be[2 * lane];
    float2 rr = *(const float2*)&hres[(size_t)wid * HID + 2 * lane];
    float o0 = fmaxf(dx * rs * gg.x + bb.x, 0.f) + rr.x;
    float o1 = fmaxf(dy * rs * gg.y + bb.y, 0.f) + rr.y;
    *(float2*)&hres[(size_t)wid * HID + 2 * lane] = make_float2(o0, o1);
}

// ---------------- output projection: xlo[n,0:2] = h[n]·Wo ; also attn scalars ----------------
__global__ __launch_bounds__(256) void out_proj(const float* __restrict__ h, const float* __restrict__ Wo,
                                                const float* __restrict__ aso, const float* __restrict__ ado,
                                                float* __restrict__ xlo, float* __restrict__ also,
                                                float* __restrict__ aldo, int Nn) {
    int gid = blockIdx.x * 256 + threadIdx.x;
    int wid = gid >> 6, lane = threadIdx.x & 63;
    if (wid >= Nn) return;
    float2 v = *(const float2*)&h[(size_t)wid * HID + 2 * lane];
    float2 w0 = *(const float2*)&Wo[(2 * lane) * 2];
    float2 w1 = *(const float2*)&Wo[(2 * lane + 1) * 2];
    float p0 = v.x * w0.x + v.y * w1.x;
    float p1 = v.x * w0.y + v.y * w1.y;
    #pragma unroll
    for (int m = 1; m < 64; m <<= 1) {
        p0 += __shfl_xor(p0, m, 64);
        p1 += __shfl_xor(p1, m, 64);
    }
    if (lane == 0) {
        xlo[wid * 2 + 0] = p0;
        xlo[wid * 2 + 1] = p1;
        also[wid] = p0 * aso[0] + p1 * aso[1];
        aldo[wid] = p0 * ado[0] + p1 * ado[1];
    }
}

// ---------------- output aggregation (H=1, C=2), lanes stride edges ----------------
__global__ __launch_bounds__(256) void out_agg(const float* __restrict__ xlo, const float* __restrict__ also,
                                               const float* __restrict__ aldo, const int* __restrict__ off,
                                               const int* __restrict__ csr, const float* __restrict__ bo,
                                               float* __restrict__ out, int Nn) {
    int gid = blockIdx.x * 256 + threadIdx.x;
    int wid = gid >> 6, lane = threadIdx.x & 63;
    if (wid >= Nn) return;
    float aldn = aldo[wid];
    float eself = lrelu(also[wid] + aldn);
    int b = off[wid], e = off[wid + 1];
    float mloc = -INFINITY;
    for (int j = b + lane; j < e; j += 64)
        mloc = fmaxf(mloc, lrelu(also[csr[j]] + aldn));
    #pragma unroll
    for (int m = 1; m < 64; m <<= 1) mloc = fmaxf(mloc, __shfl_xor(mloc, m, 64));
    float mm = fmaxf(mloc, eself);
    float dl = 0.f, a0 = 0.f, a1 = 0.f;
    for (int j = b + lane; j < e; j += 64) {
        int s = csr[j];
        float w = __expf(lrelu(also[s] + aldn) - mm);
        dl += w;
        a0 += w * xlo[s * 2 + 0];
        a1 += w * xlo[s * 2 + 1];
    }
    #pragma unroll
    for (int m = 1; m < 64; m <<= 1) {
        dl += __shfl_xor(dl, m, 64);
        a0 += __shfl_xor(a0, m, 64);
        a1 += __shfl_xor(a1, m, 64);
    }
    if (lane == 0) {
        float wsf = __expf(eself - mm);
        dl += wsf;
        a0 += wsf * xlo[wid * 2 + 0];
        a1 += wsf * xlo[wid * 2 + 1];
        float inv = 1.f / (dl + 1e-16f);
        out[wid * 2 + 0] = a0 * inv + bo[0];
        out[wid * 2 + 1] = a1 * inv + bo[1];
    }
}

extern "C" void kernel_launch(void* const* d_in, const int* in_sizes, int n_in,
                              void* d_out, int out_size, void* d_ws, size_t ws_size,
                              hipStream_t stream) {
    const float* x   = (const float*)d_in[0];
    const int*   ei  = (const int*)d_in[1];
    const float* W1  = (const float*)d_in[2];
    const float* as1 = (const float*)d_in[3];
    const float* ad1 = (const float*)d_in[4];
    const float* b1  = (const float*)d_in[5];
    const float* g1  = (const float*)d_in[6];
    const float* be1 = (const float*)d_in[7];
    const float* rw  = (const float*)d_in[8];
    const float* rb  = (const float*)d_in[9];
    const float* W2  = (const float*)d_in[10];
    const float* as2 = (const float*)d_in[11];
    const float* ad2 = (const float*)d_in[12];
    const float* b2  = (const float*)d_in[13];
    const float* g2  = (const float*)d_in[14];
    const float* be2 = (const float*)d_in[15];
    const float* W3  = (const float*)d_in[16];
    const float* as3 = (const float*)d_in[17];
    const float* ad3 = (const float*)d_in[18];
    const float* b3  = (const float*)d_in[19];
    const float* g3  = (const float*)d_in[20];
    const float* be3 = (const float*)d_in[21];
    const float* Wo  = (const float*)d_in[22];
    const float* aso = (const float*)d_in[23];
    const float* ado = (const float*)d_in[24];
    const float* bo  = (const float*)d_in[25];

    int N = in_sizes[0] / 64;   // 50000
    int E = in_sizes[1] / 2;    // 800000
    const int* srcE = ei;
    const int* dstE = ei + E;

    char* w = (char*)d_ws;
    auto alloc = [&](size_t b) { char* p = w; w += (b + 255) & ~(size_t)255; return p; };
    int* cnt   = (int*)alloc((size_t)N * 4);
    int* off   = (int*)alloc((size_t)(N + 1) * 4);
    int* cur   = (int*)alloc((size_t)N * 4);
    int* csr   = (int*)alloc((size_t)E * 4);
    float* hbuf = (float*)alloc((size_t)N * HID * 4);   // res / h
    float* xlb  = (float*)alloc((size_t)N * HID * 4);   // xl
    float* gb   = (float*)alloc((size_t)N * HID * 4);   // gat out
    float* als  = (float*)alloc((size_t)N * HEADS * 4);
    float* ald  = (float*)alloc((size_t)N * HEADS * 4);
    float* xlo  = (float*)alloc((size_t)N * 2 * 4);
    float* alsoB = (float*)alloc((size_t)N * 4);
    float* aldoB = (float*)alloc((size_t)N * 4);

    hipMemsetAsync(cnt, 0, (size_t)N * 4, stream);
    int gE = (E + 255) / 256;
    count_k<<<gE, 256, 0, stream>>>(dstE, cnt, E);
    scan_k<<<1, 256, 0, stream>>>(cnt, off, cur, N);
    scatter_k<<<gE, 256, 0, stream>>>(srcE, dstE, cur, csr, E);

    int gM = (N + 31) / 32;
    int gW = (N + 3) / 4;

    // residual projection: hbuf = x @ rw + rb
    gemm_k<64><<<gM, 256, 0, stream>>>(x, rw, rb, hbuf, N);

    // ---- layer 1 ----
    gemm_k<64><<<gM, 256, 0, stream>>>(x, W1, nullptr, xlb, N);
    attn_dots<<<gW, 256, 0, stream>>>(xlb, as1, ad1, als, ald, N);
    gat_agg<<<gW, 256, 0, stream>>>(xlb, als, ald, off, csr, b1, gb, N);
    ln_relu_res<<<gW, 256, 0, stream>>>(gb, g1, be1, hbuf, N);

    // ---- layer 2 ----
    gemm_k<128><<<gM, 256, 0, stream>>>(hbuf, W2, nullptr, xlb, N);
    attn_dots<<<gW, 256, 0, stream>>>(xlb, as2, ad2, als, ald, N);
    gat_agg<<<gW, 256, 0, stream>>>(xlb, als, ald, off, csr, b2, gb, N);
    ln_relu_res<<<gW, 256, 0, stream>>>(gb, g2, be2, hbuf, N);

    // ---- layer 3 ----
    gemm_k<128><<<gM, 256, 0, stream>>>(hbuf, W3, nullptr, xlb, N);
    attn_dots<<<gW, 256, 0, stream>>>(xlb, as3, ad3, als, ald, N);
    gat_agg<<<gW, 256, 0, stream>>>(xlb, als, ald, off, csr, b3, gb, N);
    ln_relu_res<<<gW, 256, 0, stream>>>(gb, g3, be3, hbuf, N);

    // ---- output layer ----
    out_proj<<<gW, 256, 0, stream>>>(hbuf, Wo, aso, ado, xlo, alsoB, aldoB, N);
    out_agg<<<gW, 256, 0, stream>>>(xlo, alsoB, aldoB, off, csr, bo, (float*)d_out, N);
}

// Round 2
// 684.394 us; speedup vs baseline: 1.1737x; 1.1737x over previous
//
#include <hip/hip_runtime.h>
#include <math.h>

#define HID 128
#define HEADS 4
#define NEG_SLOPE 0.2f
#define LN_EPS 1e-5f

__device__ __forceinline__ float lrelu(float v) { return v > 0.f ? v : NEG_SLOPE * v; }

// ---------------- CSR build ----------------
__global__ __launch_bounds__(256) void count_k(const int* __restrict__ dst, int* __restrict__ cnt, int E) {
    int i = blockIdx.x * 256 + threadIdx.x;
    if (i < E) atomicAdd(&cnt[dst[i]], 1);
}

__global__ __launch_bounds__(256) void scan_k(const int* __restrict__ cnt, int* __restrict__ off,
                                              int* __restrict__ cur, int Nn) {
    __shared__ int part[256];
    int t = threadIdx.x;
    int chunk = (Nn + 255) / 256;
    int b0 = t * chunk;
    int b1 = b0 + chunk; if (b1 > Nn) b1 = Nn; if (b0 > Nn) b0 = Nn;
    int s = 0;
    for (int i = b0; i < b1; ++i) s += cnt[i];
    part[t] = s;
    __syncthreads();
    for (int ofs = 1; ofs < 256; ofs <<= 1) {
        int v = (t >= ofs) ? part[t - ofs] : 0;
        __syncthreads();
        part[t] += v;
        __syncthreads();
    }
    int run = part[t] - s;
    for (int i = b0; i < b1; ++i) {
        int c = cnt[i];
        off[i] = run;
        cur[i] = run;
        run += c;
    }
    if (t == 255) off[Nn] = part[255];
}

__global__ __launch_bounds__(256) void scatter_k(const int* __restrict__ src, const int* __restrict__ dst,
                                                 int* __restrict__ cur, int* __restrict__ csr, int E) {
    int i = blockIdx.x * 256 + threadIdx.x;
    if (i < E) {
        int p = atomicAdd(&cur[dst[i]], 1);
        csr[p] = src[i];
    }
}

// ---------------- GEMM: C[M,128] = A[M,K] @ W[K,128] (+bias) ----------------
template <int K>
__global__ __launch_bounds__(256) void gemm_k(const float* __restrict__ A, const float* __restrict__ W,
                                              const float* __restrict__ bias, float* __restrict__ C, int M) {
    __shared__ float Ws[32 * HID];
    __shared__ float As[32 * 36];
    int t = threadIdx.x;
    int row0 = blockIdx.x * 32;
    int r0 = (t >> 5) << 2;
    int c0 = (t & 31) << 2;
    float acc[4][4] = {};
    for (int k0 = 0; k0 < K; k0 += 32) {
        #pragma unroll
        for (int i = 0; i < 4; ++i) {
            int fid = t + i * 256;
            int kk = fid >> 5;
            int c = (fid & 31) << 2;
            *(float4*)&Ws[kk * HID + c] = *(const float4*)&W[(k0 + kk) * HID + c];
        }
        {
            int r = t >> 3;
            int kk0 = (t & 7) << 2;
            float4 a4 = make_float4(0.f, 0.f, 0.f, 0.f);
            if (row0 + r < M) a4 = *(const float4*)&A[(size_t)(row0 + r) * K + k0 + kk0];
            As[(kk0 + 0) * 36 + r] = a4.x;
            As[(kk0 + 1) * 36 + r] = a4.y;
            As[(kk0 + 2) * 36 + r] = a4.z;
            As[(kk0 + 3) * 36 + r] = a4.w;
        }
        __syncthreads();
        #pragma unroll
        for (int kk = 0; kk < 32; ++kk) {
            float4 a4 = *(const float4*)&As[kk * 36 + r0];
            float4 w4 = *(const float4*)&Ws[kk * HID + c0];
            float av[4] = {a4.x, a4.y, a4.z, a4.w};
            float wv[4] = {w4.x, w4.y, w4.z, w4.w};
            #pragma unroll
            for (int i = 0; i < 4; ++i)
                #pragma unroll
                for (int j = 0; j < 4; ++j)
                    acc[i][j] = fmaf(av[i], wv[j], acc[i][j]);
        }
        __syncthreads();
    }
    float4 b4 = make_float4(0.f, 0.f, 0.f, 0.f);
    if (bias) b4 = *(const float4*)&bias[c0];
    #pragma unroll
    for (int i = 0; i < 4; ++i) {
        int r = row0 + r0 + i;
        if (r < M) {
            float4 o;
            o.x = acc[i][0] + b4.x;
            o.y = acc[i][1] + b4.y;
            o.z = acc[i][2] + b4.z;
            o.w = acc[i][3] + b4.w;
            *(float4*)&C[(size_t)r * HID + c0] = o;
        }
    }
}

// ---------------- attention dot products ----------------
__global__ __launch_bounds__(256) void attn_dots(const float* __restrict__ xl, const float* __restrict__ a_s,
                                                 const float* __restrict__ a_d, float* __restrict__ als,
                                                 float* __restrict__ ald, int Nn) {
    int gid = blockIdx.x * 256 + threadIdx.x;
    int wid = gid >> 6, lane = threadIdx.x & 63;
    if (wid >= Nn) return;
    int h = lane >> 4;
    float2 v = *(const float2*)&xl[(size_t)wid * HID + 2 * lane];
    float2 vs = *(const float2*)&a_s[2 * lane];
    float2 vd = *(const float2*)&a_d[2 * lane];
    float ps = v.x * vs.x + v.y * vs.y;
    float pd = v.x * vd.x + v.y * vd.y;
    #pragma unroll
    for (int m = 1; m < 16; m <<= 1) {
        ps += __shfl_xor(ps, m, 64);
        pd += __shfl_xor(pd, m, 64);
    }
    if ((lane & 15) == 0) {
        als[wid * HEADS + h] = ps;
        ald[wid * HEADS + h] = pd;
    }
}

// ---------------- softmax weights: per-edge w, per-node inv + self ----------------
__global__ __launch_bounds__(256) void attn_alpha(const float* __restrict__ als, const float* __restrict__ ald,
                                                  const int* __restrict__ off, const int* __restrict__ csr,
                                                  float* __restrict__ alphaw, float* __restrict__ nself,
                                                  float* __restrict__ ninv, int Nn) {
    int gid = blockIdx.x * 256 + threadIdx.x;
    int wid = gid >> 6, lane = threadIdx.x & 63;
    if (wid >= Nn) return;
    float4 aldn = *(const float4*)&ald[wid * 4];
    float4 alsn = *(const float4*)&als[wid * 4];
    float e0 = lrelu(alsn.x + aldn.x);
    float e1 = lrelu(alsn.y + aldn.y);
    float e2 = lrelu(alsn.z + aldn.z);
    float e3 = lrelu(alsn.w + aldn.w);
    float m0 = e0, m1 = e1, m2 = e2, m3 = e3;
    int b = off[wid], e = off[wid + 1];
    for (int c = b; c < e; c += 64) {
        int j = c + lane;
        bool v = j < e;
        int s = v ? csr[j] : 0;
        float4 a4 = *(const float4*)&als[(size_t)s * 4];
        float t0 = v ? lrelu(a4.x + aldn.x) : -INFINITY;
        float t1 = v ? lrelu(a4.y + aldn.y) : -INFINITY;
        float t2 = v ? lrelu(a4.z + aldn.z) : -INFINITY;
        float t3 = v ? lrelu(a4.w + aldn.w) : -INFINITY;
        m0 = fmaxf(m0, t0); m1 = fmaxf(m1, t1);
        m2 = fmaxf(m2, t2); m3 = fmaxf(m3, t3);
    }
    #pragma unroll
    for (int d = 1; d < 64; d <<= 1) {
        m0 = fmaxf(m0, __shfl_xor(m0, d, 64));
        m1 = fmaxf(m1, __shfl_xor(m1, d, 64));
        m2 = fmaxf(m2, __shfl_xor(m2, d, 64));
        m3 = fmaxf(m3, __shfl_xor(m3, d, 64));
    }
    float d0 = 0.f, d1 = 0.f, d2 = 0.f, d3 = 0.f;
    for (int c = b; c < e; c += 64) {
        int j = c + lane;
        bool v = j < e;
        int s = v ? csr[j] : 0;
        float4 a4 = *(const float4*)&als[(size_t)s * 4];
        float w0 = v ? __expf(lrelu(a4.x + aldn.x) - m0) : 0.f;
        float w1 = v ? __expf(lrelu(a4.y + aldn.y) - m1) : 0.f;
        float w2 = v ? __expf(lrelu(a4.z + aldn.z) - m2) : 0.f;
        float w3 = v ? __expf(lrelu(a4.w + aldn.w) - m3) : 0.f;
        if (v) *(float4*)&alphaw[(size_t)j * 4] = make_float4(w0, w1, w2, w3);
        d0 += w0; d1 += w1; d2 += w2; d3 += w3;
    }
    #pragma unroll
    for (int d = 1; d < 64; d <<= 1) {
        d0 += __shfl_xor(d0, d, 64);
        d1 += __shfl_xor(d1, d, 64);
        d2 += __shfl_xor(d2, d, 64);
        d3 += __shfl_xor(d3, d, 64);
    }
    if (lane == 0) {
        float ws0 = __expf(e0 - m0), ws1 = __expf(e1 - m1);
        float ws2 = __expf(e2 - m2), ws3 = __expf(e3 - m3);
        float i0 = 1.f / (d0 + ws0 + 1e-16f);
        float i1 = 1.f / (d1 + ws1 + 1e-16f);
        float i2 = 1.f / (d2 + ws2 + 1e-16f);
        float i3 = 1.f / (d3 + ws3 + 1e-16f);
        *(float4*)&nself[wid * 4] = make_float4(ws0 * i0, ws1 * i1, ws2 * i2, ws3 * i3);
        *(float4*)&ninv[wid * 4] = make_float4(i0, i1, i2, i3);
    }
}

// ---------------- gather: out[n] = inv * sum_j w_j * xl[s_j] + self + bias ----------------
__global__ __launch_bounds__(256) void gat_gather(const float* __restrict__ xl, const float* __restrict__ alphaw,
                                                  const float* __restrict__ nself, const float* __restrict__ ninv,
                                                  const int* __restrict__ off, const int* __restrict__ csr,
                                                  const float* __restrict__ bias, float* __restrict__ out, int Nn) {
    int gid = blockIdx.x * 256 + threadIdx.x;
    int wid = gid >> 6, lane = threadIdx.x & 63;
    if (wid >= Nn) return;
    int half = lane >> 5;      // which edge of the in-flight pair
    int cl = lane & 31;        // float4 channel group
    int h = cl >> 3;           // head of this channel group
    int b = off[wid], e = off[wid + 1];
    float4 acc = make_float4(0.f, 0.f, 0.f, 0.f);
    for (int c = b + half; c < e; c += 2) {
        int s = csr[c];
        float w = alphaw[(size_t)c * 4 + h];
        float4 v = *(const float4*)&xl[(size_t)s * HID + cl * 4];
        acc.x = fmaf(w, v.x, acc.x);
        acc.y = fmaf(w, v.y, acc.y);
        acc.z = fmaf(w, v.z, acc.z);
        acc.w = fmaf(w, v.w, acc.w);
    }
    acc.x += __shfl_xor(acc.x, 32, 64);
    acc.y += __shfl_xor(acc.y, 32, 64);
    acc.z += __shfl_xor(acc.z, 32, 64);
    acc.w += __shfl_xor(acc.w, 32, 64);
    if (half == 0) {
        float inv = ninv[wid * 4 + h];
        float sa = nself[wid * 4 + h];
        float4 xv = *(const float4*)&xl[(size_t)wid * HID + cl * 4];
        float4 bi = *(const float4*)&bias[cl * 4];
        float4 o;
        o.x = fmaf(acc.x, inv, fmaf(sa, xv.x, bi.x));
        o.y = fmaf(acc.y, inv, fmaf(sa, xv.y, bi.y));
        o.z = fmaf(acc.z, inv, fmaf(sa, xv.z, bi.z));
        o.w = fmaf(acc.w, inv, fmaf(sa, xv.w, bi.w));
        *(float4*)&out[(size_t)wid * HID + cl * 4] = o;
    }
}

// ---------------- LayerNorm + ReLU + residual ----------------
__global__ __launch_bounds__(256) void ln_relu_res(const float* __restrict__ gin, const float* __restrict__ g,
                                                   const float* __restrict__ be, float* __restrict__ hres, int Nn) {
    int gid = blockIdx.x * 256 + threadIdx.x;
    int wid = gid >> 6, lane = threadIdx.x & 63;
    if (wid >= Nn) return;
    float2 v = *(const float2*)&gin[(size_t)wid * HID + 2 * lane];
    float s = v.x + v.y;
    #pragma unroll
    for (int m = 1; m < 64; m <<= 1) s += __shfl_xor(s, m, 64);
    float mu = s * (1.0f / HID);
    float dx = v.x - mu, dy = v.y - mu;
    float q = dx * dx + dy * dy;
    #pragma unroll
    for (int m = 1; m < 64; m <<= 1) q += __shfl_xor(q, m, 64);
    float rs = rsqrtf(q * (1.0f / HID) + LN_EPS);
    float2 gg = *(const float2*)&g[2 * lane];
    float2 bb = *(const float2*)&be[2 * lane];
    float2 rr = *(const float2*)&hres[(size_t)wid * HID + 2 * lane];
    float o0 = fmaxf(dx * rs * gg.x + bb.x, 0.f) + rr.x;
    float o1 = fmaxf(dy * rs * gg.y + bb.y, 0.f) + rr.y;
    *(float2*)&hres[(size_t)wid * HID + 2 * lane] = make_float2(o0, o1);
}

// ---------------- output projection ----------------
__global__ __launch_bounds__(256) void out_proj(const float* __restrict__ h, const float* __restrict__ Wo,
                                                const float* __restrict__ aso, const float* __restrict__ ado,
                                                float* __restrict__ xlo, float* __restrict__ also,
                                                float* __restrict__ aldo, int Nn) {
    int gid = blockIdx.x * 256 + threadIdx.x;
    int wid = gid >> 6, lane = threadIdx.x & 63;
    if (wid >= Nn) return;
    float2 v = *(const float2*)&h[(size_t)wid * HID + 2 * lane];
    float2 w0 = *(const float2*)&Wo[(2 * lane) * 2];
    float2 w1 = *(const float2*)&Wo[(2 * lane + 1) * 2];
    float p0 = v.x * w0.x + v.y * w1.x;
    float p1 = v.x * w0.y + v.y * w1.y;
    #pragma unroll
    for (int m = 1; m < 64; m <<= 1) {
        p0 += __shfl_xor(p0, m, 64);
        p1 += __shfl_xor(p1, m, 64);
    }
    if (lane == 0) {
        xlo[wid * 2 + 0] = p0;
        xlo[wid * 2 + 1] = p1;
        also[wid] = p0 * aso[0] + p1 * aso[1];
        aldo[wid] = p0 * ado[0] + p1 * ado[1];
    }
}

// ---------------- output aggregation ----------------
__global__ __launch_bounds__(256) void out_agg(const float* __restrict__ xlo, const float* __restrict__ also,
                                               const float* __restrict__ aldo, const int* __restrict__ off,
                                               const int* __restrict__ csr, const float* __restrict__ bo,
                                               float* __restrict__ out, int Nn) {
    int gid = blockIdx.x * 256 + threadIdx.x;
    int wid = gid >> 6, lane = threadIdx.x & 63;
    if (wid >= Nn) return;
    float aldn = aldo[wid];
    float eself = lrelu(also[wid] + aldn);
    int b = off[wid], e = off[wid + 1];
    float mloc = -INFINITY;
    for (int j = b + lane; j < e; j += 64)
        mloc = fmaxf(mloc, lrelu(also[csr[j]] + aldn));
    #pragma unroll
    for (int m = 1; m < 64; m <<= 1) mloc = fmaxf(mloc, __shfl_xor(mloc, m, 64));
    float mm = fmaxf(mloc, eself);
    float dl = 0.f, a0 = 0.f, a1 = 0.f;
    for (int j = b + lane; j < e; j += 64) {
        int s = csr[j];
        float w = __expf(lrelu(also[s] + aldn) - mm);
        dl += w;
        a0 += w * xlo[s * 2 + 0];
        a1 += w * xlo[s * 2 + 1];
    }
    #pragma unroll
    for (int m = 1; m < 64; m <<= 1) {
        dl += __shfl_xor(dl, m, 64);
        a0 += __shfl_xor(a0, m, 64);
        a1 += __shfl_xor(a1, m, 64);
    }
    if (lane == 0) {
        float wsf = __expf(eself - mm);
        dl += wsf;
        a0 += wsf * xlo[wid * 2 + 0];
        a1 += wsf * xlo[wid * 2 + 1];
        float inv = 1.f / (dl + 1e-16f);
        out[wid * 2 + 0] = a0 * inv + bo[0];
        out[wid * 2 + 1] = a1 * inv + bo[1];
    }
}

extern "C" void kernel_launch(void* const* d_in, const int* in_sizes, int n_in,
                              void* d_out, int out_size, void* d_ws, size_t ws_size,
                              hipStream_t stream) {
    const float* x   = (const float*)d_in[0];
    const int*   ei  = (const int*)d_in[1];
    const float* W1  = (const float*)d_in[2];
    const float* as1 = (const float*)d_in[3];
    const float* ad1 = (const float*)d_in[4];
    const float* b1  = (const float*)d_in[5];
    const float* g1  = (const float*)d_in[6];
    const float* be1 = (const float*)d_in[7];
    const float* rw  = (const float*)d_in[8];
    const float* rb  = (const float*)d_in[9];
    const float* W2  = (const float*)d_in[10];
    const float* as2 = (const float*)d_in[11];
    const float* ad2 = (const float*)d_in[12];
    const float* b2  = (const float*)d_in[13];
    const float* g2  = (const float*)d_in[14];
    const float* be2 = (const float*)d_in[15];
    const float* W3  = (const float*)d_in[16];
    const float* as3 = (const float*)d_in[17];
    const float* ad3 = (const float*)d_in[18];
    const float* b3  = (const float*)d_in[19];
    const float* g3  = (const float*)d_in[20];
    const float* be3 = (const float*)d_in[21];
    const float* Wo  = (const float*)d_in[22];
    const float* aso = (const float*)d_in[23];
    const float* ado = (const float*)d_in[24];
    const float* bo  = (const float*)d_in[25];

    int N = in_sizes[0] / 64;   // 50000
    int E = in_sizes[1] / 2;    // 800000
    const int* srcE = ei;
    const int* dstE = ei + E;

    char* w = (char*)d_ws;
    auto alloc = [&](size_t b) { char* p = w; w += (b + 255) & ~(size_t)255; return p; };
    int* cnt    = (int*)alloc((size_t)N * 4);
    int* off    = (int*)alloc((size_t)(N + 1) * 4);
    int* cur    = (int*)alloc((size_t)N * 4);
    int* csr    = (int*)alloc((size_t)E * 4);
    float* hbuf = (float*)alloc((size_t)N * HID * 4);
    float* xlb  = (float*)alloc((size_t)N * HID * 4);
    float* gb   = (float*)alloc((size_t)N * HID * 4);
    float* als  = (float*)alloc((size_t)N * HEADS * 4);
    float* ald  = (float*)alloc((size_t)N * HEADS * 4);
    float* alphaw = (float*)alloc((size_t)E * HEADS * 4);
    float* nself  = (float*)alloc((size_t)N * HEADS * 4);
    float* ninv   = (float*)alloc((size_t)N * HEADS * 4);
    float* xlo  = (float*)alloc((size_t)N * 2 * 4);
    float* alsoB = (float*)alloc((size_t)N * 4);
    float* aldoB = (float*)alloc((size_t)N * 4);

    hipMemsetAsync(cnt, 0, (size_t)N * 4, stream);
    int gE = (E + 255) / 256;
    count_k<<<gE, 256, 0, stream>>>(dstE, cnt, E);
    scan_k<<<1, 256, 0, stream>>>(cnt, off, cur, N);
    scatter_k<<<gE, 256, 0, stream>>>(srcE, dstE, cur, csr, E);

    int gM = (N + 31) / 32;
    int gW = (N + 3) / 4;

    gemm_k<64><<<gM, 256, 0, stream>>>(x, rw, rb, hbuf, N);

    // ---- layer 1 ----
    gemm_k<64><<<gM, 256, 0, stream>>>(x, W1, nullptr, xlb, N);
    attn_dots<<<gW, 256, 0, stream>>>(xlb, as1, ad1, als, ald, N);
    attn_alpha<<<gW, 256, 0, stream>>>(als, ald, off, csr, alphaw, nself, ninv, N);
    gat_gather<<<gW, 256, 0, stream>>>(xlb, alphaw, nself, ninv, off, csr, b1, gb, N);
    ln_relu_res<<<gW, 256, 0, stream>>>(gb, g1, be1, hbuf, N);

    // ---- layer 2 ----
    gemm_k<128><<<gM, 256, 0, stream>>>(hbuf, W2, nullptr, xlb, N);
    attn_dots<<<gW, 256, 0, stream>>>(xlb, as2, ad2, als, ald, N);
    attn_alpha<<<gW, 256, 0, stream>>>(als, ald, off, csr, alphaw, nself, ninv, N);
    gat_gather<<<gW, 256, 0, stream>>>(xlb, alphaw, nself, ninv, off, csr, b2, gb, N);
    ln_relu_res<<<gW, 256, 0, stream>>>(gb, g2, be2, hbuf, N);

    // ---- layer 3 ----
    gemm_k<128><<<gM, 256, 0, stream>>>(hbuf, W3, nullptr, xlb, N);
    attn_dots<<<gW, 256, 0, stream>>>(xlb, as3, ad3, als, ald, N);
    attn_alpha<<<gW, 256, 0, stream>>>(als, ald, off, csr, alphaw, nself, ninv, N);
    gat_gather<<<gW, 256, 0, stream>>>(xlb, alphaw, nself, ninv, off, csr, b3, gb, N);
    ln_relu_res<<<gW, 256, 0, stream>>>(gb, g3, be3, hbuf, N);

    // ---- output layer ----
    out_proj<<<gW, 256, 0, stream>>>(hbuf, Wo, aso, ado, xlo, alsoB, aldoB, N);
    out_agg<<<gW, 256, 0, stream>>>(xlo, alsoB, aldoB, off, csr, bo, (float*)d_out, N);
}

// Round 3
// 562.038 us; speedup vs baseline: 1.4292x; 1.2177x over previous
//
#include <hip/hip_runtime.h>
#include <math.h>

#define HID 128
#define HEADS 4
#define NEG_SLOPE 0.2f
#define LN_EPS 1e-5f

__device__ __forceinline__ float lrelu(float v) { return v > 0.f ? v : NEG_SLOPE * v; }

// ---------------- CSR build ----------------
__global__ __launch_bounds__(256) void count_k(const int* __restrict__ dst, int* __restrict__ cnt, int E) {
    int i = blockIdx.x * 256 + threadIdx.x;
    if (i < E) atomicAdd(&cnt[dst[i]], 1);
}

// pass 1: per-block (1024 elems) local exclusive scan + block total
__global__ __launch_bounds__(256) void scan1_k(const int* __restrict__ cnt, int* __restrict__ off,
                                               int* __restrict__ blk, int Nn) {
    __shared__ int part[256];
    int t = threadIdx.x;
    int base = blockIdx.x * 1024 + t * 4;
    int v0 = base + 0 < Nn ? cnt[base + 0] : 0;
    int v1 = base + 1 < Nn ? cnt[base + 1] : 0;
    int v2 = base + 2 < Nn ? cnt[base + 2] : 0;
    int v3 = base + 3 < Nn ? cnt[base + 3] : 0;
    int s = v0 + v1 + v2 + v3;
    part[t] = s;
    __syncthreads();
    #pragma unroll
    for (int ofs = 1; ofs < 256; ofs <<= 1) {
        int p = (t >= ofs) ? part[t - ofs] : 0;
        __syncthreads();
        part[t] += p;
        __syncthreads();
    }
    int run = part[t] - s;  // exclusive prefix within block
    if (base + 0 < Nn) off[base + 0] = run; run += v0;
    if (base + 1 < Nn) off[base + 1] = run; run += v1;
    if (base + 2 < Nn) off[base + 2] = run; run += v2;
    if (base + 3 < Nn) off[base + 3] = run;
    if (t == 255) blk[blockIdx.x] = part[255];
}

// pass 2: one wave scans block totals (exclusive), nblk <= 64
__global__ __launch_bounds__(64) void scan2_k(int* __restrict__ blk, int nblk) {
    int t = threadIdx.x;
    int v = t < nblk ? blk[t] : 0;
    int inc = v;
    #pragma unroll
    for (int ofs = 1; ofs < 64; ofs <<= 1) {
        int p = __shfl_up(inc, ofs, 64);
        if (t >= ofs) inc += p;
    }
    if (t < nblk) blk[t] = inc - v;  // exclusive
}

// pass 3: add block base, write off/cur, set off[Nn]=E
__global__ __launch_bounds__(256) void scan3_k(int* __restrict__ off, int* __restrict__ cur,
                                               const int* __restrict__ blk, int Nn, int E) {
    int i = blockIdx.x * 256 + threadIdx.x;
    if (i < Nn) {
        int o = off[i] + blk[i >> 10];
        off[i] = o;
        cur[i] = o;
    }
    if (i == 0) off[Nn] = E;
}

__global__ __launch_bounds__(256) void scatter_k(const int* __restrict__ src, const int* __restrict__ dst,
                                                 int* __restrict__ cur, int* __restrict__ csr, int E) {
    int i = blockIdx.x * 256 + threadIdx.x;
    if (i < E) {
        int p = atomicAdd(&cur[dst[i]], 1);
        csr[p] = src[i];
    }
}

// ---------------- GEMM: C[M,128] = A[M,K] @ W[K,128] (+bias) ----------------
template <int K>
__global__ __launch_bounds__(256) void gemm_k(const float* __restrict__ A, const float* __restrict__ W,
                                              const float* __restrict__ bias, float* __restrict__ C, int M) {
    __shared__ float Ws[32 * HID];
    __shared__ float As[32 * 36];
    int t = threadIdx.x;
    int row0 = blockIdx.x * 32;
    int r0 = (t >> 5) << 2;
    int c0 = (t & 31) << 2;
    float acc[4][4] = {};
    for (int k0 = 0; k0 < K; k0 += 32) {
        #pragma unroll
        for (int i = 0; i < 4; ++i) {
            int fid = t + i * 256;
            int kk = fid >> 5;
            int c = (fid & 31) << 2;
            *(float4*)&Ws[kk * HID + c] = *(const float4*)&W[(k0 + kk) * HID + c];
        }
        {
            int r = t >> 3;
            int kk0 = (t & 7) << 2;
            float4 a4 = make_float4(0.f, 0.f, 0.f, 0.f);
            if (row0 + r < M) a4 = *(const float4*)&A[(size_t)(row0 + r) * K + k0 + kk0];
            As[(kk0 + 0) * 36 + r] = a4.x;
            As[(kk0 + 1) * 36 + r] = a4.y;
            As[(kk0 + 2) * 36 + r] = a4.z;
            As[(kk0 + 3) * 36 + r] = a4.w;
        }
        __syncthreads();
        #pragma unroll
        for (int kk = 0; kk < 32; ++kk) {
            float4 a4 = *(const float4*)&As[kk * 36 + r0];
            float4 w4 = *(const float4*)&Ws[kk * HID + c0];
            float av[4] = {a4.x, a4.y, a4.z, a4.w};
            float wv[4] = {w4.x, w4.y, w4.z, w4.w};
            #pragma unroll
            for (int i = 0; i < 4; ++i)
                #pragma unroll
                for (int j = 0; j < 4; ++j)
                    acc[i][j] = fmaf(av[i], wv[j], acc[i][j]);
        }
        __syncthreads();
    }
    float4 b4 = make_float4(0.f, 0.f, 0.f, 0.f);
    if (bias) b4 = *(const float4*)&bias[c0];
    #pragma unroll
    for (int i = 0; i < 4; ++i) {
        int r = row0 + r0 + i;
        if (r < M) {
            float4 o;
            o.x = acc[i][0] + b4.x;
            o.y = acc[i][1] + b4.y;
            o.z = acc[i][2] + b4.z;
            o.w = acc[i][3] + b4.w;
            *(float4*)&C[(size_t)r * HID + c0] = o;
        }
    }
}

// ---------------- attention dot products ----------------
__global__ __launch_bounds__(256) void attn_dots(const float* __restrict__ xl, const float* __restrict__ a_s,
                                                 const float* __restrict__ a_d, float* __restrict__ als,
                                                 float* __restrict__ ald, int Nn) {
    int gid = blockIdx.x * 256 + threadIdx.x;
    int wid = gid >> 6, lane = threadIdx.x & 63;
    if (wid >= Nn) return;
    int h = lane >> 4;
    float2 v = *(const float2*)&xl[(size_t)wid * HID + 2 * lane];
    float2 vs = *(const float2*)&a_s[2 * lane];
    float2 vd = *(const float2*)&a_d[2 * lane];
    float ps = v.x * vs.x + v.y * vs.y;
    float pd = v.x * vd.x + v.y * vd.y;
    #pragma unroll
    for (int m = 1; m < 16; m <<= 1) {
        ps += __shfl_xor(ps, m, 64);
        pd += __shfl_xor(pd, m, 64);
    }
    if ((lane & 15) == 0) {
        als[wid * HEADS + h] = ps;
        ald[wid * HEADS + h] = pd;
    }
}

// ---------------- softmax weights: per-edge w, per-node inv + self ----------------
__global__ __launch_bounds__(256) void attn_alpha(const float* __restrict__ als, const float* __restrict__ ald,
                                                  const int* __restrict__ off, const int* __restrict__ csr,
                                                  float* __restrict__ alphaw, float* __restrict__ nself,
                                                  float* __restrict__ ninv, int Nn) {
    int gid = blockIdx.x * 256 + threadIdx.x;
    int wid = gid >> 6, lane = threadIdx.x & 63;
    if (wid >= Nn) return;
    float4 aldn = *(const float4*)&ald[wid * 4];
    float4 alsn = *(const float4*)&als[wid * 4];
    float e0 = lrelu(alsn.x + aldn.x);
    float e1 = lrelu(alsn.y + aldn.y);
    float e2 = lrelu(alsn.z + aldn.z);
    float e3 = lrelu(alsn.w + aldn.w);
    float m0 = e0, m1 = e1, m2 = e2, m3 = e3;
    int b = off[wid], e = off[wid + 1];
    for (int c = b; c < e; c += 64) {
        int j = c + lane;
        bool v = j < e;
        int s = v ? csr[j] : 0;
        float4 a4 = *(const float4*)&als[(size_t)s * 4];
        float t0 = v ? lrelu(a4.x + aldn.x) : -INFINITY;
        float t1 = v ? lrelu(a4.y + aldn.y) : -INFINITY;
        float t2 = v ? lrelu(a4.z + aldn.z) : -INFINITY;
        float t3 = v ? lrelu(a4.w + aldn.w) : -INFINITY;
        m0 = fmaxf(m0, t0); m1 = fmaxf(m1, t1);
        m2 = fmaxf(m2, t2); m3 = fmaxf(m3, t3);
    }
    #pragma unroll
    for (int d = 1; d < 64; d <<= 1) {
        m0 = fmaxf(m0, __shfl_xor(m0, d, 64));
        m1 = fmaxf(m1, __shfl_xor(m1, d, 64));
        m2 = fmaxf(m2, __shfl_xor(m2, d, 64));
        m3 = fmaxf(m3, __shfl_xor(m3, d, 64));
    }
    float d0 = 0.f, d1 = 0.f, d2 = 0.f, d3 = 0.f;
    for (int c = b; c < e; c += 64) {
        int j = c + lane;
        bool v = j < e;
        int s = v ? csr[j] : 0;
        float4 a4 = *(const float4*)&als[(size_t)s * 4];
        float w0 = v ? __expf(lrelu(a4.x + aldn.x) - m0) : 0.f;
        float w1 = v ? __expf(lrelu(a4.y + aldn.y) - m1) : 0.f;
        float w2 = v ? __expf(lrelu(a4.z + aldn.z) - m2) : 0.f;
        float w3 = v ? __expf(lrelu(a4.w + aldn.w) - m3) : 0.f;
        if (v) *(float4*)&alphaw[(size_t)j * 4] = make_float4(w0, w1, w2, w3);
        d0 += w0; d1 += w1; d2 += w2; d3 += w3;
    }
    #pragma unroll
    for (int d = 1; d < 64; d <<= 1) {
        d0 += __shfl_xor(d0, d, 64);
        d1 += __shfl_xor(d1, d, 64);
        d2 += __shfl_xor(d2, d, 64);
        d3 += __shfl_xor(d3, d, 64);
    }
    if (lane == 0) {
        float ws0 = __expf(e0 - m0), ws1 = __expf(e1 - m1);
        float ws2 = __expf(e2 - m2), ws3 = __expf(e3 - m3);
        float i0 = 1.f / (d0 + ws0 + 1e-16f);
        float i1 = 1.f / (d1 + ws1 + 1e-16f);
        float i2 = 1.f / (d2 + ws2 + 1e-16f);
        float i3 = 1.f / (d3 + ws3 + 1e-16f);
        *(float4*)&nself[wid * 4] = make_float4(ws0 * i0, ws1 * i1, ws2 * i2, ws3 * i3);
        *(float4*)&ninv[wid * 4] = make_float4(i0, i1, i2, i3);
    }
}

// ---------------- gather: out[n] = inv * sum_j w_j * xl[s_j] + self + bias ----------------
__global__ __launch_bounds__(256) void gat_gather(const float* __restrict__ xl, const float* __restrict__ alphaw,
                                                  const float* __restrict__ nself, const float* __restrict__ ninv,
                                                  const int* __restrict__ off, const int* __restrict__ csr,
                                                  const float* __restrict__ bias, float* __restrict__ out, int Nn) {
    int gid = blockIdx.x * 256 + threadIdx.x;
    int wid = gid >> 6, lane = threadIdx.x & 63;
    if (wid >= Nn) return;
    int half = lane >> 5;
    int cl = lane & 31;
    int h = cl >> 3;
    int b = off[wid], e = off[wid + 1];
    float4 acc = make_float4(0.f, 0.f, 0.f, 0.f);
    for (int c = b + half; c < e; c += 2) {
        int s = csr[c];
        float w = alphaw[(size_t)c * 4 + h];
        float4 v = *(const float4*)&xl[(size_t)s * HID + cl * 4];
        acc.x = fmaf(w, v.x, acc.x);
        acc.y = fmaf(w, v.y, acc.y);
        acc.z = fmaf(w, v.z, acc.z);
        acc.w = fmaf(w, v.w, acc.w);
    }
    acc.x += __shfl_xor(acc.x, 32, 64);
    acc.y += __shfl_xor(acc.y, 32, 64);
    acc.z += __shfl_xor(acc.z, 32, 64);
    acc.w += __shfl_xor(acc.w, 32, 64);
    if (half == 0) {
        float inv = ninv[wid * 4 + h];
        float sa = nself[wid * 4 + h];
        float4 xv = *(const float4*)&xl[(size_t)wid * HID + cl * 4];
        float4 bi = *(const float4*)&bias[cl * 4];
        float4 o;
        o.x = fmaf(acc.x, inv, fmaf(sa, xv.x, bi.x));
        o.y = fmaf(acc.y, inv, fmaf(sa, xv.y, bi.y));
        o.z = fmaf(acc.z, inv, fmaf(sa, xv.z, bi.z));
        o.w = fmaf(acc.w, inv, fmaf(sa, xv.w, bi.w));
        *(float4*)&out[(size_t)wid * HID + cl * 4] = o;
    }
}

// ---------------- LayerNorm + ReLU + residual ----------------
__global__ __launch_bounds__(256) void ln_relu_res(const float* __restrict__ gin, const float* __restrict__ g,
                                                   const float* __restrict__ be, float* __restrict__ hres, int Nn) {
    int gid = blockIdx.x * 256 + threadIdx.x;
    int wid = gid >> 6, lane = threadIdx.x & 63;
    if (wid >= Nn) return;
    float2 v = *(const float2*)&gin[(size_t)wid * HID + 2 * lane];
    float s = v.x + v.y;
    #pragma unroll
    for (int m = 1; m < 64; m <<= 1) s += __shfl_xor(s, m, 64);
    float mu = s * (1.0f / HID);
    float dx = v.x - mu, dy = v.y - mu;
    float q = dx * dx + dy * dy;
    #pragma unroll
    for (int m = 1; m < 64; m <<= 1) q += __shfl_xor(q, m, 64);
    float rs = rsqrtf(q * (1.0f / HID) + LN_EPS);
    float2 gg = *(const float2*)&g[2 * lane];
    float2 bb = *(const float2*)&be[2 * lane];
    float2 rr = *(const float2*)&hres[(size_t)wid * HID + 2 * lane];
    float o0 = fmaxf(dx * rs * gg.x + bb.x, 0.f) + rr.x;
    float o1 = fmaxf(dy * rs * gg.y + bb.y, 0.f) + rr.y;
    *(float2*)&hres[(size_t)wid * HID + 2 * lane] = make_float2(o0, o1);
}

// ---------------- output projection ----------------
__global__ __launch_bounds__(256) void out_proj(const float* __restrict__ h, const float* __restrict__ Wo,
                                                const float* __restrict__ aso, const float* __restrict__ ado,
                                                float* __restrict__ xlo, float* __restrict__ also,
                                                float* __restrict__ aldo, int Nn) {
    int gid = blockIdx.x * 256 + threadIdx.x;
    int wid = gid >> 6, lane = threadIdx.x & 63;
    if (wid >= Nn) return;
    float2 v = *(const float2*)&h[(size_t)wid * HID + 2 * lane];
    float2 w0 = *(const float2*)&Wo[(2 * lane) * 2];
    float2 w1 = *(const float2*)&Wo[(2 * lane + 1) * 2];
    float p0 = v.x * w0.x + v.y * w1.x;
    float p1 = v.x * w0.y + v.y * w1.y;
    #pragma unroll
    for (int m = 1; m < 64; m <<= 1) {
        p0 += __shfl_xor(p0, m, 64);
        p1 += __shfl_xor(p1, m, 64);
    }
    if (lane == 0) {
        xlo[wid * 2 + 0] = p0;
        xlo[wid * 2 + 1] = p1;
        also[wid] = p0 * aso[0] + p1 * aso[1];
        aldo[wid] = p0 * ado[0] + p1 * ado[1];
    }
}

// ---------------- output aggregation ----------------
__global__ __launch_bounds__(256) void out_agg(const float* __restrict__ xlo, const float* __restrict__ also,
                                               const float* __restrict__ aldo, const int* __restrict__ off,
                                               const int* __restrict__ csr, const float* __restrict__ bo,
                                               float* __restrict__ out, int Nn) {
    int gid = blockIdx.x * 256 + threadIdx.x;
    int wid = gid >> 6, lane = threadIdx.x & 63;
    if (wid >= Nn) return;
    float aldn = aldo[wid];
    float eself = lrelu(also[wid] + aldn);
    int b = off[wid], e = off[wid + 1];
    float mloc = -INFINITY;
    for (int j = b + lane; j < e; j += 64)
        mloc = fmaxf(mloc, lrelu(also[csr[j]] + aldn));
    #pragma unroll
    for (int m = 1; m < 64; m <<= 1) mloc = fmaxf(mloc, __shfl_xor(mloc, m, 64));
    float mm = fmaxf(mloc, eself);
    float dl = 0.f, a0 = 0.f, a1 = 0.f;
    for (int j = b + lane; j < e; j += 64) {
        int s = csr[j];
        float w = __expf(lrelu(also[s] + aldn) - mm);
        dl += w;
        a0 += w * xlo[s * 2 + 0];
        a1 += w * xlo[s * 2 + 1];
    }
    #pragma unroll
    for (int m = 1; m < 64; m <<= 1) {
        dl += __shfl_xor(dl, m, 64);
        a0 += __shfl_xor(a0, m, 64);
        a1 += __shfl_xor(a1, m, 64);
    }
    if (lane == 0) {
        float wsf = __expf(eself - mm);
        dl += wsf;
        a0 += wsf * xlo[wid * 2 + 0];
        a1 += wsf * xlo[wid * 2 + 1];
        float inv = 1.f / (dl + 1e-16f);
        out[wid * 2 + 0] = a0 * inv + bo[0];
        out[wid * 2 + 1] = a1 * inv + bo[1];
    }
}

extern "C" void kernel_launch(void* const* d_in, const int* in_sizes, int n_in,
                              void* d_out, int out_size, void* d_ws, size_t ws_size,
                              hipStream_t stream) {
    const float* x   = (const float*)d_in[0];
    const int*   ei  = (const int*)d_in[1];
    const float* W1  = (const float*)d_in[2];
    const float* as1 = (const float*)d_in[3];
    const float* ad1 = (const float*)d_in[4];
    const float* b1  = (const float*)d_in[5];
    const float* g1  = (const float*)d_in[6];
    const float* be1 = (const float*)d_in[7];
    const float* rw  = (const float*)d_in[8];
    const float* rb  = (const float*)d_in[9];
    const float* W2  = (const float*)d_in[10];
    const float* as2 = (const float*)d_in[11];
    const float* ad2 = (const float*)d_in[12];
    const float* b2  = (const float*)d_in[13];
    const float* g2  = (const float*)d_in[14];
    const float* be2 = (const float*)d_in[15];
    const float* W3  = (const float*)d_in[16];
    const float* as3 = (const float*)d_in[17];
    const float* ad3 = (const float*)d_in[18];
    const float* b3  = (const float*)d_in[19];
    const float* g3  = (const float*)d_in[20];
    const float* be3 = (const float*)d_in[21];
    const float* Wo  = (const float*)d_in[22];
    const float* aso = (const float*)d_in[23];
    const float* ado = (const float*)d_in[24];
    const float* bo  = (const float*)d_in[25];

    int N = in_sizes[0] / 64;   // 50000
    int E = in_sizes[1] / 2;    // 800000
    const int* srcE = ei;
    const int* dstE = ei + E;

    char* w = (char*)d_ws;
    auto alloc = [&](size_t b) { char* p = w; w += (b + 255) & ~(size_t)255; return p; };
    int* cnt    = (int*)alloc((size_t)N * 4);
    int* off    = (int*)alloc((size_t)(N + 1) * 4);
    int* cur    = (int*)alloc((size_t)N * 4);
    int* blk    = (int*)alloc(((size_t)N / 1024 + 2) * 4);
    int* csr    = (int*)alloc((size_t)E * 4);
    float* hbuf = (float*)alloc((size_t)N * HID * 4);
    float* xlb  = (float*)alloc((size_t)N * HID * 4);
    float* gb   = (float*)alloc((size_t)N * HID * 4);
    float* als  = (float*)alloc((size_t)N * HEADS * 4);
    float* ald  = (float*)alloc((size_t)N * HEADS * 4);
    float* alphaw = (float*)alloc((size_t)E * HEADS * 4);
    float* nself  = (float*)alloc((size_t)N * HEADS * 4);
    float* ninv   = (float*)alloc((size_t)N * HEADS * 4);
    float* xlo  = (float*)alloc((size_t)N * 2 * 4);
    float* alsoB = (float*)alloc((size_t)N * 4);
    float* aldoB = (float*)alloc((size_t)N * 4);

    hipMemsetAsync(cnt, 0, (size_t)N * 4, stream);
    int gE = (E + 255) / 256;
    int nblk = (N + 1023) / 1024;
    count_k<<<gE, 256, 0, stream>>>(dstE, cnt, E);
    scan1_k<<<nblk, 256, 0, stream>>>(cnt, off, blk, N);
    scan2_k<<<1, 64, 0, stream>>>(blk, nblk);
    scan3_k<<<(N + 256) / 256, 256, 0, stream>>>(off, cur, blk, N, E);
    scatter_k<<<gE, 256, 0, stream>>>(srcE, dstE, cur, csr, E);

    int gM = (N + 31) / 32;
    int gW = (N + 3) / 4;

    gemm_k<64><<<gM, 256, 0, stream>>>(x, rw, rb, hbuf, N);

    // ---- layer 1 ----
    gemm_k<64><<<gM, 256, 0, stream>>>(x, W1, nullptr, xlb, N);
    attn_dots<<<gW, 256, 0, stream>>>(xlb, as1, ad1, als, ald, N);
    attn_alpha<<<gW, 256, 0, stream>>>(als, ald, off, csr, alphaw, nself, ninv, N);
    gat_gather<<<gW, 256, 0, stream>>>(xlb, alphaw, nself, ninv, off, csr, b1, gb, N);
    ln_relu_res<<<gW, 256, 0, stream>>>(gb, g1, be1, hbuf, N);

    // ---- layer 2 ----
    gemm_k<128><<<gM, 256, 0, stream>>>(hbuf, W2, nullptr, xlb, N);
    attn_dots<<<gW, 256, 0, stream>>>(xlb, as2, ad2, als, ald, N);
    attn_alpha<<<gW, 256, 0, stream>>>(als, ald, off, csr, alphaw, nself, ninv, N);
    gat_gather<<<gW, 256, 0, stream>>>(xlb, alphaw, nself, ninv, off, csr, b2, gb, N);
    ln_relu_res<<<gW, 256, 0, stream>>>(gb, g2, be2, hbuf, N);

    // ---- layer 3 ----
    gemm_k<128><<<gM, 256, 0, stream>>>(hbuf, W3, nullptr, xlb, N);
    attn_dots<<<gW, 256, 0, stream>>>(xlb, as3, ad3, als, ald, N);
    attn_alpha<<<gW, 256, 0, stream>>>(als, ald, off, csr, alphaw, nself, ninv, N);
    gat_gather<<<gW, 256, 0, stream>>>(xlb, alphaw, nself, ninv, off, csr, b3, gb, N);
    ln_relu_res<<<gW, 256, 0, stream>>>(gb, g3, be3, hbuf, N);

    // ---- output layer ----
    out_proj<<<gW, 256, 0, stream>>>(hbuf, Wo, aso, ado, xlo, alsoB, aldoB, N);
    out_agg<<<gW, 256, 0, stream>>>(xlo, alsoB, aldoB, off, csr, bo, (float*)d_out, N);
}

// Round 4
// 498.037 us; speedup vs baseline: 1.6129x; 1.1285x over previous
//
#include <hip/hip_runtime.h>
#include <math.h>

#define HID 128
#define HEADS 4
#define NEG_SLOPE 0.2f
#define LN_EPS 1e-5f

typedef unsigned short ushortT;
typedef unsigned int uintT;

__device__ __forceinline__ float lrelu(float v) { return v > 0.f ? v : NEG_SLOPE * v; }

__device__ __forceinline__ ushortT f2bf(float f) {
    uintT u = __float_as_uint(f);
    u += 0x7fffu + ((u >> 16) & 1u);   // round-to-nearest-even
    return (ushortT)(u >> 16);
}

// ---------------- CSR build ----------------
__global__ __launch_bounds__(256) void count_k(const int* __restrict__ dst, int* __restrict__ cnt, int E) {
    int i = blockIdx.x * 256 + threadIdx.x;
    if (i < E) atomicAdd(&cnt[dst[i]], 1);
}

__global__ __launch_bounds__(256) void scan1_k(const int* __restrict__ cnt, int* __restrict__ off,
                                               int* __restrict__ blk, int Nn) {
    __shared__ int part[256];
    int t = threadIdx.x;
    int base = blockIdx.x * 1024 + t * 4;
    int v0 = base + 0 < Nn ? cnt[base + 0] : 0;
    int v1 = base + 1 < Nn ? cnt[base + 1] : 0;
    int v2 = base + 2 < Nn ? cnt[base + 2] : 0;
    int v3 = base + 3 < Nn ? cnt[base + 3] : 0;
    int s = v0 + v1 + v2 + v3;
    part[t] = s;
    __syncthreads();
    #pragma unroll
    for (int ofs = 1; ofs < 256; ofs <<= 1) {
        int p = (t >= ofs) ? part[t - ofs] : 0;
        __syncthreads();
        part[t] += p;
        __syncthreads();
    }
    int run = part[t] - s;
    if (base + 0 < Nn) off[base + 0] = run; run += v0;
    if (base + 1 < Nn) off[base + 1] = run; run += v1;
    if (base + 2 < Nn) off[base + 2] = run; run += v2;
    if (base + 3 < Nn) off[base + 3] = run;
    if (t == 255) blk[blockIdx.x] = part[255];
}

__global__ __launch_bounds__(64) void scan2_k(int* __restrict__ blk, int nblk) {
    int t = threadIdx.x;
    int v = t < nblk ? blk[t] : 0;
    int inc = v;
    #pragma unroll
    for (int ofs = 1; ofs < 64; ofs <<= 1) {
        int p = __shfl_up(inc, ofs, 64);
        if (t >= ofs) inc += p;
    }
    if (t < nblk) blk[t] = inc - v;
}

__global__ __launch_bounds__(256) void scan3_k(int* __restrict__ off, int* __restrict__ cur,
                                               const int* __restrict__ blk, int Nn, int E) {
    int i = blockIdx.x * 256 + threadIdx.x;
    if (i < Nn) {
        int o = off[i] + blk[i >> 10];
        off[i] = o;
        cur[i] = o;
    }
    if (i == 0) off[Nn] = E;
}

__global__ __launch_bounds__(256) void scatter_k(const int* __restrict__ src, const int* __restrict__ dst,
                                                 int* __restrict__ cur, int* __restrict__ csr, int E) {
    int i = blockIdx.x * 256 + threadIdx.x;
    if (i < E) {
        int p = atomicAdd(&cur[dst[i]], 1);
        csr[p] = src[i];
    }
}

// ---------------- GEMM: C[M,128] = A[M,K] @ W[K,128] (+bias), optional bf16 dual store ----------------
template <int K>
__global__ __launch_bounds__(256) void gemm_k(const float* __restrict__ A, const float* __restrict__ W,
                                              const float* __restrict__ bias, float* __restrict__ C, int M,
                                              ushortT* __restrict__ Ch) {
    __shared__ float Ws[32 * HID];
    __shared__ float As[32 * 36];
    int t = threadIdx.x;
    int row0 = blockIdx.x * 32;
    int r0 = (t >> 5) << 2;
    int c0 = (t & 31) << 2;
    float acc[4][4] = {};
    for (int k0 = 0; k0 < K; k0 += 32) {
        #pragma unroll
        for (int i = 0; i < 4; ++i) {
            int fid = t + i * 256;
            int kk = fid >> 5;
            int c = (fid & 31) << 2;
            *(float4*)&Ws[kk * HID + c] = *(const float4*)&W[(k0 + kk) * HID + c];
        }
        {
            int r = t >> 3;
            int kk0 = (t & 7) << 2;
            float4 a4 = make_float4(0.f, 0.f, 0.f, 0.f);
            if (row0 + r < M) a4 = *(const float4*)&A[(size_t)(row0 + r) * K + k0 + kk0];
            As[(kk0 + 0) * 36 + r] = a4.x;
            As[(kk0 + 1) * 36 + r] = a4.y;
            As[(kk0 + 2) * 36 + r] = a4.z;
            As[(kk0 + 3) * 36 + r] = a4.w;
        }
        __syncthreads();
        #pragma unroll
        for (int kk = 0; kk < 32; ++kk) {
            float4 a4 = *(const float4*)&As[kk * 36 + r0];
            float4 w4 = *(const float4*)&Ws[kk * HID + c0];
            float av[4] = {a4.x, a4.y, a4.z, a4.w};
            float wv[4] = {w4.x, w4.y, w4.z, w4.w};
            #pragma unroll
            for (int i = 0; i < 4; ++i)
                #pragma unroll
                for (int j = 0; j < 4; ++j)
                    acc[i][j] = fmaf(av[i], wv[j], acc[i][j]);
        }
        __syncthreads();
    }
    float4 b4 = make_float4(0.f, 0.f, 0.f, 0.f);
    if (bias) b4 = *(const float4*)&bias[c0];
    #pragma unroll
    for (int i = 0; i < 4; ++i) {
        int r = row0 + r0 + i;
        if (r < M) {
            float4 o;
            o.x = acc[i][0] + b4.x;
            o.y = acc[i][1] + b4.y;
            o.z = acc[i][2] + b4.z;
            o.w = acc[i][3] + b4.w;
            *(float4*)&C[(size_t)r * HID + c0] = o;
            if (Ch) {
                ushort4 hv;
                hv.x = f2bf(o.x); hv.y = f2bf(o.y);
                hv.z = f2bf(o.z); hv.w = f2bf(o.w);
                *(ushort4*)&Ch[(size_t)r * HID + c0] = hv;
            }
        }
    }
}

// ---------------- attention dot products ----------------
__global__ __launch_bounds__(256) void attn_dots(const float* __restrict__ xl, const float* __restrict__ a_s,
                                                 const float* __restrict__ a_d, float* __restrict__ als,
                                                 float* __restrict__ ald, int Nn) {
    int gid = blockIdx.x * 256 + threadIdx.x;
    int wid = gid >> 6, lane = threadIdx.x & 63;
    if (wid >= Nn) return;
    int h = lane >> 4;
    float2 v = *(const float2*)&xl[(size_t)wid * HID + 2 * lane];
    float2 vs = *(const float2*)&a_s[2 * lane];
    float2 vd = *(const float2*)&a_d[2 * lane];
    float ps = v.x * vs.x + v.y * vs.y;
    float pd = v.x * vd.x + v.y * vd.y;
    #pragma unroll
    for (int m = 1; m < 16; m <<= 1) {
        ps += __shfl_xor(ps, m, 64);
        pd += __shfl_xor(pd, m, 64);
    }
    if ((lane & 15) == 0) {
        als[wid * HEADS + h] = ps;
        ald[wid * HEADS + h] = pd;
    }
}

// ---------------- softmax weights ----------------
__global__ __launch_bounds__(256) void attn_alpha(const float* __restrict__ als, const float* __restrict__ ald,
                                                  const int* __restrict__ off, const int* __restrict__ csr,
                                                  float* __restrict__ alphaw, float* __restrict__ nself,
                                                  float* __restrict__ ninv, int Nn) {
    int gid = blockIdx.x * 256 + threadIdx.x;
    int wid = gid >> 6, lane = threadIdx.x & 63;
    if (wid >= Nn) return;
    float4 aldn = *(const float4*)&ald[wid * 4];
    float4 alsn = *(const float4*)&als[wid * 4];
    float e0 = lrelu(alsn.x + aldn.x);
    float e1 = lrelu(alsn.y + aldn.y);
    float e2 = lrelu(alsn.z + aldn.z);
    float e3 = lrelu(alsn.w + aldn.w);
    float m0 = e0, m1 = e1, m2 = e2, m3 = e3;
    int b = off[wid], e = off[wid + 1];
    for (int c = b; c < e; c += 64) {
        int j = c + lane;
        bool v = j < e;
        int s = v ? csr[j] : 0;
        float4 a4 = *(const float4*)&als[(size_t)s * 4];
        float t0 = v ? lrelu(a4.x + aldn.x) : -INFINITY;
        float t1 = v ? lrelu(a4.y + aldn.y) : -INFINITY;
        float t2 = v ? lrelu(a4.z + aldn.z) : -INFINITY;
        float t3 = v ? lrelu(a4.w + aldn.w) : -INFINITY;
        m0 = fmaxf(m0, t0); m1 = fmaxf(m1, t1);
        m2 = fmaxf(m2, t2); m3 = fmaxf(m3, t3);
    }
    #pragma unroll
    for (int d = 1; d < 64; d <<= 1) {
        m0 = fmaxf(m0, __shfl_xor(m0, d, 64));
        m1 = fmaxf(m1, __shfl_xor(m1, d, 64));
        m2 = fmaxf(m2, __shfl_xor(m2, d, 64));
        m3 = fmaxf(m3, __shfl_xor(m3, d, 64));
    }
    float d0 = 0.f, d1 = 0.f, d2 = 0.f, d3 = 0.f;
    for (int c = b; c < e; c += 64) {
        int j = c + lane;
        bool v = j < e;
        int s = v ? csr[j] : 0;
        float4 a4 = *(const float4*)&als[(size_t)s * 4];
        float w0 = v ? __expf(lrelu(a4.x + aldn.x) - m0) : 0.f;
        float w1 = v ? __expf(lrelu(a4.y + aldn.y) - m1) : 0.f;
        float w2 = v ? __expf(lrelu(a4.z + aldn.z) - m2) : 0.f;
        float w3 = v ? __expf(lrelu(a4.w + aldn.w) - m3) : 0.f;
        if (v) *(float4*)&alphaw[(size_t)j * 4] = make_float4(w0, w1, w2, w3);
        d0 += w0; d1 += w1; d2 += w2; d3 += w3;
    }
    #pragma unroll
    for (int d = 1; d < 64; d <<= 1) {
        d0 += __shfl_xor(d0, d, 64);
        d1 += __shfl_xor(d1, d, 64);
        d2 += __shfl_xor(d2, d, 64);
        d3 += __shfl_xor(d3, d, 64);
    }
    if (lane == 0) {
        float ws0 = __expf(e0 - m0), ws1 = __expf(e1 - m1);
        float ws2 = __expf(e2 - m2), ws3 = __expf(e3 - m3);
        float i0 = 1.f / (d0 + ws0 + 1e-16f);
        float i1 = 1.f / (d1 + ws1 + 1e-16f);
        float i2 = 1.f / (d2 + ws2 + 1e-16f);
        float i3 = 1.f / (d3 + ws3 + 1e-16f);
        *(float4*)&nself[wid * 4] = make_float4(ws0 * i0, ws1 * i1, ws2 * i2, ws3 * i3);
        *(float4*)&ninv[wid * 4] = make_float4(i0, i1, i2, i3);
    }
}

// ---------------- fused gather (bf16 src rows) + LayerNorm + ReLU + residual ----------------
// wave/node; 4 edges in flight (16 lanes x bf16x8 = 256B row each)
__global__ __launch_bounds__(256) void gat_gather_ln(
        const float* __restrict__ xl, const ushortT* __restrict__ xlh,
        const float* __restrict__ alphaw, const float* __restrict__ nself,
        const float* __restrict__ ninv, const int* __restrict__ off,
        const int* __restrict__ csr, const float* __restrict__ bias,
        const float* __restrict__ g, const float* __restrict__ be,
        float* __restrict__ hres, int Nn) {
    int gid = blockIdx.x * 256 + threadIdx.x;
    int wid = gid >> 6, lane = threadIdx.x & 63;
    if (wid >= Nn) return;
    int q = lane >> 4;        // edge slot 0..3
    int cl = lane & 15;       // channel group: ch [cl*8, cl*8+8)
    int h = cl >> 2;          // head
    int b = off[wid], e = off[wid + 1];
    float acc[8] = {};
    for (int c = b + q; c < e; c += 4) {
        int s = csr[c];
        float w = alphaw[(size_t)c * 4 + h];
        uint4 hv = *(const uint4*)&xlh[(size_t)s * HID + cl * 8];
        acc[0] = fmaf(w, __uint_as_float(hv.x << 16), acc[0]);
        acc[1] = fmaf(w, __uint_as_float(hv.x & 0xffff0000u), acc[1]);
        acc[2] = fmaf(w, __uint_as_float(hv.y << 16), acc[2]);
        acc[3] = fmaf(w, __uint_as_float(hv.y & 0xffff0000u), acc[3]);
        acc[4] = fmaf(w, __uint_as_float(hv.z << 16), acc[4]);
        acc[5] = fmaf(w, __uint_as_float(hv.z & 0xffff0000u), acc[5]);
        acc[6] = fmaf(w, __uint_as_float(hv.w << 16), acc[6]);
        acc[7] = fmaf(w, __uint_as_float(hv.w & 0xffff0000u), acc[7]);
    }
    #pragma unroll
    for (int k = 0; k < 8; ++k) {
        acc[k] += __shfl_xor(acc[k], 16, 64);
        acc[k] += __shfl_xor(acc[k], 32, 64);
    }
    // all 64 lanes now hold the full edge-sum for their channel group cl
    float inv = ninv[wid * 4 + h];
    float sa = nself[wid * 4 + h];
    float4 xv0 = *(const float4*)&xl[(size_t)wid * HID + cl * 8];
    float4 xv1 = *(const float4*)&xl[(size_t)wid * HID + cl * 8 + 4];
    float4 bi0 = *(const float4*)&bias[cl * 8];
    float4 bi1 = *(const float4*)&bias[cl * 8 + 4];
    float o[8];
    o[0] = fmaf(acc[0], inv, fmaf(sa, xv0.x, bi0.x));
    o[1] = fmaf(acc[1], inv, fmaf(sa, xv0.y, bi0.y));
    o[2] = fmaf(acc[2], inv, fmaf(sa, xv0.z, bi0.z));
    o[3] = fmaf(acc[3], inv, fmaf(sa, xv0.w, bi0.w));
    o[4] = fmaf(acc[4], inv, fmaf(sa, xv1.x, bi1.x));
    o[5] = fmaf(acc[5], inv, fmaf(sa, xv1.y, bi1.y));
    o[6] = fmaf(acc[6], inv, fmaf(sa, xv1.z, bi1.z));
    o[7] = fmaf(acc[7], inv, fmaf(sa, xv1.w, bi1.w));
    // LayerNorm over the 128-ch row: reduce over cl (bits 0..3); q-copies identical
    float s1 = o[0] + o[1] + o[2] + o[3] + o[4] + o[5] + o[6] + o[7];
    #pragma unroll
    for (int m = 1; m < 16; m <<= 1) s1 += __shfl_xor(s1, m, 64);
    float mu = s1 * (1.0f / HID);
    float qv = 0.f;
    #pragma unroll
    for (int k = 0; k < 8; ++k) { float d = o[k] - mu; qv += d * d; }
    #pragma unroll
    for (int m = 1; m < 16; m <<= 1) qv += __shfl_xor(qv, m, 64);
    float rs = rsqrtf(qv * (1.0f / HID) + LN_EPS);
    if (q == 0) {
        float4 g0 = *(const float4*)&g[cl * 8];
        float4 g1 = *(const float4*)&g[cl * 8 + 4];
        float4 e0 = *(const float4*)&be[cl * 8];
        float4 e1 = *(const float4*)&be[cl * 8 + 4];
        float4 r0 = *(const float4*)&hres[(size_t)wid * HID + cl * 8];
        float4 r1 = *(const float4*)&hres[(size_t)wid * HID + cl * 8 + 4];
        float4 w0, w1;
        w0.x = fmaxf((o[0] - mu) * rs * g0.x + e0.x, 0.f) + r0.x;
        w0.y = fmaxf((o[1] - mu) * rs * g0.y + e0.y, 0.f) + r0.y;
        w0.z = fmaxf((o[2] - mu) * rs * g0.z + e0.z, 0.f) + r0.z;
        w0.w = fmaxf((o[3] - mu) * rs * g0.w + e0.w, 0.f) + r0.w;
        w1.x = fmaxf((o[4] - mu) * rs * g1.x + e1.x, 0.f) + r1.x;
        w1.y = fmaxf((o[5] - mu) * rs * g1.y + e1.y, 0.f) + r1.y;
        w1.z = fmaxf((o[6] - mu) * rs * g1.z + e1.z, 0.f) + r1.z;
        w1.w = fmaxf((o[7] - mu) * rs * g1.w + e1.w, 0.f) + r1.w;
        *(float4*)&hres[(size_t)wid * HID + cl * 8] = w0;
        *(float4*)&hres[(size_t)wid * HID + cl * 8 + 4] = w1;
    }
}

// ---------------- output projection ----------------
__global__ __launch_bounds__(256) void out_proj(const float* __restrict__ h, const float* __restrict__ Wo,
                                                const float* __restrict__ aso, const float* __restrict__ ado,
                                                float* __restrict__ xlo, float* __restrict__ also,
                                                float* __restrict__ aldo, int Nn) {
    int gid = blockIdx.x * 256 + threadIdx.x;
    int wid = gid >> 6, lane = threadIdx.x & 63;
    if (wid >= Nn) return;
    float2 v = *(const float2*)&h[(size_t)wid * HID + 2 * lane];
    float2 w0 = *(const float2*)&Wo[(2 * lane) * 2];
    float2 w1 = *(const float2*)&Wo[(2 * lane + 1) * 2];
    float p0 = v.x * w0.x + v.y * w1.x;
    float p1 = v.x * w0.y + v.y * w1.y;
    #pragma unroll
    for (int m = 1; m < 64; m <<= 1) {
        p0 += __shfl_xor(p0, m, 64);
        p1 += __shfl_xor(p1, m, 64);
    }
    if (lane == 0) {
        xlo[wid * 2 + 0] = p0;
        xlo[wid * 2 + 1] = p1;
        also[wid] = p0 * aso[0] + p1 * aso[1];
        aldo[wid] = p0 * ado[0] + p1 * ado[1];
    }
}

// ---------------- output aggregation ----------------
__global__ __launch_bounds__(256) void out_agg(const float* __restrict__ xlo, const float* __restrict__ also,
                                               const float* __restrict__ aldo, const int* __restrict__ off,
                                               const int* __restrict__ csr, const float* __restrict__ bo,
                                               float* __restrict__ out, int Nn) {
    int gid = blockIdx.x * 256 + threadIdx.x;
    int wid = gid >> 6, lane = threadIdx.x & 63;
    if (wid >= Nn) return;
    float aldn = aldo[wid];
    float eself = lrelu(also[wid] + aldn);
    int b = off[wid], e = off[wid + 1];
    float mloc = -INFINITY;
    for (int j = b + lane; j < e; j += 64)
        mloc = fmaxf(mloc, lrelu(also[csr[j]] + aldn));
    #pragma unroll
    for (int m = 1; m < 64; m <<= 1) mloc = fmaxf(mloc, __shfl_xor(mloc, m, 64));
    float mm = fmaxf(mloc, eself);
    float dl = 0.f, a0 = 0.f, a1 = 0.f;
    for (int j = b + lane; j < e; j += 64) {
        int s = csr[j];
        float w = __expf(lrelu(also[s] + aldn) - mm);
        dl += w;
        a0 += w * xlo[s * 2 + 0];
        a1 += w * xlo[s * 2 + 1];
    }
    #pragma unroll
    for (int m = 1; m < 64; m <<= 1) {
        dl += __shfl_xor(dl, m, 64);
        a0 += __shfl_xor(a0, m, 64);
        a1 += __shfl_xor(a1, m, 64);
    }
    if (lane == 0) {
        float wsf = __expf(eself - mm);
        dl += wsf;
        a0 += wsf * xlo[wid * 2 + 0];
        a1 += wsf * xlo[wid * 2 + 1];
        float inv = 1.f / (dl + 1e-16f);
        out[wid * 2 + 0] = a0 * inv + bo[0];
        out[wid * 2 + 1] = a1 * inv + bo[1];
    }
}

extern "C" void kernel_launch(void* const* d_in, const int* in_sizes, int n_in,
                              void* d_out, int out_size, void* d_ws, size_t ws_size,
                              hipStream_t stream) {
    const float* x   = (const float*)d_in[0];
    const int*   ei  = (const int*)d_in[1];
    const float* W1  = (const float*)d_in[2];
    const float* as1 = (const float*)d_in[3];
    const float* ad1 = (const float*)d_in[4];
    const float* b1  = (const float*)d_in[5];
    const float* g1  = (const float*)d_in[6];
    const float* be1 = (const float*)d_in[7];
    const float* rw  = (const float*)d_in[8];
    const float* rb  = (const float*)d_in[9];
    const float* W2  = (const float*)d_in[10];
    const float* as2 = (const float*)d_in[11];
    const float* ad2 = (const float*)d_in[12];
    const float* b2  = (const float*)d_in[13];
    const float* g2  = (const float*)d_in[14];
    const float* be2 = (const float*)d_in[15];
    const float* W3  = (const float*)d_in[16];
    const float* as3 = (const float*)d_in[17];
    const float* ad3 = (const float*)d_in[18];
    const float* b3  = (const float*)d_in[19];
    const float* g3  = (const float*)d_in[20];
    const float* be3 = (const float*)d_in[21];
    const float* Wo  = (const float*)d_in[22];
    const float* aso = (const float*)d_in[23];
    const float* ado = (const float*)d_in[24];
    const float* bo  = (const float*)d_in[25];

    int N = in_sizes[0] / 64;   // 50000
    int E = in_sizes[1] / 2;    // 800000
    const int* srcE = ei;
    const int* dstE = ei + E;

    char* w = (char*)d_ws;
    auto alloc = [&](size_t b) { char* p = w; w += (b + 255) & ~(size_t)255; return p; };
    int* cnt    = (int*)alloc((size_t)N * 4);
    int* off    = (int*)alloc((size_t)(N + 1) * 4);
    int* cur    = (int*)alloc((size_t)N * 4);
    int* blk    = (int*)alloc(((size_t)N / 1024 + 2) * 4);
    int* csr    = (int*)alloc((size_t)E * 4);
    float* hbuf = (float*)alloc((size_t)N * HID * 4);
    float* xlb  = (float*)alloc((size_t)N * HID * 4);
    ushortT* xlh = (ushortT*)alloc((size_t)N * HID * 2);
    float* als  = (float*)alloc((size_t)N * HEADS * 4);
    float* ald  = (float*)alloc((size_t)N * HEADS * 4);
    float* alphaw = (float*)alloc((size_t)E * HEADS * 4);
    float* nself  = (float*)alloc((size_t)N * HEADS * 4);
    float* ninv   = (float*)alloc((size_t)N * HEADS * 4);
    float* xlo  = (float*)alloc((size_t)N * 2 * 4);
    float* alsoB = (float*)alloc((size_t)N * 4);
    float* aldoB = (float*)alloc((size_t)N * 4);

    hipMemsetAsync(cnt, 0, (size_t)N * 4, stream);
    int gE = (E + 255) / 256;
    int nblk = (N + 1023) / 1024;
    count_k<<<gE, 256, 0, stream>>>(dstE, cnt, E);
    scan1_k<<<nblk, 256, 0, stream>>>(cnt, off, blk, N);
    scan2_k<<<1, 64, 0, stream>>>(blk, nblk);
    scan3_k<<<(N + 256) / 256, 256, 0, stream>>>(off, cur, blk, N, E);
    scatter_k<<<gE, 256, 0, stream>>>(srcE, dstE, cur, csr, E);

    int gM = (N + 31) / 32;
    int gW = (N + 3) / 4;

    // residual projection: hbuf = x @ rw + rb
    gemm_k<64><<<gM, 256, 0, stream>>>(x, rw, rb, hbuf, N, nullptr);

    // ---- layer 1 ----
    gemm_k<64><<<gM, 256, 0, stream>>>(x, W1, nullptr, xlb, N, xlh);
    attn_dots<<<gW, 256, 0, stream>>>(xlb, as1, ad1, als, ald, N);
    attn_alpha<<<gW, 256, 0, stream>>>(als, ald, off, csr, alphaw, nself, ninv, N);
    gat_gather_ln<<<gW, 256, 0, stream>>>(xlb, xlh, alphaw, nself, ninv, off, csr, b1, g1, be1, hbuf, N);

    // ---- layer 2 ----
    gemm_k<128><<<gM, 256, 0, stream>>>(hbuf, W2, nullptr, xlb, N, xlh);
    attn_dots<<<gW, 256, 0, stream>>>(xlb, as2, ad2, als, ald, N);
    attn_alpha<<<gW, 256, 0, stream>>>(als, ald, off, csr, alphaw, nself, ninv, N);
    gat_gather_ln<<<gW, 256, 0, stream>>>(xlb, xlh, alphaw, nself, ninv, off, csr, b2, g2, be2, hbuf, N);

    // ---- layer 3 ----
    gemm_k<128><<<gM, 256, 0, stream>>>(hbuf, W3, nullptr, xlb, N, xlh);
    attn_dots<<<gW, 256, 0, stream>>>(xlb, as3, ad3, als, ald, N);
    attn_alpha<<<gW, 256, 0, stream>>>(als, ald, off, csr, alphaw, nself, ninv, N);
    gat_gather_ln<<<gW, 256, 0, stream>>>(xlb, xlh, alphaw, nself, ninv, off, csr, b3, g3, be3, hbuf, N);

    // ---- output layer ----
    out_proj<<<gW, 256, 0, stream>>>(hbuf, Wo, aso, ado, xlo, alsoB, aldoB, N);
    out_agg<<<gW, 256, 0, stream>>>(xlo, alsoB, aldoB, off, csr, bo, (float*)d_out, N);
}

// Round 5
// 442.902 us; speedup vs baseline: 1.8137x; 1.1245x over previous
//
#include <hip/hip_runtime.h>
#include <math.h>

#define HID 128
#define HEADS 4
#define NEG_SLOPE 0.2f
#define LN_EPS 1e-5f
#define BCAP 4096   // per-bucket capacity (avg 2046 for N=50K, E=800K)

typedef unsigned short ushortT;
typedef unsigned int uintT;

__device__ __forceinline__ float lrelu(float v) { return v > 0.f ? v : NEG_SLOPE * v; }

__device__ __forceinline__ ushortT f2bf(float f) {
    uintT u = __float_as_uint(f);
    u += 0x7fffu + ((u >> 16) & 1u);   // round-to-nearest-even
    return (ushortT)(u >> 16);
}

// ---------------- CSR build ----------------
__global__ __launch_bounds__(256) void count_k(const int* __restrict__ dst, int* __restrict__ cnt, int E) {
    int i = blockIdx.x * 256 + threadIdx.x;
    if (i < E) atomicAdd(&cnt[dst[i]], 1);
}

__global__ __launch_bounds__(256) void scan1_k(const int* __restrict__ cnt, int* __restrict__ off,
                                               int* __restrict__ blk, int Nn) {
    __shared__ int part[256];
    int t = threadIdx.x;
    int base = blockIdx.x * 1024 + t * 4;
    int v0 = base + 0 < Nn ? cnt[base + 0] : 0;
    int v1 = base + 1 < Nn ? cnt[base + 1] : 0;
    int v2 = base + 2 < Nn ? cnt[base + 2] : 0;
    int v3 = base + 3 < Nn ? cnt[base + 3] : 0;
    int s = v0 + v1 + v2 + v3;
    part[t] = s;
    __syncthreads();
    #pragma unroll
    for (int ofs = 1; ofs < 256; ofs <<= 1) {
        int p = (t >= ofs) ? part[t - ofs] : 0;
        __syncthreads();
        part[t] += p;
        __syncthreads();
    }
    int run = part[t] - s;
    if (base + 0 < Nn) off[base + 0] = run; run += v0;
    if (base + 1 < Nn) off[base + 1] = run; run += v1;
    if (base + 2 < Nn) off[base + 2] = run; run += v2;
    if (base + 3 < Nn) off[base + 3] = run;
    if (t == 255) blk[blockIdx.x] = part[255];
}

__global__ __launch_bounds__(64) void scan2_k(int* __restrict__ blk, int nblk) {
    int t = threadIdx.x;
    int v = t < nblk ? blk[t] : 0;
    int inc = v;
    #pragma unroll
    for (int ofs = 1; ofs < 64; ofs <<= 1) {
        int p = __shfl_up(inc, ofs, 64);
        if (t >= ofs) inc += p;
    }
    if (t < nblk) blk[t] = inc - v;
}

__global__ __launch_bounds__(256) void scan3_k(int* __restrict__ off, const int* __restrict__ blk, int Nn, int E) {
    int i = blockIdx.x * 256 + threadIdx.x;
    if (i < Nn) off[i] += blk[i >> 10];
    if (i == 0) off[Nn] = E;
}

// pass A: bin edges by dst>>7 into bucket buffer (LDS-aggregated, coalesced flush)
__global__ __launch_bounds__(256) void binA_k(const int* __restrict__ src, const int* __restrict__ dst,
                                              int* __restrict__ gcur, int2* __restrict__ buf, int E, int NB) {
    __shared__ int hist[512];
    __shared__ int bbase[512];
    __shared__ int lcur[512];
    int t = threadIdx.x;
    for (int i = t; i < NB; i += 256) { hist[i] = 0; lcur[i] = 0; }
    __syncthreads();
    int e0 = blockIdx.x * 4096;
    int2 ed[16];
    #pragma unroll
    for (int j = 0; j < 16; ++j) {
        int idx = e0 + j * 256 + t;
        if (idx < E) {
            ed[j].x = src[idx];
            ed[j].y = dst[idx];
            atomicAdd(&hist[ed[j].y >> 7], 1);
        } else {
            ed[j].y = -1;
        }
    }
    __syncthreads();
    for (int i = t; i < NB; i += 256) {
        int c = hist[i];
        bbase[i] = c > 0 ? atomicAdd(&gcur[i], c) : 0;
    }
    __syncthreads();
    #pragma unroll
    for (int j = 0; j < 16; ++j) {
        if (ed[j].y >= 0) {
            int b = ed[j].y >> 7;
            int pos = bbase[b] + atomicAdd(&lcur[b], 1);
            buf[(size_t)b * BCAP + pos] = ed[j];
        }
    }
}

// pass B: per-bucket scatter into csr (writes confined to ~16KB window -> L2-absorbed)
__global__ __launch_bounds__(256) void binB_k(const int2* __restrict__ buf, const int* __restrict__ gcnt,
                                              const int* __restrict__ off, int* __restrict__ csr) {
    __shared__ int lcur[128];
    int t = threadIdx.x, b = blockIdx.x;
    if (t < 128) lcur[t] = 0;
    __syncthreads();
    int nb = gcnt[b];
    int nodebase = b << 7;
    for (int i = t; i < nb; i += 256) {
        int2 e = buf[(size_t)b * BCAP + i];
        int p = off[e.y] + atomicAdd(&lcur[e.y - nodebase], 1);
        csr[p] = e.x;
    }
}

// ---------------- GEMM: C[M,128] = A[M,K] @ W[K,128] (+bias) + bf16 dual store + fused attn dots ----------------
template <int K>
__global__ __launch_bounds__(256) void gemm_k(const float* __restrict__ A, const float* __restrict__ W,
                                              const float* __restrict__ bias, float* __restrict__ C, int M,
                                              ushortT* __restrict__ Ch,
                                              const float* __restrict__ a_srcp, const float* __restrict__ a_dstp,
                                              float* __restrict__ als, float* __restrict__ ald) {
    __shared__ float Ws[32 * HID];
    __shared__ float As[32 * 36];
    int t = threadIdx.x;
    int row0 = blockIdx.x * 32;
    int r0 = (t >> 5) << 2;
    int c0 = (t & 31) << 2;
    float acc[4][4] = {};
    for (int k0 = 0; k0 < K; k0 += 32) {
        #pragma unroll
        for (int i = 0; i < 4; ++i) {
            int fid = t + i * 256;
            int kk = fid >> 5;
            int c = (fid & 31) << 2;
            *(float4*)&Ws[kk * HID + c] = *(const float4*)&W[(k0 + kk) * HID + c];
        }
        {
            int r = t >> 3;
            int kk0 = (t & 7) << 2;
            float4 a4 = make_float4(0.f, 0.f, 0.f, 0.f);
            if (row0 + r < M) a4 = *(const float4*)&A[(size_t)(row0 + r) * K + k0 + kk0];
            As[(kk0 + 0) * 36 + r] = a4.x;
            As[(kk0 + 1) * 36 + r] = a4.y;
            As[(kk0 + 2) * 36 + r] = a4.z;
            As[(kk0 + 3) * 36 + r] = a4.w;
        }
        __syncthreads();
        #pragma unroll
        for (int kk = 0; kk < 32; ++kk) {
            float4 a4 = *(const float4*)&As[kk * 36 + r0];
            float4 w4 = *(const float4*)&Ws[kk * HID + c0];
            float av[4] = {a4.x, a4.y, a4.z, a4.w};
            float wv[4] = {w4.x, w4.y, w4.z, w4.w};
            #pragma unroll
            for (int i = 0; i < 4; ++i)
                #pragma unroll
                for (int j = 0; j < 4; ++j)
                    acc[i][j] = fmaf(av[i], wv[j], acc[i][j]);
        }
        __syncthreads();
    }
    float4 b4 = make_float4(0.f, 0.f, 0.f, 0.f);
    if (bias) b4 = *(const float4*)&bias[c0];
    float4 as4 = make_float4(0.f, 0.f, 0.f, 0.f);
    float4 ad4 = make_float4(0.f, 0.f, 0.f, 0.f);
    if (als) {
        as4 = *(const float4*)&a_srcp[c0];   // a layout [4][32] flat == 128 floats, index == c0
        ad4 = *(const float4*)&a_dstp[c0];
    }
    int h = (t & 31) >> 3;
    #pragma unroll
    for (int i = 0; i < 4; ++i) {
        int r = row0 + r0 + i;
        float4 o;
        o.x = acc[i][0] + b4.x;
        o.y = acc[i][1] + b4.y;
        o.z = acc[i][2] + b4.z;
        o.w = acc[i][3] + b4.w;
        if (r < M) {
            *(float4*)&C[(size_t)r * HID + c0] = o;
            if (Ch) {
                ushort4 hv;
                hv.x = f2bf(o.x); hv.y = f2bf(o.y);
                hv.z = f2bf(o.z); hv.w = f2bf(o.w);
                *(ushort4*)&Ch[(size_t)r * HID + c0] = hv;
            }
        }
        if (als) {
            float ps = o.x * as4.x + o.y * as4.y + o.z * as4.z + o.w * as4.w;
            float pd = o.x * ad4.x + o.y * ad4.y + o.z * ad4.z + o.w * ad4.w;
            ps += __shfl_xor(ps, 1, 64); pd += __shfl_xor(pd, 1, 64);
            ps += __shfl_xor(ps, 2, 64); pd += __shfl_xor(pd, 2, 64);
            ps += __shfl_xor(ps, 4, 64); pd += __shfl_xor(pd, 4, 64);
            if ((t & 7) == 0 && r < M) {
                als[r * 4 + h] = ps;
                ald[r * 4 + h] = pd;
            }
        }
    }
}

// ---------------- softmax weights ----------------
__global__ __launch_bounds__(256) void attn_alpha(const float* __restrict__ als, const float* __restrict__ ald,
                                                  const int* __restrict__ off, const int* __restrict__ csr,
                                                  float* __restrict__ alphaw, float* __restrict__ nself,
                                                  float* __restrict__ ninv, int Nn) {
    int gid = blockIdx.x * 256 + threadIdx.x;
    int wid = gid >> 6, lane = threadIdx.x & 63;
    if (wid >= Nn) return;
    float4 aldn = *(const float4*)&ald[wid * 4];
    float4 alsn = *(const float4*)&als[wid * 4];
    float e0 = lrelu(alsn.x + aldn.x);
    float e1 = lrelu(alsn.y + aldn.y);
    float e2 = lrelu(alsn.z + aldn.z);
    float e3 = lrelu(alsn.w + aldn.w);
    float m0 = e0, m1 = e1, m2 = e2, m3 = e3;
    int b = off[wid], e = off[wid + 1];
    for (int c = b; c < e; c += 64) {
        int j = c + lane;
        bool v = j < e;
        int s = v ? csr[j] : 0;
        float4 a4 = *(const float4*)&als[(size_t)s * 4];
        float t0 = v ? lrelu(a4.x + aldn.x) : -INFINITY;
        float t1 = v ? lrelu(a4.y + aldn.y) : -INFINITY;
        float t2 = v ? lrelu(a4.z + aldn.z) : -INFINITY;
        float t3 = v ? lrelu(a4.w + aldn.w) : -INFINITY;
        m0 = fmaxf(m0, t0); m1 = fmaxf(m1, t1);
        m2 = fmaxf(m2, t2); m3 = fmaxf(m3, t3);
    }
    #pragma unroll
    for (int d = 1; d < 64; d <<= 1) {
        m0 = fmaxf(m0, __shfl_xor(m0, d, 64));
        m1 = fmaxf(m1, __shfl_xor(m1, d, 64));
        m2 = fmaxf(m2, __shfl_xor(m2, d, 64));
        m3 = fmaxf(m3, __shfl_xor(m3, d, 64));
    }
    float d0 = 0.f, d1 = 0.f, d2 = 0.f, d3 = 0.f;
    for (int c = b; c < e; c += 64) {
        int j = c + lane;
        bool v = j < e;
        int s = v ? csr[j] : 0;
        float4 a4 = *(const float4*)&als[(size_t)s * 4];
        float w0 = v ? __expf(lrelu(a4.x + aldn.x) - m0) : 0.f;
        float w1 = v ? __expf(lrelu(a4.y + aldn.y) - m1) : 0.f;
        float w2 = v ? __expf(lrelu(a4.z + aldn.z) - m2) : 0.f;
        float w3 = v ? __expf(lrelu(a4.w + aldn.w) - m3) : 0.f;
        if (v) *(float4*)&alphaw[(size_t)j * 4] = make_float4(w0, w1, w2, w3);
        d0 += w0; d1 += w1; d2 += w2; d3 += w3;
    }
    #pragma unroll
    for (int d = 1; d < 64; d <<= 1) {
        d0 += __shfl_xor(d0, d, 64);
        d1 += __shfl_xor(d1, d, 64);
        d2 += __shfl_xor(d2, d, 64);
        d3 += __shfl_xor(d3, d, 64);
    }
    if (lane == 0) {
        float ws0 = __expf(e0 - m0), ws1 = __expf(e1 - m1);
        float ws2 = __expf(e2 - m2), ws3 = __expf(e3 - m3);
        float i0 = 1.f / (d0 + ws0 + 1e-16f);
        float i1 = 1.f / (d1 + ws1 + 1e-16f);
        float i2 = 1.f / (d2 + ws2 + 1e-16f);
        float i3 = 1.f / (d3 + ws3 + 1e-16f);
        *(float4*)&nself[wid * 4] = make_float4(ws0 * i0, ws1 * i1, ws2 * i2, ws3 * i3);
        *(float4*)&ninv[wid * 4] = make_float4(i0, i1, i2, i3);
    }
}

// ---------------- fused gather (bf16 src rows) + LayerNorm + ReLU + residual ----------------
__global__ __launch_bounds__(256) void gat_gather_ln(
        const float* __restrict__ xl, const ushortT* __restrict__ xlh,
        const float* __restrict__ alphaw, const float* __restrict__ nself,
        const float* __restrict__ ninv, const int* __restrict__ off,
        const int* __restrict__ csr, const float* __restrict__ bias,
        const float* __restrict__ g, const float* __restrict__ be,
        float* __restrict__ hres, int Nn) {
    int gid = blockIdx.x * 256 + threadIdx.x;
    int wid = gid >> 6, lane = threadIdx.x & 63;
    if (wid >= Nn) return;
    int q = lane >> 4;
    int cl = lane & 15;
    int h = cl >> 2;
    int b = off[wid], e = off[wid + 1];
    float acc[8] = {};
    for (int c = b + q; c < e; c += 4) {
        int s = csr[c];
        float w = alphaw[(size_t)c * 4 + h];
        uint4 hv = *(const uint4*)&xlh[(size_t)s * HID + cl * 8];
        acc[0] = fmaf(w, __uint_as_float(hv.x << 16), acc[0]);
        acc[1] = fmaf(w, __uint_as_float(hv.x & 0xffff0000u), acc[1]);
        acc[2] = fmaf(w, __uint_as_float(hv.y << 16), acc[2]);
        acc[3] = fmaf(w, __uint_as_float(hv.y & 0xffff0000u), acc[3]);
        acc[4] = fmaf(w, __uint_as_float(hv.z << 16), acc[4]);
        acc[5] = fmaf(w, __uint_as_float(hv.z & 0xffff0000u), acc[5]);
        acc[6] = fmaf(w, __uint_as_float(hv.w << 16), acc[6]);
        acc[7] = fmaf(w, __uint_as_float(hv.w & 0xffff0000u), acc[7]);
    }
    #pragma unroll
    for (int k = 0; k < 8; ++k) {
        acc[k] += __shfl_xor(acc[k], 16, 64);
        acc[k] += __shfl_xor(acc[k], 32, 64);
    }
    float inv = ninv[wid * 4 + h];
    float sa = nself[wid * 4 + h];
    float4 xv0 = *(const float4*)&xl[(size_t)wid * HID + cl * 8];
    float4 xv1 = *(const float4*)&xl[(size_t)wid * HID + cl * 8 + 4];
    float4 bi0 = *(const float4*)&bias[cl * 8];
    float4 bi1 = *(const float4*)&bias[cl * 8 + 4];
    float o[8];
    o[0] = fmaf(acc[0], inv, fmaf(sa, xv0.x, bi0.x));
    o[1] = fmaf(acc[1], inv, fmaf(sa, xv0.y, bi0.y));
    o[2] = fmaf(acc[2], inv, fmaf(sa, xv0.z, bi0.z));
    o[3] = fmaf(acc[3], inv, fmaf(sa, xv0.w, bi0.w));
    o[4] = fmaf(acc[4], inv, fmaf(sa, xv1.x, bi1.x));
    o[5] = fmaf(acc[5], inv, fmaf(sa, xv1.y, bi1.y));
    o[6] = fmaf(acc[6], inv, fmaf(sa, xv1.z, bi1.z));
    o[7] = fmaf(acc[7], inv, fmaf(sa, xv1.w, bi1.w));
    float s1 = o[0] + o[1] + o[2] + o[3] + o[4] + o[5] + o[6] + o[7];
    #pragma unroll
    for (int m = 1; m < 16; m <<= 1) s1 += __shfl_xor(s1, m, 64);
    float mu = s1 * (1.0f / HID);
    float qv = 0.f;
    #pragma unroll
    for (int k = 0; k < 8; ++k) { float d = o[k] - mu; qv += d * d; }
    #pragma unroll
    for (int m = 1; m < 16; m <<= 1) qv += __shfl_xor(qv, m, 64);
    float rs = rsqrtf(qv * (1.0f / HID) + LN_EPS);
    if (q == 0) {
        float4 g0 = *(const float4*)&g[cl * 8];
        float4 g1 = *(const float4*)&g[cl * 8 + 4];
        float4 e0 = *(const float4*)&be[cl * 8];
        float4 e1 = *(const float4*)&be[cl * 8 + 4];
        float4 r0 = *(const float4*)&hres[(size_t)wid * HID + cl * 8];
        float4 r1 = *(const float4*)&hres[(size_t)wid * HID + cl * 8 + 4];
        float4 w0, w1;
        w0.x = fmaxf((o[0] - mu) * rs * g0.x + e0.x, 0.f) + r0.x;
        w0.y = fmaxf((o[1] - mu) * rs * g0.y + e0.y, 0.f) + r0.y;
        w0.z = fmaxf((o[2] - mu) * rs * g0.z + e0.z, 0.f) + r0.z;
        w0.w = fmaxf((o[3] - mu) * rs * g0.w + e0.w, 0.f) + r0.w;
        w1.x = fmaxf((o[4] - mu) * rs * g1.x + e1.x, 0.f) + r1.x;
        w1.y = fmaxf((o[5] - mu) * rs * g1.y + e1.y, 0.f) + r1.y;
        w1.z = fmaxf((o[6] - mu) * rs * g1.z + e1.z, 0.f) + r1.z;
        w1.w = fmaxf((o[7] - mu) * rs * g1.w + e1.w, 0.f) + r1.w;
        *(float4*)&hres[(size_t)wid * HID + cl * 8] = w0;
        *(float4*)&hres[(size_t)wid * HID + cl * 8 + 4] = w1;
    }
}

// ---------------- output projection ----------------
__global__ __launch_bounds__(256) void out_proj(const float* __restrict__ h, const float* __restrict__ Wo,
                                                const float* __restrict__ aso, const float* __restrict__ ado,
                                                float* __restrict__ xlo, float* __restrict__ also,
                                                float* __restrict__ aldo, int Nn) {
    int gid = blockIdx.x * 256 + threadIdx.x;
    int wid = gid >> 6, lane = threadIdx.x & 63;
    if (wid >= Nn) return;
    float2 v = *(const float2*)&h[(size_t)wid * HID + 2 * lane];
    float2 w0 = *(const float2*)&Wo[(2 * lane) * 2];
    float2 w1 = *(const float2*)&Wo[(2 * lane + 1) * 2];
    float p0 = v.x * w0.x + v.y * w1.x;
    float p1 = v.x * w0.y + v.y * w1.y;
    #pragma unroll
    for (int m = 1; m < 64; m <<= 1) {
        p0 += __shfl_xor(p0, m, 64);
        p1 += __shfl_xor(p1, m, 64);
    }
    if (lane == 0) {
        xlo[wid * 2 + 0] = p0;
        xlo[wid * 2 + 1] = p1;
        also[wid] = p0 * aso[0] + p1 * aso[1];
        aldo[wid] = p0 * ado[0] + p1 * ado[1];
    }
}

// ---------------- output aggregation ----------------
__global__ __launch_bounds__(256) void out_agg(const float* __restrict__ xlo, const float* __restrict__ also,
                                               const float* __restrict__ aldo, const int* __restrict__ off,
                                               const int* __restrict__ csr, const float* __restrict__ bo,
                                               float* __restrict__ out, int Nn) {
    int gid = blockIdx.x * 256 + threadIdx.x;
    int wid = gid >> 6, lane = threadIdx.x & 63;
    if (wid >= Nn) return;
    float aldn = aldo[wid];
    float eself = lrelu(also[wid] + aldn);
    int b = off[wid], e = off[wid + 1];
    float mloc = -INFINITY;
    for (int j = b + lane; j < e; j += 64)
        mloc = fmaxf(mloc, lrelu(also[csr[j]] + aldn));
    #pragma unroll
    for (int m = 1; m < 64; m <<= 1) mloc = fmaxf(mloc, __shfl_xor(mloc, m, 64));
    float mm = fmaxf(mloc, eself);
    float dl = 0.f, a0 = 0.f, a1 = 0.f;
    for (int j = b + lane; j < e; j += 64) {
        int s = csr[j];
        float w = __expf(lrelu(also[s] + aldn) - mm);
        dl += w;
        a0 += w * xlo[s * 2 + 0];
        a1 += w * xlo[s * 2 + 1];
    }
    #pragma unroll
    for (int m = 1; m < 64; m <<= 1) {
        dl += __shfl_xor(dl, m, 64);
        a0 += __shfl_xor(a0, m, 64);
        a1 += __shfl_xor(a1, m, 64);
    }
    if (lane == 0) {
        float wsf = __expf(eself - mm);
        dl += wsf;
        a0 += wsf * xlo[wid * 2 + 0];
        a1 += wsf * xlo[wid * 2 + 1];
        float inv = 1.f / (dl + 1e-16f);
        out[wid * 2 + 0] = a0 * inv + bo[0];
        out[wid * 2 + 1] = a1 * inv + bo[1];
    }
}

extern "C" void kernel_launch(void* const* d_in, const int* in_sizes, int n_in,
                              void* d_out, int out_size, void* d_ws, size_t ws_size,
                              hipStream_t stream) {
    const float* x   = (const float*)d_in[0];
    const int*   ei  = (const int*)d_in[1];
    const float* W1  = (const float*)d_in[2];
    const float* as1 = (const float*)d_in[3];
    const float* ad1 = (const float*)d_in[4];
    const float* b1  = (const float*)d_in[5];
    const float* g1  = (const float*)d_in[6];
    const float* be1 = (const float*)d_in[7];
    const float* rw  = (const float*)d_in[8];
    const float* rb  = (const float*)d_in[9];
    const float* W2  = (const float*)d_in[10];
    const float* as2 = (const float*)d_in[11];
    const float* ad2 = (const float*)d_in[12];
    const float* b2  = (const float*)d_in[13];
    const float* g2  = (const float*)d_in[14];
    const float* be2 = (const float*)d_in[15];
    const float* W3  = (const float*)d_in[16];
    const float* as3 = (const float*)d_in[17];
    const float* ad3 = (const float*)d_in[18];
    const float* b3  = (const float*)d_in[19];
    const float* g3  = (const float*)d_in[20];
    const float* be3 = (const float*)d_in[21];
    const float* Wo  = (const float*)d_in[22];
    const float* aso = (const float*)d_in[23];
    const float* ado = (const float*)d_in[24];
    const float* bo  = (const float*)d_in[25];

    int N = in_sizes[0] / 64;   // 50000
    int E = in_sizes[1] / 2;    // 800000
    const int* srcE = ei;
    const int* dstE = ei + E;
    int NB = (N + 127) >> 7;    // 391 buckets

    char* w = (char*)d_ws;
    auto alloc = [&](size_t b) { char* p = w; w += (b + 255) & ~(size_t)255; return p; };
    int* cnt    = (int*)alloc((size_t)N * 4);
    int* off    = (int*)alloc((size_t)(N + 1) * 4);
    int* gcur   = (int*)alloc((size_t)NB * 4);
    int* blk    = (int*)alloc(((size_t)N / 1024 + 2) * 4);
    int* csr    = (int*)alloc((size_t)E * 4);
    int2* bbuf  = (int2*)alloc((size_t)NB * BCAP * 8);
    float* hbuf = (float*)alloc((size_t)N * HID * 4);
    float* xlb  = (float*)alloc((size_t)N * HID * 4);
    ushortT* xlh = (ushortT*)alloc((size_t)N * HID * 2);
    float* als  = (float*)alloc((size_t)N * HEADS * 4);
    float* ald  = (float*)alloc((size_t)N * HEADS * 4);
    float* alphaw = (float*)alloc((size_t)E * HEADS * 4);
    float* nself  = (float*)alloc((size_t)N * HEADS * 4);
    float* ninv   = (float*)alloc((size_t)N * HEADS * 4);
    float* xlo  = (float*)alloc((size_t)N * 2 * 4);
    float* alsoB = (float*)alloc((size_t)N * 4);
    float* aldoB = (float*)alloc((size_t)N * 4);

    hipMemsetAsync(cnt, 0, (size_t)N * 4, stream);
    hipMemsetAsync(gcur, 0, (size_t)NB * 4, stream);
    int gE = (E + 255) / 256;
    int nblk = (N + 1023) / 1024;
    count_k<<<gE, 256, 0, stream>>>(dstE, cnt, E);
    scan1_k<<<nblk, 256, 0, stream>>>(cnt, off, blk, N);
    scan2_k<<<1, 64, 0, stream>>>(blk, nblk);
    scan3_k<<<(N + 256) / 256, 256, 0, stream>>>(off, blk, N, E);
    binA_k<<<(E + 4095) / 4096, 256, 0, stream>>>(srcE, dstE, gcur, bbuf, E, NB);
    binB_k<<<NB, 256, 0, stream>>>(bbuf, gcur, off, csr);

    int gM = (N + 31) / 32;
    int gW = (N + 3) / 4;

    // residual projection: hbuf = x @ rw + rb
    gemm_k<64><<<gM, 256, 0, stream>>>(x, rw, rb, hbuf, N, nullptr, nullptr, nullptr, nullptr, nullptr);

    // ---- layer 1 ----
    gemm_k<64><<<gM, 256, 0, stream>>>(x, W1, nullptr, xlb, N, xlh, as1, ad1, als, ald);
    attn_alpha<<<gW, 256, 0, stream>>>(als, ald, off, csr, alphaw, nself, ninv, N);
    gat_gather_ln<<<gW, 256, 0, stream>>>(xlb, xlh, alphaw, nself, ninv, off, csr, b1, g1, be1, hbuf, N);

    // ---- layer 2 ----
    gemm_k<128><<<gM, 256, 0, stream>>>(hbuf, W2, nullptr, xlb, N, xlh, as2, ad2, als, ald);
    attn_alpha<<<gW, 256, 0, stream>>>(als, ald, off, csr, alphaw, nself, ninv, N);
    gat_gather_ln<<<gW, 256, 0, stream>>>(xlb, xlh, alphaw, nself, ninv, off, csr, b2, g2, be2, hbuf, N);

    // ---- layer 3 ----
    gemm_k<128><<<gM, 256, 0, stream>>>(hbuf, W3, nullptr, xlb, N, xlh, as3, ad3, als, ald);
    attn_alpha<<<gW, 256, 0, stream>>>(als, ald, off, csr, alphaw, nself, ninv, N);
    gat_gather_ln<<<gW, 256, 0, stream>>>(xlb, xlh, alphaw, nself, ninv, off, csr, b3, g3, be3, hbuf, N);

    // ---- output layer ----
    out_proj<<<gW, 256, 0, stream>>>(hbuf, Wo, aso, ado, xlo, alsoB, aldoB, N);
    out_agg<<<gW, 256, 0, stream>>>(xlo, alsoB, aldoB, off, csr, bo, (float*)d_out, N);
}

// Round 6
// 366.021 us; speedup vs baseline: 2.1947x; 1.2100x over previous
//
#include <hip/hip_runtime.h>
#include <math.h>

#define HID 128
#define HEADS 4
#define NEG_SLOPE 0.2f
#define LN_EPS 1e-5f
#define BCAP 4096   // per-bucket capacity (avg 2046 for N=50K, E=800K)

typedef unsigned short ushortT;
typedef unsigned int uintT;

__device__ __forceinline__ float lrelu(float v) { return v > 0.f ? v : NEG_SLOPE * v; }

__device__ __forceinline__ ushortT f2bf(float f) {
    uintT u = __float_as_uint(f);
    u += 0x7fffu + ((u >> 16) & 1u);   // round-to-nearest-even
    return (ushortT)(u >> 16);
}

// ---------------- CSR build ----------------
__global__ __launch_bounds__(256) void count_k(const int* __restrict__ dst, int* __restrict__ cnt, int E) {
    int i = blockIdx.x * 256 + threadIdx.x;
    if (i < E) atomicAdd(&cnt[dst[i]], 1);
}

__global__ __launch_bounds__(256) void scan1_k(const int* __restrict__ cnt, int* __restrict__ off,
                                               int* __restrict__ blk, int Nn) {
    __shared__ int part[256];
    int t = threadIdx.x;
    int base = blockIdx.x * 1024 + t * 4;
    int v0 = base + 0 < Nn ? cnt[base + 0] : 0;
    int v1 = base + 1 < Nn ? cnt[base + 1] : 0;
    int v2 = base + 2 < Nn ? cnt[base + 2] : 0;
    int v3 = base + 3 < Nn ? cnt[base + 3] : 0;
    int s = v0 + v1 + v2 + v3;
    part[t] = s;
    __syncthreads();
    #pragma unroll
    for (int ofs = 1; ofs < 256; ofs <<= 1) {
        int p = (t >= ofs) ? part[t - ofs] : 0;
        __syncthreads();
        part[t] += p;
        __syncthreads();
    }
    int run = part[t] - s;
    if (base + 0 < Nn) off[base + 0] = run; run += v0;
    if (base + 1 < Nn) off[base + 1] = run; run += v1;
    if (base + 2 < Nn) off[base + 2] = run; run += v2;
    if (base + 3 < Nn) off[base + 3] = run;
    if (t == 255) blk[blockIdx.x] = part[255];
}

__global__ __launch_bounds__(64) void scan2_k(int* __restrict__ blk, int nblk) {
    int t = threadIdx.x;
    int v = t < nblk ? blk[t] : 0;
    int inc = v;
    #pragma unroll
    for (int ofs = 1; ofs < 64; ofs <<= 1) {
        int p = __shfl_up(inc, ofs, 64);
        if (t >= ofs) inc += p;
    }
    if (t < nblk) blk[t] = inc - v;
}

__global__ __launch_bounds__(256) void scan3_k(int* __restrict__ off, const int* __restrict__ blk, int Nn, int E) {
    int i = blockIdx.x * 256 + threadIdx.x;
    if (i < Nn) off[i] += blk[i >> 10];
    if (i == 0) off[Nn] = E;
}

// pass A: bin edges by dst>>7 into bucket buffer (LDS-aggregated, coalesced flush)
__global__ __launch_bounds__(256) void binA_k(const int* __restrict__ src, const int* __restrict__ dst,
                                              int* __restrict__ gcur, int2* __restrict__ buf, int E, int NB) {
    __shared__ int hist[512];
    __shared__ int bbase[512];
    __shared__ int lcur[512];
    int t = threadIdx.x;
    for (int i = t; i < NB; i += 256) { hist[i] = 0; lcur[i] = 0; }
    __syncthreads();
    int e0 = blockIdx.x * 4096;
    int2 ed[16];
    #pragma unroll
    for (int j = 0; j < 16; ++j) {
        int idx = e0 + j * 256 + t;
        if (idx < E) {
            ed[j].x = src[idx];
            ed[j].y = dst[idx];
            atomicAdd(&hist[ed[j].y >> 7], 1);
        } else {
            ed[j].y = -1;
        }
    }
    __syncthreads();
    for (int i = t; i < NB; i += 256) {
        int c = hist[i];
        bbase[i] = c > 0 ? atomicAdd(&gcur[i], c) : 0;
    }
    __syncthreads();
    #pragma unroll
    for (int j = 0; j < 16; ++j) {
        if (ed[j].y >= 0) {
            int b = ed[j].y >> 7;
            int pos = bbase[b] + atomicAdd(&lcur[b], 1);
            buf[(size_t)b * BCAP + pos] = ed[j];
        }
    }
}

// pass B: per-bucket scatter into csr (writes confined to ~16KB window -> L2-absorbed)
__global__ __launch_bounds__(256) void binB_k(const int2* __restrict__ buf, const int* __restrict__ gcnt,
                                              const int* __restrict__ off, int* __restrict__ csr) {
    __shared__ int lcur[128];
    int t = threadIdx.x, b = blockIdx.x;
    if (t < 128) lcur[t] = 0;
    __syncthreads();
    int nb = gcnt[b];
    int nodebase = b << 7;
    for (int i = t; i < nb; i += 256) {
        int2 e = buf[(size_t)b * BCAP + i];
        int p = off[e.y] + atomicAdd(&lcur[e.y - nodebase], 1);
        csr[p] = e.x;
    }
}

// ---------------- GEMM: [M,K]x[K,128]; optional fp32 C, optional bf16 Ch, optional fused attn dots ----------------
template <int K>
__global__ __launch_bounds__(256) void gemm_k(const float* __restrict__ A, const float* __restrict__ W,
                                              const float* __restrict__ bias, float* __restrict__ C, int M,
                                              ushortT* __restrict__ Ch,
                                              const float* __restrict__ a_srcp, const float* __restrict__ a_dstp,
                                              float* __restrict__ als, float* __restrict__ ald) {
    __shared__ float Ws[32 * HID];
    __shared__ float As[32 * 36];
    int t = threadIdx.x;
    int row0 = blockIdx.x * 32;
    int r0 = (t >> 5) << 2;
    int c0 = (t & 31) << 2;
    float acc[4][4] = {};
    for (int k0 = 0; k0 < K; k0 += 32) {
        #pragma unroll
        for (int i = 0; i < 4; ++i) {
            int fid = t + i * 256;
            int kk = fid >> 5;
            int c = (fid & 31) << 2;
            *(float4*)&Ws[kk * HID + c] = *(const float4*)&W[(k0 + kk) * HID + c];
        }
        {
            int r = t >> 3;
            int kk0 = (t & 7) << 2;
            float4 a4 = make_float4(0.f, 0.f, 0.f, 0.f);
            if (row0 + r < M) a4 = *(const float4*)&A[(size_t)(row0 + r) * K + k0 + kk0];
            As[(kk0 + 0) * 36 + r] = a4.x;
            As[(kk0 + 1) * 36 + r] = a4.y;
            As[(kk0 + 2) * 36 + r] = a4.z;
            As[(kk0 + 3) * 36 + r] = a4.w;
        }
        __syncthreads();
        #pragma unroll
        for (int kk = 0; kk < 32; ++kk) {
            float4 a4 = *(const float4*)&As[kk * 36 + r0];
            float4 w4 = *(const float4*)&Ws[kk * HID + c0];
            float av[4] = {a4.x, a4.y, a4.z, a4.w};
            float wv[4] = {w4.x, w4.y, w4.z, w4.w};
            #pragma unroll
            for (int i = 0; i < 4; ++i)
                #pragma unroll
                for (int j = 0; j < 4; ++j)
                    acc[i][j] = fmaf(av[i], wv[j], acc[i][j]);
        }
        __syncthreads();
    }
    float4 b4 = make_float4(0.f, 0.f, 0.f, 0.f);
    if (bias) b4 = *(const float4*)&bias[c0];
    float4 as4 = make_float4(0.f, 0.f, 0.f, 0.f);
    float4 ad4 = make_float4(0.f, 0.f, 0.f, 0.f);
    if (als) {
        as4 = *(const float4*)&a_srcp[c0];   // a layout [4][32] flat == 128 floats
        ad4 = *(const float4*)&a_dstp[c0];
    }
    int h = (t & 31) >> 3;
    #pragma unroll
    for (int i = 0; i < 4; ++i) {
        int r = row0 + r0 + i;
        float4 o;
        o.x = acc[i][0] + b4.x;
        o.y = acc[i][1] + b4.y;
        o.z = acc[i][2] + b4.z;
        o.w = acc[i][3] + b4.w;
        if (r < M) {
            if (C) *(float4*)&C[(size_t)r * HID + c0] = o;
            if (Ch) {
                ushort4 hv;
                hv.x = f2bf(o.x); hv.y = f2bf(o.y);
                hv.z = f2bf(o.z); hv.w = f2bf(o.w);
                *(ushort4*)&Ch[(size_t)r * HID + c0] = hv;
            }
        }
        if (als) {
            float ps = o.x * as4.x + o.y * as4.y + o.z * as4.z + o.w * as4.w;
            float pd = o.x * ad4.x + o.y * ad4.y + o.z * ad4.z + o.w * ad4.w;
            ps += __shfl_xor(ps, 1, 64); pd += __shfl_xor(pd, 1, 64);
            ps += __shfl_xor(ps, 2, 64); pd += __shfl_xor(pd, 2, 64);
            ps += __shfl_xor(ps, 4, 64); pd += __shfl_xor(pd, 4, 64);
            if ((t & 7) == 0 && r < M) {
                als[r * 4 + h] = ps;
                ald[r * 4 + h] = pd;
            }
        }
    }
}

// ---------------- fully fused GAT: max pass + online softmax gather + LN + ReLU + residual ----------------
// wave/node; max pass uses all 64 lanes; gather: 4 edges in flight x 16 lanes (bf16x8 each)
__global__ __launch_bounds__(256) void gat_fused(
        const ushortT* __restrict__ xlh, const float* __restrict__ als,
        const float* __restrict__ ald, const int* __restrict__ off,
        const int* __restrict__ csr, const float* __restrict__ bias,
        const float* __restrict__ g, const float* __restrict__ be,
        float* __restrict__ hres, int Nn) {
    int gid = blockIdx.x * 256 + threadIdx.x;
    int wid = gid >> 6, lane = threadIdx.x & 63;
    if (wid >= Nn) return;
    int q = lane >> 4;
    int cl = lane & 15;
    int h = cl >> 2;
    float4 aldn = *(const float4*)&ald[wid * 4];
    float4 alsn = *(const float4*)&als[wid * 4];
    float e0 = lrelu(alsn.x + aldn.x);
    float e1 = lrelu(alsn.y + aldn.y);
    float e2 = lrelu(alsn.z + aldn.z);
    float e3 = lrelu(alsn.w + aldn.w);
    int b = off[wid], e = off[wid + 1];
    // pass 1: per-head max over in-edges (als table is L2-resident)
    float m0 = e0, m1 = e1, m2 = e2, m3 = e3;
    for (int c = b + lane; c < e; c += 64) {
        int s = csr[c];
        float4 a4 = *(const float4*)&als[(size_t)s * 4];
        m0 = fmaxf(m0, lrelu(a4.x + aldn.x));
        m1 = fmaxf(m1, lrelu(a4.y + aldn.y));
        m2 = fmaxf(m2, lrelu(a4.z + aldn.z));
        m3 = fmaxf(m3, lrelu(a4.w + aldn.w));
    }
    #pragma unroll
    for (int d = 1; d < 64; d <<= 1) {
        m0 = fmaxf(m0, __shfl_xor(m0, d, 64));
        m1 = fmaxf(m1, __shfl_xor(m1, d, 64));
        m2 = fmaxf(m2, __shfl_xor(m2, d, 64));
        m3 = fmaxf(m3, __shfl_xor(m3, d, 64));
    }
    float mh   = h == 0 ? m0 : h == 1 ? m1 : h == 2 ? m2 : m3;
    float aldh = h == 0 ? aldn.x : h == 1 ? aldn.y : h == 2 ? aldn.z : aldn.w;
    float eh   = h == 0 ? e0 : h == 1 ? e1 : h == 2 ? e2 : e3;
    // pass 2: gather with online weight + denominator
    float acc[8] = {};
    float dsum = 0.f;
    for (int c = b + q; c < e; c += 4) {
        int s = csr[c];
        float w = __expf(lrelu(als[(size_t)s * 4 + h] + aldh) - mh);
        dsum += w;
        uint4 hv = *(const uint4*)&xlh[(size_t)s * HID + cl * 8];
        acc[0] = fmaf(w, __uint_as_float(hv.x << 16), acc[0]);
        acc[1] = fmaf(w, __uint_as_float(hv.x & 0xffff0000u), acc[1]);
        acc[2] = fmaf(w, __uint_as_float(hv.y << 16), acc[2]);
        acc[3] = fmaf(w, __uint_as_float(hv.y & 0xffff0000u), acc[3]);
        acc[4] = fmaf(w, __uint_as_float(hv.z << 16), acc[4]);
        acc[5] = fmaf(w, __uint_as_float(hv.z & 0xffff0000u), acc[5]);
        acc[6] = fmaf(w, __uint_as_float(hv.w << 16), acc[6]);
        acc[7] = fmaf(w, __uint_as_float(hv.w & 0xffff0000u), acc[7]);
    }
    #pragma unroll
    for (int k = 0; k < 8; ++k) {
        acc[k] += __shfl_xor(acc[k], 16, 64);
        acc[k] += __shfl_xor(acc[k], 32, 64);
    }
    dsum += __shfl_xor(dsum, 16, 64);
    dsum += __shfl_xor(dsum, 32, 64);
    float wself = __expf(eh - mh);
    float inv = 1.f / (dsum + wself + 1e-16f);
    // self row (bf16)
    uint4 sv = *(const uint4*)&xlh[(size_t)wid * HID + cl * 8];
    float sx[8];
    sx[0] = __uint_as_float(sv.x << 16);
    sx[1] = __uint_as_float(sv.x & 0xffff0000u);
    sx[2] = __uint_as_float(sv.y << 16);
    sx[3] = __uint_as_float(sv.y & 0xffff0000u);
    sx[4] = __uint_as_float(sv.z << 16);
    sx[5] = __uint_as_float(sv.z & 0xffff0000u);
    sx[6] = __uint_as_float(sv.w << 16);
    sx[7] = __uint_as_float(sv.w & 0xffff0000u);
    float4 bi0 = *(const float4*)&bias[cl * 8];
    float4 bi1 = *(const float4*)&bias[cl * 8 + 4];
    float o[8];
    o[0] = fmaf(acc[0] + wself * sx[0], inv, bi0.x);
    o[1] = fmaf(acc[1] + wself * sx[1], inv, bi0.y);
    o[2] = fmaf(acc[2] + wself * sx[2], inv, bi0.z);
    o[3] = fmaf(acc[3] + wself * sx[3], inv, bi0.w);
    o[4] = fmaf(acc[4] + wself * sx[4], inv, bi1.x);
    o[5] = fmaf(acc[5] + wself * sx[5], inv, bi1.y);
    o[6] = fmaf(acc[6] + wself * sx[6], inv, bi1.z);
    o[7] = fmaf(acc[7] + wself * sx[7], inv, bi1.w);
    // LayerNorm over the 128-ch row (reduce over cl bits; q copies identical)
    float s1 = o[0] + o[1] + o[2] + o[3] + o[4] + o[5] + o[6] + o[7];
    #pragma unroll
    for (int m = 1; m < 16; m <<= 1) s1 += __shfl_xor(s1, m, 64);
    float mu = s1 * (1.0f / HID);
    float qv = 0.f;
    #pragma unroll
    for (int k = 0; k < 8; ++k) { float d = o[k] - mu; qv += d * d; }
    #pragma unroll
    for (int m = 1; m < 16; m <<= 1) qv += __shfl_xor(qv, m, 64);
    float rs = rsqrtf(qv * (1.0f / HID) + LN_EPS);
    if (q == 0) {
        float4 g0 = *(const float4*)&g[cl * 8];
        float4 g1 = *(const float4*)&g[cl * 8 + 4];
        float4 be0 = *(const float4*)&be[cl * 8];
        float4 be1 = *(const float4*)&be[cl * 8 + 4];
        float4 r0 = *(const float4*)&hres[(size_t)wid * HID + cl * 8];
        float4 r1 = *(const float4*)&hres[(size_t)wid * HID + cl * 8 + 4];
        float4 w0, w1;
        w0.x = fmaxf((o[0] - mu) * rs * g0.x + be0.x, 0.f) + r0.x;
        w0.y = fmaxf((o[1] - mu) * rs * g0.y + be0.y, 0.f) + r0.y;
        w0.z = fmaxf((o[2] - mu) * rs * g0.z + be0.z, 0.f) + r0.z;
        w0.w = fmaxf((o[3] - mu) * rs * g0.w + be0.w, 0.f) + r0.w;
        w1.x = fmaxf((o[4] - mu) * rs * g1.x + be1.x, 0.f) + r1.x;
        w1.y = fmaxf((o[5] - mu) * rs * g1.y + be1.y, 0.f) + r1.y;
        w1.z = fmaxf((o[6] - mu) * rs * g1.z + be1.z, 0.f) + r1.z;
        w1.w = fmaxf((o[7] - mu) * rs * g1.w + be1.w, 0.f) + r1.w;
        *(float4*)&hres[(size_t)wid * HID + cl * 8] = w0;
        *(float4*)&hres[(size_t)wid * HID + cl * 8 + 4] = w1;
    }
}

// ---------------- output projection ----------------
__global__ __launch_bounds__(256) void out_proj(const float* __restrict__ h, const float* __restrict__ Wo,
                                                const float* __restrict__ aso, const float* __restrict__ ado,
                                                float* __restrict__ xlo, float* __restrict__ also,
                                                float* __restrict__ aldo, int Nn) {
    int gid = blockIdx.x * 256 + threadIdx.x;
    int wid = gid >> 6, lane = threadIdx.x & 63;
    if (wid >= Nn) return;
    float2 v = *(const float2*)&h[(size_t)wid * HID + 2 * lane];
    float2 w0 = *(const float2*)&Wo[(2 * lane) * 2];
    float2 w1 = *(const float2*)&Wo[(2 * lane + 1) * 2];
    float p0 = v.x * w0.x + v.y * w1.x;
    float p1 = v.x * w0.y + v.y * w1.y;
    #pragma unroll
    for (int m = 1; m < 64; m <<= 1) {
        p0 += __shfl_xor(p0, m, 64);
        p1 += __shfl_xor(p1, m, 64);
    }
    if (lane == 0) {
        xlo[wid * 2 + 0] = p0;
        xlo[wid * 2 + 1] = p1;
        also[wid] = p0 * aso[0] + p1 * aso[1];
        aldo[wid] = p0 * ado[0] + p1 * ado[1];
    }
}

// ---------------- output aggregation ----------------
__global__ __launch_bounds__(256) void out_agg(const float* __restrict__ xlo, const float* __restrict__ also,
                                               const float* __restrict__ aldo, const int* __restrict__ off,
                                               const int* __restrict__ csr, const float* __restrict__ bo,
                                               float* __restrict__ out, int Nn) {
    int gid = blockIdx.x * 256 + threadIdx.x;
    int wid = gid >> 6, lane = threadIdx.x & 63;
    if (wid >= Nn) return;
    float aldn = aldo[wid];
    float eself = lrelu(also[wid] + aldn);
    int b = off[wid], e = off[wid + 1];
    float mloc = -INFINITY;
    for (int j = b + lane; j < e; j += 64)
        mloc = fmaxf(mloc, lrelu(also[csr[j]] + aldn));
    #pragma unroll
    for (int m = 1; m < 64; m <<= 1) mloc = fmaxf(mloc, __shfl_xor(mloc, m, 64));
    float mm = fmaxf(mloc, eself);
    float dl = 0.f, a0 = 0.f, a1 = 0.f;
    for (int j = b + lane; j < e; j += 64) {
        int s = csr[j];
        float w = __expf(lrelu(also[s] + aldn) - mm);
        dl += w;
        a0 += w * xlo[s * 2 + 0];
        a1 += w * xlo[s * 2 + 1];
    }
    #pragma unroll
    for (int m = 1; m < 64; m <<= 1) {
        dl += __shfl_xor(dl, m, 64);
        a0 += __shfl_xor(a0, m, 64);
        a1 += __shfl_xor(a1, m, 64);
    }
    if (lane == 0) {
        float wsf = __expf(eself - mm);
        dl += wsf;
        a0 += wsf * xlo[wid * 2 + 0];
        a1 += wsf * xlo[wid * 2 + 1];
        float inv = 1.f / (dl + 1e-16f);
        out[wid * 2 + 0] = a0 * inv + bo[0];
        out[wid * 2 + 1] = a1 * inv + bo[1];
    }
}

extern "C" void kernel_launch(void* const* d_in, const int* in_sizes, int n_in,
                              void* d_out, int out_size, void* d_ws, size_t ws_size,
                              hipStream_t stream) {
    const float* x   = (const float*)d_in[0];
    const int*   ei  = (const int*)d_in[1];
    const float* W1  = (const float*)d_in[2];
    const float* as1 = (const float*)d_in[3];
    const float* ad1 = (const float*)d_in[4];
    const float* b1  = (const float*)d_in[5];
    const float* g1  = (const float*)d_in[6];
    const float* be1 = (const float*)d_in[7];
    const float* rw  = (const float*)d_in[8];
    const float* rb  = (const float*)d_in[9];
    const float* W2  = (const float*)d_in[10];
    const float* as2 = (const float*)d_in[11];
    const float* ad2 = (const float*)d_in[12];
    const float* b2  = (const float*)d_in[13];
    const float* g2  = (const float*)d_in[14];
    const float* be2 = (const float*)d_in[15];
    const float* W3  = (const float*)d_in[16];
    const float* as3 = (const float*)d_in[17];
    const float* ad3 = (const float*)d_in[18];
    const float* b3  = (const float*)d_in[19];
    const float* g3  = (const float*)d_in[20];
    const float* be3 = (const float*)d_in[21];
    const float* Wo  = (const float*)d_in[22];
    const float* aso = (const float*)d_in[23];
    const float* ado = (const float*)d_in[24];
    const float* bo  = (const float*)d_in[25];

    int N = in_sizes[0] / 64;   // 50000
    int E = in_sizes[1] / 2;    // 800000
    const int* srcE = ei;
    const int* dstE = ei + E;
    int NB = (N + 127) >> 7;    // 391 buckets

    char* w = (char*)d_ws;
    auto alloc = [&](size_t b) { char* p = w; w += (b + 255) & ~(size_t)255; return p; };
    int* cnt    = (int*)alloc((size_t)N * 4);
    int* off    = (int*)alloc((size_t)(N + 1) * 4);
    int* gcur   = (int*)alloc((size_t)NB * 4);
    int* blk    = (int*)alloc(((size_t)N / 1024 + 2) * 4);
    int* csr    = (int*)alloc((size_t)E * 4);
    int2* bbuf  = (int2*)alloc((size_t)NB * BCAP * 8);
    float* hbuf = (float*)alloc((size_t)N * HID * 4);
    ushortT* xlh = (ushortT*)alloc((size_t)N * HID * 2);
    float* als  = (float*)alloc((size_t)N * HEADS * 4);
    float* ald  = (float*)alloc((size_t)N * HEADS * 4);
    float* xlo  = (float*)alloc((size_t)N * 2 * 4);
    float* alsoB = (float*)alloc((size_t)N * 4);
    float* aldoB = (float*)alloc((size_t)N * 4);

    hipMemsetAsync(cnt, 0, (size_t)N * 4, stream);
    hipMemsetAsync(gcur, 0, (size_t)NB * 4, stream);
    int gE = (E + 255) / 256;
    int nblk = (N + 1023) / 1024;
    count_k<<<gE, 256, 0, stream>>>(dstE, cnt, E);
    scan1_k<<<nblk, 256, 0, stream>>>(cnt, off, blk, N);
    scan2_k<<<1, 64, 0, stream>>>(blk, nblk);
    scan3_k<<<(N + 256) / 256, 256, 0, stream>>>(off, blk, N, E);
    binA_k<<<(E + 4095) / 4096, 256, 0, stream>>>(srcE, dstE, gcur, bbuf, E, NB);
    binB_k<<<NB, 256, 0, stream>>>(bbuf, gcur, off, csr);

    int gM = (N + 31) / 32;
    int gW = (N + 3) / 4;

    // residual projection: hbuf = x @ rw + rb (fp32 only)
    gemm_k<64><<<gM, 256, 0, stream>>>(x, rw, rb, hbuf, N, nullptr, nullptr, nullptr, nullptr, nullptr);

    // ---- layer 1 ----
    gemm_k<64><<<gM, 256, 0, stream>>>(x, W1, nullptr, nullptr, N, xlh, as1, ad1, als, ald);
    gat_fused<<<gW, 256, 0, stream>>>(xlh, als, ald, off, csr, b1, g1, be1, hbuf, N);

    // ---- layer 2 ----
    gemm_k<128><<<gM, 256, 0, stream>>>(hbuf, W2, nullptr, nullptr, N, xlh, as2, ad2, als, ald);
    gat_fused<<<gW, 256, 0, stream>>>(xlh, als, ald, off, csr, b2, g2, be2, hbuf, N);

    // ---- layer 3 ----
    gemm_k<128><<<gM, 256, 0, stream>>>(hbuf, W3, nullptr, nullptr, N, xlh, as3, ad3, als, ald);
    gat_fused<<<gW, 256, 0, stream>>>(xlh, als, ald, off, csr, b3, g3, be3, hbuf, N);

    // ---- output layer ----
    out_proj<<<gW, 256, 0, stream>>>(hbuf, Wo, aso, ado, xlo, alsoB, aldoB, N);
    out_agg<<<gW, 256, 0, stream>>>(xlo, alsoB, aldoB, off, csr, bo, (float*)d_out, N);
}

// Round 7
// 343.302 us; speedup vs baseline: 2.3399x; 1.0662x over previous
//
#include <hip/hip_runtime.h>
#include <math.h>

#define HID 128
#define HEADS 4
#define NEG_SLOPE 0.2f
#define LN_EPS 1e-5f
#define BCAP 4096   // per-bucket capacity (avg 2046 for N=50K, E=800K)

typedef unsigned short ushortT;
typedef unsigned int uintT;

__device__ __forceinline__ float lrelu(float v) { return v > 0.f ? v : NEG_SLOPE * v; }

__device__ __forceinline__ ushortT f2bf(float f) {
    uintT u = __float_as_uint(f);
    u += 0x7fffu + ((u >> 16) & 1u);   // round-to-nearest-even
    return (ushortT)(u >> 16);
}

// ---------------- CSR build ----------------
__global__ __launch_bounds__(256) void count_k(const int* __restrict__ dst, int* __restrict__ cnt, int E) {
    int i = blockIdx.x * 256 + threadIdx.x;
    if (i < E) atomicAdd(&cnt[dst[i]], 1);
}

__global__ __launch_bounds__(256) void scan1_k(const int* __restrict__ cnt, int* __restrict__ off,
                                               int* __restrict__ blk, int Nn) {
    __shared__ int part[256];
    int t = threadIdx.x;
    int base = blockIdx.x * 1024 + t * 4;
    int v0 = base + 0 < Nn ? cnt[base + 0] : 0;
    int v1 = base + 1 < Nn ? cnt[base + 1] : 0;
    int v2 = base + 2 < Nn ? cnt[base + 2] : 0;
    int v3 = base + 3 < Nn ? cnt[base + 3] : 0;
    int s = v0 + v1 + v2 + v3;
    part[t] = s;
    __syncthreads();
    #pragma unroll
    for (int ofs = 1; ofs < 256; ofs <<= 1) {
        int p = (t >= ofs) ? part[t - ofs] : 0;
        __syncthreads();
        part[t] += p;
        __syncthreads();
    }
    int run = part[t] - s;
    if (base + 0 < Nn) off[base + 0] = run; run += v0;
    if (base + 1 < Nn) off[base + 1] = run; run += v1;
    if (base + 2 < Nn) off[base + 2] = run; run += v2;
    if (base + 3 < Nn) off[base + 3] = run;
    if (t == 255) blk[blockIdx.x] = part[255];
}

__global__ __launch_bounds__(64) void scan2_k(int* __restrict__ blk, int nblk) {
    int t = threadIdx.x;
    int v = t < nblk ? blk[t] : 0;
    int inc = v;
    #pragma unroll
    for (int ofs = 1; ofs < 64; ofs <<= 1) {
        int p = __shfl_up(inc, ofs, 64);
        if (t >= ofs) inc += p;
    }
    if (t < nblk) blk[t] = inc - v;
}

__global__ __launch_bounds__(256) void scan3_k(int* __restrict__ off, const int* __restrict__ blk, int Nn, int E) {
    int i = blockIdx.x * 256 + threadIdx.x;
    if (i < Nn) off[i] += blk[i >> 10];
    if (i == 0) off[Nn] = E;
}

// pass A: bin edges by dst>>7 into bucket buffer (LDS-aggregated, coalesced flush)
__global__ __launch_bounds__(256) void binA_k(const int* __restrict__ src, const int* __restrict__ dst,
                                              int* __restrict__ gcur, int2* __restrict__ buf, int E, int NB) {
    __shared__ int hist[512];
    __shared__ int bbase[512];
    __shared__ int lcur[512];
    int t = threadIdx.x;
    for (int i = t; i < NB; i += 256) { hist[i] = 0; lcur[i] = 0; }
    __syncthreads();
    int e0 = blockIdx.x * 4096;
    int2 ed[16];
    #pragma unroll
    for (int j = 0; j < 16; ++j) {
        int idx = e0 + j * 256 + t;
        if (idx < E) {
            ed[j].x = src[idx];
            ed[j].y = dst[idx];
            atomicAdd(&hist[ed[j].y >> 7], 1);
        } else {
            ed[j].y = -1;
        }
    }
    __syncthreads();
    for (int i = t; i < NB; i += 256) {
        int c = hist[i];
        bbase[i] = c > 0 ? atomicAdd(&gcur[i], c) : 0;
    }
    __syncthreads();
    #pragma unroll
    for (int j = 0; j < 16; ++j) {
        if (ed[j].y >= 0) {
            int b = ed[j].y >> 7;
            int pos = bbase[b] + atomicAdd(&lcur[b], 1);
            buf[(size_t)b * BCAP + pos] = ed[j];
        }
    }
}

// pass B: per-bucket scatter into csr (writes confined to ~16KB window -> L2-absorbed)
__global__ __launch_bounds__(256) void binB_k(const int2* __restrict__ buf, const int* __restrict__ gcnt,
                                              const int* __restrict__ off, int* __restrict__ csr) {
    __shared__ int lcur[128];
    int t = threadIdx.x, b = blockIdx.x;
    if (t < 128) lcur[t] = 0;
    __syncthreads();
    int nb = gcnt[b];
    int nodebase = b << 7;
    for (int i = t; i < nb; i += 256) {
        int2 e = buf[(size_t)b * BCAP + i];
        int p = off[e.y] + atomicAdd(&lcur[e.y - nodebase], 1);
        csr[p] = e.x;
    }
}

// ---------------- GEMM: [M,K]x[K,128]; optional fp32 C, optional bf16 Ch, optional fused attn dots ----------------
template <int K>
__global__ __launch_bounds__(256) void gemm_k(const float* __restrict__ A, const float* __restrict__ W,
                                              const float* __restrict__ bias, float* __restrict__ C, int M,
                                              ushortT* __restrict__ Ch,
                                              const float* __restrict__ a_srcp, const float* __restrict__ a_dstp,
                                              float* __restrict__ als, float* __restrict__ ald) {
    __shared__ float Ws[32 * HID];
    __shared__ float As[32 * 36];
    int t = threadIdx.x;
    int row0 = blockIdx.x * 32;
    int r0 = (t >> 5) << 2;
    int c0 = (t & 31) << 2;
    float acc[4][4] = {};
    for (int k0 = 0; k0 < K; k0 += 32) {
        #pragma unroll
        for (int i = 0; i < 4; ++i) {
            int fid = t + i * 256;
            int kk = fid >> 5;
            int c = (fid & 31) << 2;
            *(float4*)&Ws[kk * HID + c] = *(const float4*)&W[(k0 + kk) * HID + c];
        }
        {
            int r = t >> 3;
            int kk0 = (t & 7) << 2;
            float4 a4 = make_float4(0.f, 0.f, 0.f, 0.f);
            if (row0 + r < M) a4 = *(const float4*)&A[(size_t)(row0 + r) * K + k0 + kk0];
            As[(kk0 + 0) * 36 + r] = a4.x;
            As[(kk0 + 1) * 36 + r] = a4.y;
            As[(kk0 + 2) * 36 + r] = a4.z;
            As[(kk0 + 3) * 36 + r] = a4.w;
        }
        __syncthreads();
        #pragma unroll
        for (int kk = 0; kk < 32; ++kk) {
            float4 a4 = *(const float4*)&As[kk * 36 + r0];
            float4 w4 = *(const float4*)&Ws[kk * HID + c0];
            float av[4] = {a4.x, a4.y, a4.z, a4.w};
            float wv[4] = {w4.x, w4.y, w4.z, w4.w};
            #pragma unroll
            for (int i = 0; i < 4; ++i)
                #pragma unroll
                for (int j = 0; j < 4; ++j)
                    acc[i][j] = fmaf(av[i], wv[j], acc[i][j]);
        }
        __syncthreads();
    }
    float4 b4 = make_float4(0.f, 0.f, 0.f, 0.f);
    if (bias) b4 = *(const float4*)&bias[c0];
    float4 as4 = make_float4(0.f, 0.f, 0.f, 0.f);
    float4 ad4 = make_float4(0.f, 0.f, 0.f, 0.f);
    if (als) {
        as4 = *(const float4*)&a_srcp[c0];   // a layout [4][32] flat == 128 floats
        ad4 = *(const float4*)&a_dstp[c0];
    }
    int h = (t & 31) >> 3;
    #pragma unroll
    for (int i = 0; i < 4; ++i) {
        int r = row0 + r0 + i;
        float4 o;
        o.x = acc[i][0] + b4.x;
        o.y = acc[i][1] + b4.y;
        o.z = acc[i][2] + b4.z;
        o.w = acc[i][3] + b4.w;
        if (r < M) {
            if (C) *(float4*)&C[(size_t)r * HID + c0] = o;
            if (Ch) {
                ushort4 hv;
                hv.x = f2bf(o.x); hv.y = f2bf(o.y);
                hv.z = f2bf(o.z); hv.w = f2bf(o.w);
                *(ushort4*)&Ch[(size_t)r * HID + c0] = hv;
            }
        }
        if (als) {
            float ps = o.x * as4.x + o.y * as4.y + o.z * as4.z + o.w * as4.w;
            float pd = o.x * ad4.x + o.y * ad4.y + o.z * ad4.z + o.w * ad4.w;
            ps += __shfl_xor(ps, 1, 64); pd += __shfl_xor(pd, 1, 64);
            ps += __shfl_xor(ps, 2, 64); pd += __shfl_xor(pd, 2, 64);
            ps += __shfl_xor(ps, 4, 64); pd += __shfl_xor(pd, 4, 64);
            if ((t & 7) == 0 && r < M) {
                als[r * 4 + h] = ps;
                ald[r * 4 + h] = pd;
            }
        }
    }
}

// ---------------- fully fused GAT: single-pass online softmax (shift = self logit) + LN + ReLU + residual ----------------
// Softmax is shift-invariant; using e_self as the shift removes the max pass.
// Logits here are O(30) max, so exp args stay < ~60 -> no overflow in fp32.
__global__ __launch_bounds__(256) void gat_fused(
        const ushortT* __restrict__ xlh, const float* __restrict__ als,
        const float* __restrict__ ald, const int* __restrict__ off,
        const int* __restrict__ csr, const float* __restrict__ bias,
        const float* __restrict__ g, const float* __restrict__ be,
        float* __restrict__ hres, int Nn) {
    int gid = blockIdx.x * 256 + threadIdx.x;
    int wid = gid >> 6, lane = threadIdx.x & 63;
    if (wid >= Nn) return;
    int q = lane >> 4;
    int cl = lane & 15;
    int h = cl >> 2;
    float aldh = ald[wid * 4 + h];
    float eh = lrelu(als[wid * 4 + h] + aldh);   // self logit (per head) = softmax shift
    int b = off[wid], e = off[wid + 1];
    // single pass: gather with online weight + denominator, shift = eh
    float acc[8] = {};
    float dsum = 0.f;
    for (int c = b + q; c < e; c += 4) {
        int s = csr[c];
        float w = __expf(lrelu(als[(size_t)s * 4 + h] + aldh) - eh);
        dsum += w;
        uint4 hv = *(const uint4*)&xlh[(size_t)s * HID + cl * 8];
        acc[0] = fmaf(w, __uint_as_float(hv.x << 16), acc[0]);
        acc[1] = fmaf(w, __uint_as_float(hv.x & 0xffff0000u), acc[1]);
        acc[2] = fmaf(w, __uint_as_float(hv.y << 16), acc[2]);
        acc[3] = fmaf(w, __uint_as_float(hv.y & 0xffff0000u), acc[3]);
        acc[4] = fmaf(w, __uint_as_float(hv.z << 16), acc[4]);
        acc[5] = fmaf(w, __uint_as_float(hv.z & 0xffff0000u), acc[5]);
        acc[6] = fmaf(w, __uint_as_float(hv.w << 16), acc[6]);
        acc[7] = fmaf(w, __uint_as_float(hv.w & 0xffff0000u), acc[7]);
    }
    #pragma unroll
    for (int k = 0; k < 8; ++k) {
        acc[k] += __shfl_xor(acc[k], 16, 64);
        acc[k] += __shfl_xor(acc[k], 32, 64);
    }
    dsum += __shfl_xor(dsum, 16, 64);
    dsum += __shfl_xor(dsum, 32, 64);
    float inv = 1.f / (dsum + 1.f + 1e-16f);     // self weight = exp(0) = 1
    // self row (bf16)
    uint4 sv = *(const uint4*)&xlh[(size_t)wid * HID + cl * 8];
    float sx[8];
    sx[0] = __uint_as_float(sv.x << 16);
    sx[1] = __uint_as_float(sv.x & 0xffff0000u);
    sx[2] = __uint_as_float(sv.y << 16);
    sx[3] = __uint_as_float(sv.y & 0xffff0000u);
    sx[4] = __uint_as_float(sv.z << 16);
    sx[5] = __uint_as_float(sv.z & 0xffff0000u);
    sx[6] = __uint_as_float(sv.w << 16);
    sx[7] = __uint_as_float(sv.w & 0xffff0000u);
    float4 bi0 = *(const float4*)&bias[cl * 8];
    float4 bi1 = *(const float4*)&bias[cl * 8 + 4];
    float o[8];
    o[0] = fmaf(acc[0] + sx[0], inv, bi0.x);
    o[1] = fmaf(acc[1] + sx[1], inv, bi0.y);
    o[2] = fmaf(acc[2] + sx[2], inv, bi0.z);
    o[3] = fmaf(acc[3] + sx[3], inv, bi0.w);
    o[4] = fmaf(acc[4] + sx[4], inv, bi1.x);
    o[5] = fmaf(acc[5] + sx[5], inv, bi1.y);
    o[6] = fmaf(acc[6] + sx[6], inv, bi1.z);
    o[7] = fmaf(acc[7] + sx[7], inv, bi1.w);
    // LayerNorm over the 128-ch row (reduce over cl bits; q copies identical)
    float s1 = o[0] + o[1] + o[2] + o[3] + o[4] + o[5] + o[6] + o[7];
    #pragma unroll
    for (int m = 1; m < 16; m <<= 1) s1 += __shfl_xor(s1, m, 64);
    float mu = s1 * (1.0f / HID);
    float qv = 0.f;
    #pragma unroll
    for (int k = 0; k < 8; ++k) { float d = o[k] - mu; qv += d * d; }
    #pragma unroll
    for (int m = 1; m < 16; m <<= 1) qv += __shfl_xor(qv, m, 64);
    float rs = rsqrtf(qv * (1.0f / HID) + LN_EPS);
    if (q == 0) {
        float4 g0 = *(const float4*)&g[cl * 8];
        float4 g1 = *(const float4*)&g[cl * 8 + 4];
        float4 be0 = *(const float4*)&be[cl * 8];
        float4 be1 = *(const float4*)&be[cl * 8 + 4];
        float4 r0 = *(const float4*)&hres[(size_t)wid * HID + cl * 8];
        float4 r1 = *(const float4*)&hres[(size_t)wid * HID + cl * 8 + 4];
        float4 w0, w1;
        w0.x = fmaxf((o[0] - mu) * rs * g0.x + be0.x, 0.f) + r0.x;
        w0.y = fmaxf((o[1] - mu) * rs * g0.y + be0.y, 0.f) + r0.y;
        w0.z = fmaxf((o[2] - mu) * rs * g0.z + be0.z, 0.f) + r0.z;
        w0.w = fmaxf((o[3] - mu) * rs * g0.w + be0.w, 0.f) + r0.w;
        w1.x = fmaxf((o[4] - mu) * rs * g1.x + be1.x, 0.f) + r1.x;
        w1.y = fmaxf((o[5] - mu) * rs * g1.y + be1.y, 0.f) + r1.y;
        w1.z = fmaxf((o[6] - mu) * rs * g1.z + be1.z, 0.f) + r1.z;
        w1.w = fmaxf((o[7] - mu) * rs * g1.w + be1.w, 0.f) + r1.w;
        *(float4*)&hres[(size_t)wid * HID + cl * 8] = w0;
        *(float4*)&hres[(size_t)wid * HID + cl * 8 + 4] = w1;
    }
}

// ---------------- output projection ----------------
__global__ __launch_bounds__(256) void out_proj(const float* __restrict__ h, const float* __restrict__ Wo,
                                                const float* __restrict__ aso, const float* __restrict__ ado,
                                                float* __restrict__ xlo, float* __restrict__ also,
                                                float* __restrict__ aldo, int Nn) {
    int gid = blockIdx.x * 256 + threadIdx.x;
    int wid = gid >> 6, lane = threadIdx.x & 63;
    if (wid >= Nn) return;
    float2 v = *(const float2*)&h[(size_t)wid * HID + 2 * lane];
    float2 w0 = *(const float2*)&Wo[(2 * lane) * 2];
    float2 w1 = *(const float2*)&Wo[(2 * lane + 1) * 2];
    float p0 = v.x * w0.x + v.y * w1.x;
    float p1 = v.x * w0.y + v.y * w1.y;
    #pragma unroll
    for (int m = 1; m < 64; m <<= 1) {
        p0 += __shfl_xor(p0, m, 64);
        p1 += __shfl_xor(p1, m, 64);
    }
    if (lane == 0) {
        xlo[wid * 2 + 0] = p0;
        xlo[wid * 2 + 1] = p1;
        also[wid] = p0 * aso[0] + p1 * aso[1];
        aldo[wid] = p0 * ado[0] + p1 * ado[1];
    }
}

// ---------------- output aggregation ----------------
__global__ __launch_bounds__(256) void out_agg(const float* __restrict__ xlo, const float* __restrict__ also,
                                               const float* __restrict__ aldo, const int* __restrict__ off,
                                               const int* __restrict__ csr, const float* __restrict__ bo,
                                               float* __restrict__ out, int Nn) {
    int gid = blockIdx.x * 256 + threadIdx.x;
    int wid = gid >> 6, lane = threadIdx.x & 63;
    if (wid >= Nn) return;
    float aldn = aldo[wid];
    float eself = lrelu(also[wid] + aldn);
    int b = off[wid], e = off[wid + 1];
    float dl = 0.f, a0 = 0.f, a1 = 0.f;
    for (int j = b + lane; j < e; j += 64) {
        int s = csr[j];
        float w = __expf(lrelu(also[s] + aldn) - eself);
        dl += w;
        a0 += w * xlo[s * 2 + 0];
        a1 += w * xlo[s * 2 + 1];
    }
    #pragma unroll
    for (int m = 1; m < 64; m <<= 1) {
        dl += __shfl_xor(dl, m, 64);
        a0 += __shfl_xor(a0, m, 64);
        a1 += __shfl_xor(a1, m, 64);
    }
    if (lane == 0) {
        dl += 1.f;   // self weight exp(0)
        a0 += xlo[wid * 2 + 0];
        a1 += xlo[wid * 2 + 1];
        float inv = 1.f / (dl + 1e-16f);
        out[wid * 2 + 0] = a0 * inv + bo[0];
        out[wid * 2 + 1] = a1 * inv + bo[1];
    }
}

extern "C" void kernel_launch(void* const* d_in, const int* in_sizes, int n_in,
                              void* d_out, int out_size, void* d_ws, size_t ws_size,
                              hipStream_t stream) {
    const float* x   = (const float*)d_in[0];
    const int*   ei  = (const int*)d_in[1];
    const float* W1  = (const float*)d_in[2];
    const float* as1 = (const float*)d_in[3];
    const float* ad1 = (const float*)d_in[4];
    const float* b1  = (const float*)d_in[5];
    const float* g1  = (const float*)d_in[6];
    const float* be1 = (const float*)d_in[7];
    const float* rw  = (const float*)d_in[8];
    const float* rb  = (const float*)d_in[9];
    const float* W2  = (const float*)d_in[10];
    const float* as2 = (const float*)d_in[11];
    const float* ad2 = (const float*)d_in[12];
    const float* b2  = (const float*)d_in[13];
    const float* g2  = (const float*)d_in[14];
    const float* be2 = (const float*)d_in[15];
    const float* W3  = (const float*)d_in[16];
    const float* as3 = (const float*)d_in[17];
    const float* ad3 = (const float*)d_in[18];
    const float* b3  = (const float*)d_in[19];
    const float* g3  = (const float*)d_in[20];
    const float* be3 = (const float*)d_in[21];
    const float* Wo  = (const float*)d_in[22];
    const float* aso = (const float*)d_in[23];
    const float* ado = (const float*)d_in[24];
    const float* bo  = (const float*)d_in[25];

    int N = in_sizes[0] / 64;   // 50000
    int E = in_sizes[1] / 2;    // 800000
    const int* srcE = ei;
    const int* dstE = ei + E;
    int NB = (N + 127) >> 7;    // 391 buckets

    char* w = (char*)d_ws;
    auto alloc = [&](size_t b) { char* p = w; w += (b + 255) & ~(size_t)255; return p; };
    int* cnt    = (int*)alloc((size_t)N * 4);
    int* off    = (int*)alloc((size_t)(N + 1) * 4);
    int* gcur   = (int*)alloc((size_t)NB * 4);
    int* blk    = (int*)alloc(((size_t)N / 1024 + 2) * 4);
    int* csr    = (int*)alloc((size_t)E * 4);
    int2* bbuf  = (int2*)alloc((size_t)NB * BCAP * 8);
    float* hbuf = (float*)alloc((size_t)N * HID * 4);
    ushortT* xlh = (ushortT*)alloc((size_t)N * HID * 2);
    float* als  = (float*)alloc((size_t)N * HEADS * 4);
    float* ald  = (float*)alloc((size_t)N * HEADS * 4);
    float* xlo  = (float*)alloc((size_t)N * 2 * 4);
    float* alsoB = (float*)alloc((size_t)N * 4);
    float* aldoB = (float*)alloc((size_t)N * 4);

    hipMemsetAsync(cnt, 0, (size_t)N * 4, stream);
    hipMemsetAsync(gcur, 0, (size_t)NB * 4, stream);
    int gE = (E + 255) / 256;
    int nblk = (N + 1023) / 1024;
    count_k<<<gE, 256, 0, stream>>>(dstE, cnt, E);
    scan1_k<<<nblk, 256, 0, stream>>>(cnt, off, blk, N);
    scan2_k<<<1, 64, 0, stream>>>(blk, nblk);
    scan3_k<<<(N + 256) / 256, 256, 0, stream>>>(off, blk, N, E);
    binA_k<<<(E + 4095) / 4096, 256, 0, stream>>>(srcE, dstE, gcur, bbuf, E, NB);
    binB_k<<<NB, 256, 0, stream>>>(bbuf, gcur, off, csr);

    int gM = (N + 31) / 32;
    int gW = (N + 3) / 4;

    // residual projection: hbuf = x @ rw + rb (fp32 only)
    gemm_k<64><<<gM, 256, 0, stream>>>(x, rw, rb, hbuf, N, nullptr, nullptr, nullptr, nullptr, nullptr);

    // ---- layer 1 ----
    gemm_k<64><<<gM, 256, 0, stream>>>(x, W1, nullptr, nullptr, N, xlh, as1, ad1, als, ald);
    gat_fused<<<gW, 256, 0, stream>>>(xlh, als, ald, off, csr, b1, g1, be1, hbuf, N);

    // ---- layer 2 ----
    gemm_k<128><<<gM, 256, 0, stream>>>(hbuf, W2, nullptr, nullptr, N, xlh, as2, ad2, als, ald);
    gat_fused<<<gW, 256, 0, stream>>>(xlh, als, ald, off, csr, b2, g2, be2, hbuf, N);

    // ---- layer 3 ----
    gemm_k<128><<<gM, 256, 0, stream>>>(hbuf, W3, nullptr, nullptr, N, xlh, as3, ad3, als, ald);
    gat_fused<<<gW, 256, 0, stream>>>(xlh, als, ald, off, csr, b3, g3, be3, hbuf, N);

    // ---- output layer ----
    out_proj<<<gW, 256, 0, stream>>>(hbuf, Wo, aso, ado, xlo, alsoB, aldoB, N);
    out_agg<<<gW, 256, 0, stream>>>(xlo, alsoB, aldoB, off, csr, bo, (float*)d_out, N);
}

// Round 8
// 306.570 us; speedup vs baseline: 2.6202x; 1.1198x over previous
//
#include <hip/hip_runtime.h>
#include <math.h>

#define HID 128
#define HEADS 4
#define NEG_SLOPE 0.2f
#define LN_EPS 1e-5f
#define BCAP 4096   // per-bucket capacity (avg 2046 for N=50K, E=800K)

typedef unsigned short ushortT;
typedef unsigned int uintT;
typedef __attribute__((ext_vector_type(8))) short bf16x8;
typedef __attribute__((ext_vector_type(4))) float f32x4;

__device__ __forceinline__ float lrelu(float v) { return v > 0.f ? v : NEG_SLOPE * v; }

__device__ __forceinline__ ushortT f2bf(float f) {
    uintT u = __float_as_uint(f);
    u += 0x7fffu + ((u >> 16) & 1u);   // round-to-nearest-even
    return (ushortT)(u >> 16);
}

// ---------------- CSR build ----------------
__global__ __launch_bounds__(256) void count_k(const int* __restrict__ dst, int* __restrict__ cnt, int E) {
    int i = blockIdx.x * 256 + threadIdx.x;
    if (i < E) atomicAdd(&cnt[dst[i]], 1);
}

__global__ __launch_bounds__(256) void scan1_k(const int* __restrict__ cnt, int* __restrict__ off,
                                               int* __restrict__ blk, int Nn) {
    __shared__ int part[256];
    int t = threadIdx.x;
    int base = blockIdx.x * 1024 + t * 4;
    int v0 = base + 0 < Nn ? cnt[base + 0] : 0;
    int v1 = base + 1 < Nn ? cnt[base + 1] : 0;
    int v2 = base + 2 < Nn ? cnt[base + 2] : 0;
    int v3 = base + 3 < Nn ? cnt[base + 3] : 0;
    int s = v0 + v1 + v2 + v3;
    part[t] = s;
    __syncthreads();
    #pragma unroll
    for (int ofs = 1; ofs < 256; ofs <<= 1) {
        int p = (t >= ofs) ? part[t - ofs] : 0;
        __syncthreads();
        part[t] += p;
        __syncthreads();
    }
    int run = part[t] - s;
    if (base + 0 < Nn) off[base + 0] = run; run += v0;
    if (base + 1 < Nn) off[base + 1] = run; run += v1;
    if (base + 2 < Nn) off[base + 2] = run; run += v2;
    if (base + 3 < Nn) off[base + 3] = run;
    if (t == 255) blk[blockIdx.x] = part[255];
}

__global__ __launch_bounds__(64) void scan2_k(int* __restrict__ blk, int nblk) {
    int t = threadIdx.x;
    int v = t < nblk ? blk[t] : 0;
    int inc = v;
    #pragma unroll
    for (int ofs = 1; ofs < 64; ofs <<= 1) {
        int p = __shfl_up(inc, ofs, 64);
        if (t >= ofs) inc += p;
    }
    if (t < nblk) blk[t] = inc - v;
}

__global__ __launch_bounds__(256) void scan3_k(int* __restrict__ off, const int* __restrict__ blk, int Nn, int E) {
    int i = blockIdx.x * 256 + threadIdx.x;
    if (i < Nn) off[i] += blk[i >> 10];
    if (i == 0) off[Nn] = E;
}

// pass A: bin edges by dst>>7 into bucket buffer
__global__ __launch_bounds__(256) void binA_k(const int* __restrict__ src, const int* __restrict__ dst,
                                              int* __restrict__ gcur, int2* __restrict__ buf, int E, int NB) {
    __shared__ int hist[512];
    __shared__ int bbase[512];
    __shared__ int lcur[512];
    int t = threadIdx.x;
    for (int i = t; i < NB; i += 256) { hist[i] = 0; lcur[i] = 0; }
    __syncthreads();
    int e0 = blockIdx.x * 4096;
    int2 ed[16];
    #pragma unroll
    for (int j = 0; j < 16; ++j) {
        int idx = e0 + j * 256 + t;
        if (idx < E) {
            ed[j].x = src[idx];
            ed[j].y = dst[idx];
            atomicAdd(&hist[ed[j].y >> 7], 1);
        } else {
            ed[j].y = -1;
        }
    }
    __syncthreads();
    for (int i = t; i < NB; i += 256) {
        int c = hist[i];
        bbase[i] = c > 0 ? atomicAdd(&gcur[i], c) : 0;
    }
    __syncthreads();
    #pragma unroll
    for (int j = 0; j < 16; ++j) {
        if (ed[j].y >= 0) {
            int b = ed[j].y >> 7;
            int pos = bbase[b] + atomicAdd(&lcur[b], 1);
            buf[(size_t)b * BCAP + pos] = ed[j];
        }
    }
}

// pass B: per-bucket scatter into csr
__global__ __launch_bounds__(256) void binB_k(const int2* __restrict__ buf, const int* __restrict__ gcnt,
                                              const int* __restrict__ off, int* __restrict__ csr) {
    __shared__ int lcur[128];
    int t = threadIdx.x, b = blockIdx.x;
    if (t < 128) lcur[t] = 0;
    __syncthreads();
    int nb = gcnt[b];
    int nodebase = b << 7;
    for (int i = t; i < nb; i += 256) {
        int2 e = buf[(size_t)b * BCAP + i];
        int p = off[e.y] + atomicAdd(&lcur[e.y - nodebase], 1);
        csr[p] = e.x;
    }
}

// ---------------- conversions ----------------
__global__ __launch_bounds__(256) void xconv_k(const float* __restrict__ x, ushortT* __restrict__ xh, int n4) {
    int i = blockIdx.x * 256 + threadIdx.x;
    if (i < n4) {
        float4 v = *(const float4*)&x[(size_t)i * 4];
        ushort4 o;
        o.x = f2bf(v.x); o.y = f2bf(v.y); o.z = f2bf(v.z); o.w = f2bf(v.w);
        *(ushort4*)&xh[(size_t)i * 4] = o;
    }
}

// convert 4 weight matrices into MFMA B-fragment layout:
// frag idx = ((j*(K/32) + ks)*64 + lane)*8 + i  maps to  W[ks*32 + (lane>>4)*8 + i][j*16 + (lane&15)]
__global__ __launch_bounds__(256) void wconv4_k(const float* __restrict__ rw, const float* __restrict__ W1,
                                                const float* __restrict__ W2, const float* __restrict__ W3,
                                                ushortT* __restrict__ rwf, ushortT* __restrict__ W1f,
                                                ushortT* __restrict__ W2f, ushortT* __restrict__ W3f) {
    int id = blockIdx.x * 256 + threadIdx.x;
    const float* Wsrc; ushortT* Wdst; int kdiv; int lid;
    if (id < 8192)        { Wsrc = rw; Wdst = rwf; kdiv = 2; lid = id; }
    else if (id < 16384)  { Wsrc = W1; Wdst = W1f; kdiv = 2; lid = id - 8192; }
    else if (id < 32768)  { Wsrc = W2; Wdst = W2f; kdiv = 4; lid = id - 16384; }
    else if (id < 49152)  { Wsrc = W3; Wdst = W3f; kdiv = 4; lid = id - 32768; }
    else return;
    int i = lid & 7;
    int lane = (lid >> 3) & 63;
    int rest = lid >> 9;            // j*kdiv + ks
    int ks = rest % kdiv;
    int j = rest / kdiv;
    int k = ks * 32 + (lane >> 4) * 8 + i;
    int n = j * 16 + (lane & 15);
    Wdst[lid] = f2bf(Wsrc[k * HID + n]);
}

// ---------------- MFMA GEMM (x layer): dual output rw->Cres(+rb) and W1->Ch + attn dots ----------------
__global__ __launch_bounds__(256) void gemm_mfma_x(
        const ushortT* __restrict__ Ah, const ushortT* __restrict__ rwf, const ushortT* __restrict__ W1f,
        const float* __restrict__ rb, const float* __restrict__ a_srcp, const float* __restrict__ a_dstp,
        float* __restrict__ Cres, ushortT* __restrict__ Ch,
        float* __restrict__ als, float* __restrict__ ald, int M) {
    int t = threadIdx.x;
    int wave = t >> 6, lane = t & 63;
    int row0 = blockIdx.x * 64 + wave * 16;
    int cl = lane & 15, grp = lane >> 4;
    int rA = row0 + cl;
    f32x4 accR[8] = {};
    f32x4 acc1[8] = {};
    #pragma unroll
    for (int ks = 0; ks < 2; ++ks) {
        bf16x8 afr = {};
        if (rA < M) afr = *(const bf16x8*)&Ah[(size_t)rA * 64 + ks * 32 + grp * 8];
        #pragma unroll
        for (int j = 0; j < 8; ++j) {
            bf16x8 br = *(const bf16x8*)&rwf[(((size_t)j * 2 + ks) * 64 + lane) * 8];
            accR[j] = __builtin_amdgcn_mfma_f32_16x16x32_bf16(afr, br, accR[j], 0, 0, 0);
            bf16x8 b1 = *(const bf16x8*)&W1f[(((size_t)j * 2 + ks) * 64 + lane) * 8];
            acc1[j] = __builtin_amdgcn_mfma_f32_16x16x32_bf16(afr, b1, acc1[j], 0, 0, 0);
        }
    }
    float asv[8], adv[8], rbv[8];
    #pragma unroll
    for (int j = 0; j < 8; ++j) {
        asv[j] = a_srcp[j * 16 + cl];
        adv[j] = a_dstp[j * 16 + cl];
        rbv[j] = rb[j * 16 + cl];
    }
    #pragma unroll
    for (int reg = 0; reg < 4; ++reg) {
        int r = row0 + grp * 4 + reg;
        bool ok = r < M;
        if (ok) {
            #pragma unroll
            for (int j = 0; j < 8; ++j) {
                Cres[(size_t)r * HID + j * 16 + cl] = accR[j][reg] + rbv[j];
                Ch[(size_t)r * HID + j * 16 + cl] = f2bf(acc1[j][reg]);
            }
        }
        float ps[4], pd[4];
        #pragma unroll
        for (int h = 0; h < 4; ++h) {
            ps[h] = acc1[2 * h][reg] * asv[2 * h] + acc1[2 * h + 1][reg] * asv[2 * h + 1];
            pd[h] = acc1[2 * h][reg] * adv[2 * h] + acc1[2 * h + 1][reg] * adv[2 * h + 1];
        }
        #pragma unroll
        for (int m = 1; m < 16; m <<= 1) {
            #pragma unroll
            for (int h = 0; h < 4; ++h) {
                ps[h] += __shfl_xor(ps[h], m, 64);
                pd[h] += __shfl_xor(pd[h], m, 64);
            }
        }
        if (cl == 0 && ok) {
            *(float4*)&als[(size_t)r * 4] = make_float4(ps[0], ps[1], ps[2], ps[3]);
            *(float4*)&ald[(size_t)r * 4] = make_float4(pd[0], pd[1], pd[2], pd[3]);
        }
    }
}

// ---------------- MFMA GEMM (hidden layers, K=128): Ch + attn dots ----------------
__global__ __launch_bounds__(256) void gemm_mfma_h(
        const ushortT* __restrict__ Ah, const ushortT* __restrict__ Wf,
        const float* __restrict__ a_srcp, const float* __restrict__ a_dstp,
        ushortT* __restrict__ Ch, float* __restrict__ als, float* __restrict__ ald, int M) {
    int t = threadIdx.x;
    int wave = t >> 6, lane = t & 63;
    int row0 = blockIdx.x * 64 + wave * 16;
    int cl = lane & 15, grp = lane >> 4;
    int rA = row0 + cl;
    f32x4 acc[8] = {};
    #pragma unroll
    for (int ks = 0; ks < 4; ++ks) {
        bf16x8 afr = {};
        if (rA < M) afr = *(const bf16x8*)&Ah[(size_t)rA * HID + ks * 32 + grp * 8];
        #pragma unroll
        for (int j = 0; j < 8; ++j) {
            bf16x8 br = *(const bf16x8*)&Wf[(((size_t)j * 4 + ks) * 64 + lane) * 8];
            acc[j] = __builtin_amdgcn_mfma_f32_16x16x32_bf16(afr, br, acc[j], 0, 0, 0);
        }
    }
    float asv[8], adv[8];
    #pragma unroll
    for (int j = 0; j < 8; ++j) {
        asv[j] = a_srcp[j * 16 + cl];
        adv[j] = a_dstp[j * 16 + cl];
    }
    #pragma unroll
    for (int reg = 0; reg < 4; ++reg) {
        int r = row0 + grp * 4 + reg;
        bool ok = r < M;
        if (ok) {
            #pragma unroll
            for (int j = 0; j < 8; ++j)
                Ch[(size_t)r * HID + j * 16 + cl] = f2bf(acc[j][reg]);
        }
        float ps[4], pd[4];
        #pragma unroll
        for (int h = 0; h < 4; ++h) {
            ps[h] = acc[2 * h][reg] * asv[2 * h] + acc[2 * h + 1][reg] * asv[2 * h + 1];
            pd[h] = acc[2 * h][reg] * adv[2 * h] + acc[2 * h + 1][reg] * adv[2 * h + 1];
        }
        #pragma unroll
        for (int m = 1; m < 16; m <<= 1) {
            #pragma unroll
            for (int h = 0; h < 4; ++h) {
                ps[h] += __shfl_xor(ps[h], m, 64);
                pd[h] += __shfl_xor(pd[h], m, 64);
            }
        }
        if (cl == 0 && ok) {
            *(float4*)&als[(size_t)r * 4] = make_float4(ps[0], ps[1], ps[2], ps[3]);
            *(float4*)&ald[(size_t)r * 4] = make_float4(pd[0], pd[1], pd[2], pd[3]);
        }
    }
}

// ---------------- fully fused GAT: single-pass online softmax (shift = self logit) + LN + ReLU + residual ----------------
__global__ __launch_bounds__(256) void gat_fused(
        const ushortT* __restrict__ xlh, const float* __restrict__ als,
        const float* __restrict__ ald, const int* __restrict__ off,
        const int* __restrict__ csr, const float* __restrict__ bias,
        const float* __restrict__ g, const float* __restrict__ be,
        float* __restrict__ hres, ushortT* __restrict__ hresh, int Nn) {
    int gid = blockIdx.x * 256 + threadIdx.x;
    int wid = gid >> 6, lane = threadIdx.x & 63;
    if (wid >= Nn) return;
    int q = lane >> 4;
    int cl = lane & 15;
    int h = cl >> 2;
    float aldh = ald[wid * 4 + h];
    float eh = lrelu(als[wid * 4 + h] + aldh);   // self logit = softmax shift
    int b = off[wid], e = off[wid + 1];
    float acc[8] = {};
    float dsum = 0.f;
    for (int c = b + q; c < e; c += 4) {
        int s = csr[c];
        float w = __expf(lrelu(als[(size_t)s * 4 + h] + aldh) - eh);
        dsum += w;
        uint4 hv = *(const uint4*)&xlh[(size_t)s * HID + cl * 8];
        acc[0] = fmaf(w, __uint_as_float(hv.x << 16), acc[0]);
        acc[1] = fmaf(w, __uint_as_float(hv.x & 0xffff0000u), acc[1]);
        acc[2] = fmaf(w, __uint_as_float(hv.y << 16), acc[2]);
        acc[3] = fmaf(w, __uint_as_float(hv.y & 0xffff0000u), acc[3]);
        acc[4] = fmaf(w, __uint_as_float(hv.z << 16), acc[4]);
        acc[5] = fmaf(w, __uint_as_float(hv.z & 0xffff0000u), acc[5]);
        acc[6] = fmaf(w, __uint_as_float(hv.w << 16), acc[6]);
        acc[7] = fmaf(w, __uint_as_float(hv.w & 0xffff0000u), acc[7]);
    }
    #pragma unroll
    for (int k = 0; k < 8; ++k) {
        acc[k] += __shfl_xor(acc[k], 16, 64);
        acc[k] += __shfl_xor(acc[k], 32, 64);
    }
    dsum += __shfl_xor(dsum, 16, 64);
    dsum += __shfl_xor(dsum, 32, 64);
    float inv = 1.f / (dsum + 1.f + 1e-16f);     // self weight = exp(0) = 1
    uint4 sv = *(const uint4*)&xlh[(size_t)wid * HID + cl * 8];
    float sx[8];
    sx[0] = __uint_as_float(sv.x << 16);
    sx[1] = __uint_as_float(sv.x & 0xffff0000u);
    sx[2] = __uint_as_float(sv.y << 16);
    sx[3] = __uint_as_float(sv.y & 0xffff0000u);
    sx[4] = __uint_as_float(sv.z << 16);
    sx[5] = __uint_as_float(sv.z & 0xffff0000u);
    sx[6] = __uint_as_float(sv.w << 16);
    sx[7] = __uint_as_float(sv.w & 0xffff0000u);
    float4 bi0 = *(const float4*)&bias[cl * 8];
    float4 bi1 = *(const float4*)&bias[cl * 8 + 4];
    float o[8];
    o[0] = fmaf(acc[0] + sx[0], inv, bi0.x);
    o[1] = fmaf(acc[1] + sx[1], inv, bi0.y);
    o[2] = fmaf(acc[2] + sx[2], inv, bi0.z);
    o[3] = fmaf(acc[3] + sx[3], inv, bi0.w);
    o[4] = fmaf(acc[4] + sx[4], inv, bi1.x);
    o[5] = fmaf(acc[5] + sx[5], inv, bi1.y);
    o[6] = fmaf(acc[6] + sx[6], inv, bi1.z);
    o[7] = fmaf(acc[7] + sx[7], inv, bi1.w);
    float s1 = o[0] + o[1] + o[2] + o[3] + o[4] + o[5] + o[6] + o[7];
    #pragma unroll
    for (int m = 1; m < 16; m <<= 1) s1 += __shfl_xor(s1, m, 64);
    float mu = s1 * (1.0f / HID);
    float qv = 0.f;
    #pragma unroll
    for (int k = 0; k < 8; ++k) { float d = o[k] - mu; qv += d * d; }
    #pragma unroll
    for (int m = 1; m < 16; m <<= 1) qv += __shfl_xor(qv, m, 64);
    float rs = rsqrtf(qv * (1.0f / HID) + LN_EPS);
    if (q == 0) {
        float4 g0 = *(const float4*)&g[cl * 8];
        float4 g1 = *(const float4*)&g[cl * 8 + 4];
        float4 be0 = *(const float4*)&be[cl * 8];
        float4 be1 = *(const float4*)&be[cl * 8 + 4];
        float4 r0 = *(const float4*)&hres[(size_t)wid * HID + cl * 8];
        float4 r1 = *(const float4*)&hres[(size_t)wid * HID + cl * 8 + 4];
        float4 w0, w1;
        w0.x = fmaxf((o[0] - mu) * rs * g0.x + be0.x, 0.f) + r0.x;
        w0.y = fmaxf((o[1] - mu) * rs * g0.y + be0.y, 0.f) + r0.y;
        w0.z = fmaxf((o[2] - mu) * rs * g0.z + be0.z, 0.f) + r0.z;
        w0.w = fmaxf((o[3] - mu) * rs * g0.w + be0.w, 0.f) + r0.w;
        w1.x = fmaxf((o[4] - mu) * rs * g1.x + be1.x, 0.f) + r1.x;
        w1.y = fmaxf((o[5] - mu) * rs * g1.y + be1.y, 0.f) + r1.y;
        w1.z = fmaxf((o[6] - mu) * rs * g1.z + be1.z, 0.f) + r1.z;
        w1.w = fmaxf((o[7] - mu) * rs * g1.w + be1.w, 0.f) + r1.w;
        *(float4*)&hres[(size_t)wid * HID + cl * 8] = w0;
        *(float4*)&hres[(size_t)wid * HID + cl * 8 + 4] = w1;
        if (hresh) {
            ushort4 hv0, hv1;
            hv0.x = f2bf(w0.x); hv0.y = f2bf(w0.y); hv0.z = f2bf(w0.z); hv0.w = f2bf(w0.w);
            hv1.x = f2bf(w1.x); hv1.y = f2bf(w1.y); hv1.z = f2bf(w1.z); hv1.w = f2bf(w1.w);
            *(ushort4*)&hresh[(size_t)wid * HID + cl * 8] = hv0;
            *(ushort4*)&hresh[(size_t)wid * HID + cl * 8 + 4] = hv1;
        }
    }
}

// ---------------- output projection ----------------
__global__ __launch_bounds__(256) void out_proj(const float* __restrict__ h, const float* __restrict__ Wo,
                                                const float* __restrict__ aso, const float* __restrict__ ado,
                                                float* __restrict__ xlo, float* __restrict__ also,
                                                float* __restrict__ aldo, int Nn) {
    int gid = blockIdx.x * 256 + threadIdx.x;
    int wid = gid >> 6, lane = threadIdx.x & 63;
    if (wid >= Nn) return;
    float2 v = *(const float2*)&h[(size_t)wid * HID + 2 * lane];
    float2 w0 = *(const float2*)&Wo[(2 * lane) * 2];
    float2 w1 = *(const float2*)&Wo[(2 * lane + 1) * 2];
    float p0 = v.x * w0.x + v.y * w1.x;
    float p1 = v.x * w0.y + v.y * w1.y;
    #pragma unroll
    for (int m = 1; m < 64; m <<= 1) {
        p0 += __shfl_xor(p0, m, 64);
        p1 += __shfl_xor(p1, m, 64);
    }
    if (lane == 0) {
        xlo[wid * 2 + 0] = p0;
        xlo[wid * 2 + 1] = p1;
        also[wid] = p0 * aso[0] + p1 * aso[1];
        aldo[wid] = p0 * ado[0] + p1 * ado[1];
    }
}

// ---------------- output aggregation ----------------
__global__ __launch_bounds__(256) void out_agg(const float* __restrict__ xlo, const float* __restrict__ also,
                                               const float* __restrict__ aldo, const int* __restrict__ off,
                                               const int* __restrict__ csr, const float* __restrict__ bo,
                                               float* __restrict__ out, int Nn) {
    int gid = blockIdx.x * 256 + threadIdx.x;
    int wid = gid >> 6, lane = threadIdx.x & 63;
    if (wid >= Nn) return;
    float aldn = aldo[wid];
    float eself = lrelu(also[wid] + aldn);
    int b = off[wid], e = off[wid + 1];
    float dl = 0.f, a0 = 0.f, a1 = 0.f;
    for (int j = b + lane; j < e; j += 64) {
        int s = csr[j];
        float w = __expf(lrelu(also[s] + aldn) - eself);
        dl += w;
        a0 += w * xlo[s * 2 + 0];
        a1 += w * xlo[s * 2 + 1];
    }
    #pragma unroll
    for (int m = 1; m < 64; m <<= 1) {
        dl += __shfl_xor(dl, m, 64);
        a0 += __shfl_xor(a0, m, 64);
        a1 += __shfl_xor(a1, m, 64);
    }
    if (lane == 0) {
        dl += 1.f;   // self weight exp(0)
        a0 += xlo[wid * 2 + 0];
        a1 += xlo[wid * 2 + 1];
        float inv = 1.f / (dl + 1e-16f);
        out[wid * 2 + 0] = a0 * inv + bo[0];
        out[wid * 2 + 1] = a1 * inv + bo[1];
    }
}

extern "C" void kernel_launch(void* const* d_in, const int* in_sizes, int n_in,
                              void* d_out, int out_size, void* d_ws, size_t ws_size,
                              hipStream_t stream) {
    const float* x   = (const float*)d_in[0];
    const int*   ei  = (const int*)d_in[1];
    const float* W1  = (const float*)d_in[2];
    const float* as1 = (const float*)d_in[3];
    const float* ad1 = (const float*)d_in[4];
    const float* b1  = (const float*)d_in[5];
    const float* g1  = (const float*)d_in[6];
    const float* be1 = (const float*)d_in[7];
    const float* rw  = (const float*)d_in[8];
    const float* rb  = (const float*)d_in[9];
    const float* W2  = (const float*)d_in[10];
    const float* as2 = (const float*)d_in[11];
    const float* ad2 = (const float*)d_in[12];
    const float* b2  = (const float*)d_in[13];
    const float* g2  = (const float*)d_in[14];
    const float* be2 = (const float*)d_in[15];
    const float* W3  = (const float*)d_in[16];
    const float* as3 = (const float*)d_in[17];
    const float* ad3 = (const float*)d_in[18];
    const float* b3  = (const float*)d_in[19];
    const float* g3  = (const float*)d_in[20];
    const float* be3 = (const float*)d_in[21];
    const float* Wo  = (const float*)d_in[22];
    const float* aso = (const float*)d_in[23];
    const float* ado = (const float*)d_in[24];
    const float* bo  = (const float*)d_in[25];

    int N = in_sizes[0] / 64;   // 50000
    int E = in_sizes[1] / 2;    // 800000
    const int* srcE = ei;
    const int* dstE = ei + E;
    int NB = (N + 127) >> 7;    // 391 buckets

    char* w = (char*)d_ws;
    auto alloc = [&](size_t b) { char* p = w; w += (b + 255) & ~(size_t)255; return p; };
    int* cnt    = (int*)alloc((size_t)N * 4);
    int* off    = (int*)alloc((size_t)(N + 1) * 4);
    int* gcur   = (int*)alloc((size_t)NB * 4);
    int* blk    = (int*)alloc(((size_t)N / 1024 + 2) * 4);
    int* csr    = (int*)alloc((size_t)E * 4);
    int2* bbuf  = (int2*)alloc((size_t)NB * BCAP * 8);
    float* hbuf = (float*)alloc((size_t)N * HID * 4);
    ushortT* hresh = (ushortT*)alloc((size_t)N * HID * 2);
    ushortT* xlh = (ushortT*)alloc((size_t)N * HID * 2);
    ushortT* xh  = (ushortT*)alloc((size_t)N * 64 * 2);
    ushortT* rwf = (ushortT*)alloc(8192 * 2);
    ushortT* W1f = (ushortT*)alloc(8192 * 2);
    ushortT* W2f = (ushortT*)alloc(16384 * 2);
    ushortT* W3f = (ushortT*)alloc(16384 * 2);
    float* als  = (float*)alloc((size_t)N * HEADS * 4);
    float* ald  = (float*)alloc((size_t)N * HEADS * 4);
    float* xlo  = (float*)alloc((size_t)N * 2 * 4);
    float* alsoB = (float*)alloc((size_t)N * 4);
    float* aldoB = (float*)alloc((size_t)N * 4);

    hipMemsetAsync(cnt, 0, (size_t)N * 4, stream);
    hipMemsetAsync(gcur, 0, (size_t)NB * 4, stream);
    int gE = (E + 255) / 256;
    int nblk = (N + 1023) / 1024;
    count_k<<<gE, 256, 0, stream>>>(dstE, cnt, E);
    scan1_k<<<nblk, 256, 0, stream>>>(cnt, off, blk, N);
    scan2_k<<<1, 64, 0, stream>>>(blk, nblk);
    scan3_k<<<(N + 256) / 256, 256, 0, stream>>>(off, blk, N, E);
    binA_k<<<(E + 4095) / 4096, 256, 0, stream>>>(srcE, dstE, gcur, bbuf, E, NB);
    binB_k<<<NB, 256, 0, stream>>>(bbuf, gcur, off, csr);

    // conversions
    xconv_k<<<(N * 64 / 4 + 255) / 256, 256, 0, stream>>>(x, xh, N * 64 / 4);
    wconv4_k<<<192, 256, 0, stream>>>(rw, W1, W2, W3, rwf, W1f, W2f, W3f);

    int gG = (N + 63) / 64;   // MFMA gemm grid
    int gW = (N + 3) / 4;

    // ---- layer 1 (fused residual + W1 projection, MFMA) ----
    gemm_mfma_x<<<gG, 256, 0, stream>>>(xh, rwf, W1f, rb, as1, ad1, hbuf, xlh, als, ald, N);
    gat_fused<<<gW, 256, 0, stream>>>(xlh, als, ald, off, csr, b1, g1, be1, hbuf, hresh, N);

    // ---- layer 2 ----
    gemm_mfma_h<<<gG, 256, 0, stream>>>(hresh, W2f, as2, ad2, xlh, als, ald, N);
    gat_fused<<<gW, 256, 0, stream>>>(xlh, als, ald, off, csr, b2, g2, be2, hbuf, hresh, N);

    // ---- layer 3 ----
    gemm_mfma_h<<<gG, 256, 0, stream>>>(hresh, W3f, as3, ad3, xlh, als, ald, N);
    gat_fused<<<gW, 256, 0, stream>>>(xlh, als, ald, off, csr, b3, g3, be3, hbuf, nullptr, N);

    // ---- output layer ----
    out_proj<<<gW, 256, 0, stream>>>(hbuf, Wo, aso, ado, xlo, alsoB, aldoB, N);
    out_agg<<<gW, 256, 0, stream>>>(xlo, alsoB, aldoB, off, csr, bo, (float*)d_out, N);
}

// Round 9
// 285.856 us; speedup vs baseline: 2.8101x; 1.0725x over previous
//
#include <hip/hip_runtime.h>
#include <math.h>

#define HID 128
#define HEADS 4
#define NEG_SLOPE 0.2f
#define LN_EPS 1e-5f
#define BCAP 4096   // per-bucket capacity (avg 2046 for N=50K, E=800K)

typedef unsigned short ushortT;
typedef unsigned int uintT;
typedef __attribute__((ext_vector_type(8))) short bf16x8;
typedef __attribute__((ext_vector_type(4))) float f32x4;

__device__ __forceinline__ float lrelu(float v) { return v > 0.f ? v : NEG_SLOPE * v; }
__device__ __forceinline__ float bflo(uintT v) { return __uint_as_float(v << 16); }
__device__ __forceinline__ float bfhi(uintT v) { return __uint_as_float(v & 0xffff0000u); }

__device__ __forceinline__ ushortT f2bf(float f) {
    uintT u = __float_as_uint(f);
    u += 0x7fffu + ((u >> 16) & 1u);   // round-to-nearest-even
    return (ushortT)(u >> 16);
}

// ---------------- CSR build ----------------
__global__ __launch_bounds__(256) void count_k(const int* __restrict__ dst, int* __restrict__ cnt, int E) {
    int i = blockIdx.x * 256 + threadIdx.x;
    if (i < E) atomicAdd(&cnt[dst[i]], 1);
}

__global__ __launch_bounds__(256) void scan1_k(const int* __restrict__ cnt, int* __restrict__ off,
                                               int* __restrict__ blk, int Nn) {
    __shared__ int part[256];
    int t = threadIdx.x;
    int base = blockIdx.x * 1024 + t * 4;
    int v0 = base + 0 < Nn ? cnt[base + 0] : 0;
    int v1 = base + 1 < Nn ? cnt[base + 1] : 0;
    int v2 = base + 2 < Nn ? cnt[base + 2] : 0;
    int v3 = base + 3 < Nn ? cnt[base + 3] : 0;
    int s = v0 + v1 + v2 + v3;
    part[t] = s;
    __syncthreads();
    #pragma unroll
    for (int ofs = 1; ofs < 256; ofs <<= 1) {
        int p = (t >= ofs) ? part[t - ofs] : 0;
        __syncthreads();
        part[t] += p;
        __syncthreads();
    }
    int run = part[t] - s;
    if (base + 0 < Nn) off[base + 0] = run; run += v0;
    if (base + 1 < Nn) off[base + 1] = run; run += v1;
    if (base + 2 < Nn) off[base + 2] = run; run += v2;
    if (base + 3 < Nn) off[base + 3] = run;
    if (t == 255) blk[blockIdx.x] = part[255];
}

__global__ __launch_bounds__(64) void scan2_k(int* __restrict__ blk, int nblk) {
    int t = threadIdx.x;
    int v = t < nblk ? blk[t] : 0;
    int inc = v;
    #pragma unroll
    for (int ofs = 1; ofs < 64; ofs <<= 1) {
        int p = __shfl_up(inc, ofs, 64);
        if (t >= ofs) inc += p;
    }
    if (t < nblk) blk[t] = inc - v;
}

__global__ __launch_bounds__(256) void scan3_k(int* __restrict__ off, const int* __restrict__ blk, int Nn, int E) {
    int i = blockIdx.x * 256 + threadIdx.x;
    if (i < Nn) off[i] += blk[i >> 10];
    if (i == 0) off[Nn] = E;
}

// pass A: bin edges by dst>>7 into bucket buffer
__global__ __launch_bounds__(256) void binA_k(const int* __restrict__ src, const int* __restrict__ dst,
                                              int* __restrict__ gcur, int2* __restrict__ buf, int E, int NB) {
    __shared__ int hist[512];
    __shared__ int bbase[512];
    __shared__ int lcur[512];
    int t = threadIdx.x;
    for (int i = t; i < NB; i += 256) { hist[i] = 0; lcur[i] = 0; }
    __syncthreads();
    int e0 = blockIdx.x * 4096;
    int2 ed[16];
    #pragma unroll
    for (int j = 0; j < 16; ++j) {
        int idx = e0 + j * 256 + t;
        if (idx < E) {
            ed[j].x = src[idx];
            ed[j].y = dst[idx];
            atomicAdd(&hist[ed[j].y >> 7], 1);
        } else {
            ed[j].y = -1;
        }
    }
    __syncthreads();
    for (int i = t; i < NB; i += 256) {
        int c = hist[i];
        bbase[i] = c > 0 ? atomicAdd(&gcur[i], c) : 0;
    }
    __syncthreads();
    #pragma unroll
    for (int j = 0; j < 16; ++j) {
        if (ed[j].y >= 0) {
            int b = ed[j].y >> 7;
            int pos = bbase[b] + atomicAdd(&lcur[b], 1);
            buf[(size_t)b * BCAP + pos] = ed[j];
        }
    }
}

// pass B: per-bucket scatter into csr
__global__ __launch_bounds__(256) void binB_k(const int2* __restrict__ buf, const int* __restrict__ gcnt,
                                              const int* __restrict__ off, int* __restrict__ csr) {
    __shared__ int lcur[128];
    int t = threadIdx.x, b = blockIdx.x;
    if (t < 128) lcur[t] = 0;
    __syncthreads();
    int nb = gcnt[b];
    int nodebase = b << 7;
    for (int i = t; i < nb; i += 256) {
        int2 e = buf[(size_t)b * BCAP + i];
        int p = off[e.y] + atomicAdd(&lcur[e.y - nodebase], 1);
        csr[p] = e.x;
    }
}

// ---------------- conversions ----------------
__global__ __launch_bounds__(256) void xconv_k(const float* __restrict__ x, ushortT* __restrict__ xh, int n4) {
    int i = blockIdx.x * 256 + threadIdx.x;
    if (i < n4) {
        float4 v = *(const float4*)&x[(size_t)i * 4];
        ushort4 o;
        o.x = f2bf(v.x); o.y = f2bf(v.y); o.z = f2bf(v.z); o.w = f2bf(v.w);
        *(ushort4*)&xh[(size_t)i * 4] = o;
    }
}

// convert 4 weight matrices into MFMA B-fragment layout
__global__ __launch_bounds__(256) void wconv4_k(const float* __restrict__ rw, const float* __restrict__ W1,
                                                const float* __restrict__ W2, const float* __restrict__ W3,
                                                ushortT* __restrict__ rwf, ushortT* __restrict__ W1f,
                                                ushortT* __restrict__ W2f, ushortT* __restrict__ W3f) {
    int id = blockIdx.x * 256 + threadIdx.x;
    const float* Wsrc; ushortT* Wdst; int kdiv; int lid;
    if (id < 8192)        { Wsrc = rw; Wdst = rwf; kdiv = 2; lid = id; }
    else if (id < 16384)  { Wsrc = W1; Wdst = W1f; kdiv = 2; lid = id - 8192; }
    else if (id < 32768)  { Wsrc = W2; Wdst = W2f; kdiv = 4; lid = id - 16384; }
    else if (id < 49152)  { Wsrc = W3; Wdst = W3f; kdiv = 4; lid = id - 32768; }
    else return;
    int i = lid & 7;
    int lane = (lid >> 3) & 63;
    int rest = lid >> 9;            // j*kdiv + ks
    int ks = rest % kdiv;
    int j = rest / kdiv;
    int k = ks * 32 + (lane >> 4) * 8 + i;
    int n = j * 16 + (lane & 15);
    Wdst[lid] = f2bf(Wsrc[k * HID + n]);
}

// ---------------- MFMA GEMM (x layer): dual output rw->Cres(+rb) and W1->Ch + attn dots ----------------
__global__ __launch_bounds__(256) void gemm_mfma_x(
        const ushortT* __restrict__ Ah, const ushortT* __restrict__ rwf, const ushortT* __restrict__ W1f,
        const float* __restrict__ rb, const float* __restrict__ a_srcp, const float* __restrict__ a_dstp,
        float* __restrict__ Cres, ushortT* __restrict__ Ch,
        float* __restrict__ als, float* __restrict__ ald, int M) {
    int t = threadIdx.x;
    int wave = t >> 6, lane = t & 63;
    int row0 = blockIdx.x * 64 + wave * 16;
    int cl = lane & 15, grp = lane >> 4;
    int rA = row0 + cl;
    f32x4 accR[8] = {};
    f32x4 acc1[8] = {};
    #pragma unroll
    for (int ks = 0; ks < 2; ++ks) {
        bf16x8 afr = {};
        if (rA < M) afr = *(const bf16x8*)&Ah[(size_t)rA * 64 + ks * 32 + grp * 8];
        #pragma unroll
        for (int j = 0; j < 8; ++j) {
            bf16x8 br = *(const bf16x8*)&rwf[(((size_t)j * 2 + ks) * 64 + lane) * 8];
            accR[j] = __builtin_amdgcn_mfma_f32_16x16x32_bf16(afr, br, accR[j], 0, 0, 0);
            bf16x8 b1 = *(const bf16x8*)&W1f[(((size_t)j * 2 + ks) * 64 + lane) * 8];
            acc1[j] = __builtin_amdgcn_mfma_f32_16x16x32_bf16(afr, b1, acc1[j], 0, 0, 0);
        }
    }
    float asv[8], adv[8], rbv[8];
    #pragma unroll
    for (int j = 0; j < 8; ++j) {
        asv[j] = a_srcp[j * 16 + cl];
        adv[j] = a_dstp[j * 16 + cl];
        rbv[j] = rb[j * 16 + cl];
    }
    #pragma unroll
    for (int reg = 0; reg < 4; ++reg) {
        int r = row0 + grp * 4 + reg;
        bool ok = r < M;
        if (ok) {
            #pragma unroll
            for (int j = 0; j < 8; ++j) {
                Cres[(size_t)r * HID + j * 16 + cl] = accR[j][reg] + rbv[j];
                Ch[(size_t)r * HID + j * 16 + cl] = f2bf(acc1[j][reg]);
            }
        }
        float ps[4], pd[4];
        #pragma unroll
        for (int h = 0; h < 4; ++h) {
            ps[h] = acc1[2 * h][reg] * asv[2 * h] + acc1[2 * h + 1][reg] * asv[2 * h + 1];
            pd[h] = acc1[2 * h][reg] * adv[2 * h] + acc1[2 * h + 1][reg] * adv[2 * h + 1];
        }
        #pragma unroll
        for (int m = 1; m < 16; m <<= 1) {
            #pragma unroll
            for (int h = 0; h < 4; ++h) {
                ps[h] += __shfl_xor(ps[h], m, 64);
                pd[h] += __shfl_xor(pd[h], m, 64);
            }
        }
        if (cl == 0 && ok) {
            *(float4*)&als[(size_t)r * 4] = make_float4(ps[0], ps[1], ps[2], ps[3]);
            *(float4*)&ald[(size_t)r * 4] = make_float4(pd[0], pd[1], pd[2], pd[3]);
        }
    }
}

// ---------------- MFMA GEMM (hidden layers, K=128): Ch + attn dots ----------------
__global__ __launch_bounds__(256) void gemm_mfma_h(
        const ushortT* __restrict__ Ah, const ushortT* __restrict__ Wf,
        const float* __restrict__ a_srcp, const float* __restrict__ a_dstp,
        ushortT* __restrict__ Ch, float* __restrict__ als, float* __restrict__ ald, int M) {
    int t = threadIdx.x;
    int wave = t >> 6, lane = t & 63;
    int row0 = blockIdx.x * 64 + wave * 16;
    int cl = lane & 15, grp = lane >> 4;
    int rA = row0 + cl;
    f32x4 acc[8] = {};
    #pragma unroll
    for (int ks = 0; ks < 4; ++ks) {
        bf16x8 afr = {};
        if (rA < M) afr = *(const bf16x8*)&Ah[(size_t)rA * HID + ks * 32 + grp * 8];
        #pragma unroll
        for (int j = 0; j < 8; ++j) {
            bf16x8 br = *(const bf16x8*)&Wf[(((size_t)j * 4 + ks) * 64 + lane) * 8];
            acc[j] = __builtin_amdgcn_mfma_f32_16x16x32_bf16(afr, br, acc[j], 0, 0, 0);
        }
    }
    float asv[8], adv[8];
    #pragma unroll
    for (int j = 0; j < 8; ++j) {
        asv[j] = a_srcp[j * 16 + cl];
        adv[j] = a_dstp[j * 16 + cl];
    }
    #pragma unroll
    for (int reg = 0; reg < 4; ++reg) {
        int r = row0 + grp * 4 + reg;
        bool ok = r < M;
        if (ok) {
            #pragma unroll
            for (int j = 0; j < 8; ++j)
                Ch[(size_t)r * HID + j * 16 + cl] = f2bf(acc[j][reg]);
        }
        float ps[4], pd[4];
        #pragma unroll
        for (int h = 0; h < 4; ++h) {
            ps[h] = acc[2 * h][reg] * asv[2 * h] + acc[2 * h + 1][reg] * asv[2 * h + 1];
            pd[h] = acc[2 * h][reg] * adv[2 * h] + acc[2 * h + 1][reg] * adv[2 * h + 1];
        }
        #pragma unroll
        for (int m = 1; m < 16; m <<= 1) {
            #pragma unroll
            for (int h = 0; h < 4; ++h) {
                ps[h] += __shfl_xor(ps[h], m, 64);
                pd[h] += __shfl_xor(pd[h], m, 64);
            }
        }
        if (cl == 0 && ok) {
            *(float4*)&als[(size_t)r * 4] = make_float4(ps[0], ps[1], ps[2], ps[3]);
            *(float4*)&ald[(size_t)r * 4] = make_float4(pd[0], pd[1], pd[2], pd[3]);
        }
    }
}

// ---------------- fully fused GAT: single-pass online softmax + LN + ReLU + residual ----------------
// 2-edge unrolled gather (batched loads -> 2 row-loads in flight per slot).
// If Wo != nullptr (final layer): fuse the output projection, skip hres store.
__global__ __launch_bounds__(256) void gat_fused(
        const ushortT* __restrict__ xlh, const float* __restrict__ als,
        const float* __restrict__ ald, const int* __restrict__ off,
        const int* __restrict__ csr, const float* __restrict__ bias,
        const float* __restrict__ g, const float* __restrict__ be,
        float* __restrict__ hres, ushortT* __restrict__ hresh,
        const float* __restrict__ Wo, const float* __restrict__ aso, const float* __restrict__ ado,
        float* __restrict__ xlo, float* __restrict__ alsoB, float* __restrict__ aldoB, int Nn) {
    int gid = blockIdx.x * 256 + threadIdx.x;
    int wid = gid >> 6, lane = threadIdx.x & 63;
    if (wid >= Nn) return;
    int q = lane >> 4;
    int cl = lane & 15;
    int h = cl >> 2;
    float aldh = ald[wid * 4 + h];
    float eh = lrelu(als[wid * 4 + h] + aldh);   // self logit = softmax shift
    int b = off[wid], e = off[wid + 1];
    float acc[8] = {};
    float dsum = 0.f;
    int c = b + q;
    // main: 2 edges per slot iteration, loads batched before use
    for (; c + 4 < e; c += 8) {
        int s0 = csr[c];
        int s1 = csr[c + 4];
        float al0 = als[(size_t)s0 * 4 + h];
        float al1 = als[(size_t)s1 * 4 + h];
        uint4 hv0 = *(const uint4*)&xlh[(size_t)s0 * HID + cl * 8];
        uint4 hv1 = *(const uint4*)&xlh[(size_t)s1 * HID + cl * 8];
        float w0 = __expf(lrelu(al0 + aldh) - eh);
        float w1 = __expf(lrelu(al1 + aldh) - eh);
        dsum += w0 + w1;
        acc[0] = fmaf(w0, bflo(hv0.x), acc[0]);
        acc[1] = fmaf(w0, bfhi(hv0.x), acc[1]);
        acc[2] = fmaf(w0, bflo(hv0.y), acc[2]);
        acc[3] = fmaf(w0, bfhi(hv0.y), acc[3]);
        acc[4] = fmaf(w0, bflo(hv0.z), acc[4]);
        acc[5] = fmaf(w0, bfhi(hv0.z), acc[5]);
        acc[6] = fmaf(w0, bflo(hv0.w), acc[6]);
        acc[7] = fmaf(w0, bfhi(hv0.w), acc[7]);
        acc[0] = fmaf(w1, bflo(hv1.x), acc[0]);
        acc[1] = fmaf(w1, bfhi(hv1.x), acc[1]);
        acc[2] = fmaf(w1, bflo(hv1.y), acc[2]);
        acc[3] = fmaf(w1, bfhi(hv1.y), acc[3]);
        acc[4] = fmaf(w1, bflo(hv1.z), acc[4]);
        acc[5] = fmaf(w1, bfhi(hv1.z), acc[5]);
        acc[6] = fmaf(w1, bflo(hv1.w), acc[6]);
        acc[7] = fmaf(w1, bfhi(hv1.w), acc[7]);
    }
    if (c < e) {
        int s = csr[c];
        float al = als[(size_t)s * 4 + h];
        uint4 hv = *(const uint4*)&xlh[(size_t)s * HID + cl * 8];
        float w = __expf(lrelu(al + aldh) - eh);
        dsum += w;
        acc[0] = fmaf(w, bflo(hv.x), acc[0]);
        acc[1] = fmaf(w, bfhi(hv.x), acc[1]);
        acc[2] = fmaf(w, bflo(hv.y), acc[2]);
        acc[3] = fmaf(w, bfhi(hv.y), acc[3]);
        acc[4] = fmaf(w, bflo(hv.z), acc[4]);
        acc[5] = fmaf(w, bfhi(hv.z), acc[5]);
        acc[6] = fmaf(w, bflo(hv.w), acc[6]);
        acc[7] = fmaf(w, bfhi(hv.w), acc[7]);
    }
    #pragma unroll
    for (int k = 0; k < 8; ++k) {
        acc[k] += __shfl_xor(acc[k], 16, 64);
        acc[k] += __shfl_xor(acc[k], 32, 64);
    }
    dsum += __shfl_xor(dsum, 16, 64);
    dsum += __shfl_xor(dsum, 32, 64);
    float inv = 1.f / (dsum + 1.f + 1e-16f);     // self weight = exp(0) = 1
    uint4 sv = *(const uint4*)&xlh[(size_t)wid * HID + cl * 8];
    float sx[8];
    sx[0] = bflo(sv.x); sx[1] = bfhi(sv.x);
    sx[2] = bflo(sv.y); sx[3] = bfhi(sv.y);
    sx[4] = bflo(sv.z); sx[5] = bfhi(sv.z);
    sx[6] = bflo(sv.w); sx[7] = bfhi(sv.w);
    float4 bi0 = *(const float4*)&bias[cl * 8];
    float4 bi1 = *(const float4*)&bias[cl * 8 + 4];
    float o[8];
    #pragma unroll
    for (int k = 0; k < 8; ++k) {
        float bb = k < 4 ? (&bi0.x)[k] : (&bi1.x)[k - 4];
        o[k] = fmaf(acc[k] + sx[k], inv, bb);
    }
    float s1 = o[0] + o[1] + o[2] + o[3] + o[4] + o[5] + o[6] + o[7];
    #pragma unroll
    for (int m = 1; m < 16; m <<= 1) s1 += __shfl_xor(s1, m, 64);
    float mu = s1 * (1.0f / HID);
    float qv = 0.f;
    #pragma unroll
    for (int k = 0; k < 8; ++k) { float d = o[k] - mu; qv += d * d; }
    #pragma unroll
    for (int m = 1; m < 16; m <<= 1) qv += __shfl_xor(qv, m, 64);
    float rs = rsqrtf(qv * (1.0f / HID) + LN_EPS);
    if (q == 0) {
        float4 g0 = *(const float4*)&g[cl * 8];
        float4 g1 = *(const float4*)&g[cl * 8 + 4];
        float4 be0 = *(const float4*)&be[cl * 8];
        float4 be1 = *(const float4*)&be[cl * 8 + 4];
        float4 r0 = *(const float4*)&hres[(size_t)wid * HID + cl * 8];
        float4 r1 = *(const float4*)&hres[(size_t)wid * HID + cl * 8 + 4];
        float w[8];
        #pragma unroll
        for (int k = 0; k < 8; ++k) {
            float gg = k < 4 ? (&g0.x)[k] : (&g1.x)[k - 4];
            float ee = k < 4 ? (&be0.x)[k] : (&be1.x)[k - 4];
            float rr = k < 4 ? (&r0.x)[k] : (&r1.x)[k - 4];
            w[k] = fmaxf((o[k] - mu) * rs * gg + ee, 0.f) + rr;
        }
        if (Wo) {
            // fused output projection: p = h_row @ Wo  (HID x 2)
            float p0 = 0.f, p1 = 0.f;
            #pragma unroll
            for (int k = 0; k < 8; ++k) {
                int ch = cl * 8 + k;
                p0 = fmaf(w[k], Wo[ch * 2 + 0], p0);
                p1 = fmaf(w[k], Wo[ch * 2 + 1], p1);
            }
            #pragma unroll
            for (int m = 1; m < 16; m <<= 1) {
                p0 += __shfl_xor(p0, m, 64);
                p1 += __shfl_xor(p1, m, 64);
            }
            if (cl == 0) {
                xlo[wid * 2 + 0] = p0;
                xlo[wid * 2 + 1] = p1;
                alsoB[wid] = p0 * aso[0] + p1 * aso[1];
                aldoB[wid] = p0 * ado[0] + p1 * ado[1];
            }
        } else {
            *(float4*)&hres[(size_t)wid * HID + cl * 8] = make_float4(w[0], w[1], w[2], w[3]);
            *(float4*)&hres[(size_t)wid * HID + cl * 8 + 4] = make_float4(w[4], w[5], w[6], w[7]);
            ushort4 hv0, hv1;
            hv0.x = f2bf(w[0]); hv0.y = f2bf(w[1]); hv0.z = f2bf(w[2]); hv0.w = f2bf(w[3]);
            hv1.x = f2bf(w[4]); hv1.y = f2bf(w[5]); hv1.z = f2bf(w[6]); hv1.w = f2bf(w[7]);
            *(ushort4*)&hresh[(size_t)wid * HID + cl * 8] = hv0;
            *(ushort4*)&hresh[(size_t)wid * HID + cl * 8 + 4] = hv1;
        }
    }
}

// ---------------- output aggregation ----------------
__global__ __launch_bounds__(256) void out_agg(const float* __restrict__ xlo, const float* __restrict__ also,
                                               const float* __restrict__ aldo, const int* __restrict__ off,
                                               const int* __restrict__ csr, const float* __restrict__ bo,
                                               float* __restrict__ out, int Nn) {
    int gid = blockIdx.x * 256 + threadIdx.x;
    int wid = gid >> 6, lane = threadIdx.x & 63;
    if (wid >= Nn) return;
    float aldn = aldo[wid];
    float eself = lrelu(also[wid] + aldn);
    int b = off[wid], e = off[wid + 1];
    float dl = 0.f, a0 = 0.f, a1 = 0.f;
    for (int j = b + lane; j < e; j += 64) {
        int s = csr[j];
        float w = __expf(lrelu(also[s] + aldn) - eself);
        dl += w;
        a0 += w * xlo[s * 2 + 0];
        a1 += w * xlo[s * 2 + 1];
    }
    #pragma unroll
    for (int m = 1; m < 64; m <<= 1) {
        dl += __shfl_xor(dl, m, 64);
        a0 += __shfl_xor(a0, m, 64);
        a1 += __shfl_xor(a1, m, 64);
    }
    if (lane == 0) {
        dl += 1.f;   // self weight exp(0)
        a0 += xlo[wid * 2 + 0];
        a1 += xlo[wid * 2 + 1];
        float inv = 1.f / (dl + 1e-16f);
        out[wid * 2 + 0] = a0 * inv + bo[0];
        out[wid * 2 + 1] = a1 * inv + bo[1];
    }
}

extern "C" void kernel_launch(void* const* d_in, const int* in_sizes, int n_in,
                              void* d_out, int out_size, void* d_ws, size_t ws_size,
                              hipStream_t stream) {
    const float* x   = (const float*)d_in[0];
    const int*   ei  = (const int*)d_in[1];
    const float* W1  = (const float*)d_in[2];
    const float* as1 = (const float*)d_in[3];
    const float* ad1 = (const float*)d_in[4];
    const float* b1  = (const float*)d_in[5];
    const float* g1  = (const float*)d_in[6];
    const float* be1 = (const float*)d_in[7];
    const float* rw  = (const float*)d_in[8];
    const float* rb  = (const float*)d_in[9];
    const float* W2  = (const float*)d_in[10];
    const float* as2 = (const float*)d_in[11];
    const float* ad2 = (const float*)d_in[12];
    const float* b2  = (const float*)d_in[13];
    const float* g2  = (const float*)d_in[14];
    const float* be2 = (const float*)d_in[15];
    const float* W3  = (const float*)d_in[16];
    const float* as3 = (const float*)d_in[17];
    const float* ad3 = (const float*)d_in[18];
    const float* b3  = (const float*)d_in[19];
    const float* g3  = (const float*)d_in[20];
    const float* be3 = (const float*)d_in[21];
    const float* Wo  = (const float*)d_in[22];
    const float* aso = (const float*)d_in[23];
    const float* ado = (const float*)d_in[24];
    const float* bo  = (const float*)d_in[25];

    int N = in_sizes[0] / 64;   // 50000
    int E = in_sizes[1] / 2;    // 800000
    const int* srcE = ei;
    const int* dstE = ei + E;
    int NB = (N + 127) >> 7;    // 391 buckets

    char* w = (char*)d_ws;
    auto alloc = [&](size_t b) { char* p = w; w += (b + 255) & ~(size_t)255; return p; };
    int* cnt    = (int*)alloc((size_t)N * 4);
    int* off    = (int*)alloc((size_t)(N + 1) * 4);
    int* gcur   = (int*)alloc((size_t)NB * 4);
    int* blk    = (int*)alloc(((size_t)N / 1024 + 2) * 4);
    int* csr    = (int*)alloc((size_t)E * 4);
    int2* bbuf  = (int2*)alloc((size_t)NB * BCAP * 8);
    float* hbuf = (float*)alloc((size_t)N * HID * 4);
    ushortT* hresh = (ushortT*)alloc((size_t)N * HID * 2);
    ushortT* xlh = (ushortT*)alloc((size_t)N * HID * 2);
    ushortT* xh  = (ushortT*)alloc((size_t)N * 64 * 2);
    ushortT* rwf = (ushortT*)alloc(8192 * 2);
    ushortT* W1f = (ushortT*)alloc(8192 * 2);
    ushortT* W2f = (ushortT*)alloc(16384 * 2);
    ushortT* W3f = (ushortT*)alloc(16384 * 2);
    float* als  = (float*)alloc((size_t)N * HEADS * 4);
    float* ald  = (float*)alloc((size_t)N * HEADS * 4);
    float* xlo  = (float*)alloc((size_t)N * 2 * 4);
    float* alsoB = (float*)alloc((size_t)N * 4);
    float* aldoB = (float*)alloc((size_t)N * 4);

    hipMemsetAsync(cnt, 0, (size_t)N * 4, stream);
    hipMemsetAsync(gcur, 0, (size_t)NB * 4, stream);
    int gE = (E + 255) / 256;
    int nblk = (N + 1023) / 1024;
    count_k<<<gE, 256, 0, stream>>>(dstE, cnt, E);
    scan1_k<<<nblk, 256, 0, stream>>>(cnt, off, blk, N);
    scan2_k<<<1, 64, 0, stream>>>(blk, nblk);
    scan3_k<<<(N + 256) / 256, 256, 0, stream>>>(off, blk, N, E);
    binA_k<<<(E + 4095) / 4096, 256, 0, stream>>>(srcE, dstE, gcur, bbuf, E, NB);
    binB_k<<<NB, 256, 0, stream>>>(bbuf, gcur, off, csr);

    // conversions
    xconv_k<<<(N * 64 / 4 + 255) / 256, 256, 0, stream>>>(x, xh, N * 64 / 4);
    wconv4_k<<<192, 256, 0, stream>>>(rw, W1, W2, W3, rwf, W1f, W2f, W3f);

    int gG = (N + 63) / 64;   // MFMA gemm grid
    int gW = (N + 3) / 4;

    // ---- layer 1 (fused residual + W1 projection, MFMA) ----
    gemm_mfma_x<<<gG, 256, 0, stream>>>(xh, rwf, W1f, rb, as1, ad1, hbuf, xlh, als, ald, N);
    gat_fused<<<gW, 256, 0, stream>>>(xlh, als, ald, off, csr, b1, g1, be1, hbuf, hresh,
                                      nullptr, nullptr, nullptr, nullptr, nullptr, nullptr, N);

    // ---- layer 2 ----
    gemm_mfma_h<<<gG, 256, 0, stream>>>(hresh, W2f, as2, ad2, xlh, als, ald, N);
    gat_fused<<<gW, 256, 0, stream>>>(xlh, als, ald, off, csr, b2, g2, be2, hbuf, hresh,
                                      nullptr, nullptr, nullptr, nullptr, nullptr, nullptr, N);

    // ---- layer 3 (fused output projection) ----
    gemm_mfma_h<<<gG, 256, 0, stream>>>(hresh, W3f, as3, ad3, xlh, als, ald, N);
    gat_fused<<<gW, 256, 0, stream>>>(xlh, als, ald, off, csr, b3, g3, be3, hbuf, nullptr,
                                      Wo, aso, ado, xlo, alsoB, aldoB, N);

    // ---- output aggregation ----
    out_agg<<<gW, 256, 0, stream>>>(xlo, alsoB, aldoB, off, csr, bo, (float*)d_out, N);
}

// Round 10
// 252.437 us; speedup vs baseline: 3.1821x; 1.1324x over previous
//
#include <hip/hip_runtime.h>
#include <math.h>

#define HID 128
#define HEADS 4
#define NEG_SLOPE 0.2f
#define LN_EPS 1e-5f
#define BCAP 4096   // per-bucket capacity (avg 2046 for N=50K, E=800K)

typedef unsigned short ushortT;
typedef unsigned int uintT;
typedef __attribute__((ext_vector_type(8))) short bf16x8;
typedef __attribute__((ext_vector_type(4))) float f32x4;

__device__ __forceinline__ float lrelu(float v) { return v > 0.f ? v : NEG_SLOPE * v; }
__device__ __forceinline__ float bflo(uintT v) { return __uint_as_float(v << 16); }
__device__ __forceinline__ float bfhi(uintT v) { return __uint_as_float(v & 0xffff0000u); }

__device__ __forceinline__ ushortT f2bf(float f) {
    uintT u = __float_as_uint(f);
    u += 0x7fffu + ((u >> 16) & 1u);   // round-to-nearest-even
    return (ushortT)(u >> 16);
}

// ---------------- edge binning (pass A): bin edges by dst>>7; gcur ends as per-bucket counts ----------------
__global__ __launch_bounds__(256) void binA_k(const int* __restrict__ src, const int* __restrict__ dst,
                                              int* __restrict__ gcur, int2* __restrict__ buf, int E, int NB) {
    __shared__ int hist[512];
    __shared__ int bbase[512];
    __shared__ int lcur[512];
    int t = threadIdx.x;
    for (int i = t; i < NB; i += 256) { hist[i] = 0; lcur[i] = 0; }
    __syncthreads();
    int e0 = blockIdx.x * 4096;
    int2 ed[16];
    #pragma unroll
    for (int j = 0; j < 16; ++j) {
        int idx = e0 + j * 256 + t;
        if (idx < E) {
            ed[j].x = src[idx];
            ed[j].y = dst[idx];
            atomicAdd(&hist[ed[j].y >> 7], 1);
        } else {
            ed[j].y = -1;
        }
    }
    __syncthreads();
    for (int i = t; i < NB; i += 256) {
        int c = hist[i];
        bbase[i] = c > 0 ? atomicAdd(&gcur[i], c) : 0;
    }
    __syncthreads();
    #pragma unroll
    for (int j = 0; j < 16; ++j) {
        if (ed[j].y >= 0) {
            int b = ed[j].y >> 7;
            int pos = bbase[b] + atomicAdd(&lcur[b], 1);
            buf[(size_t)b * BCAP + pos] = ed[j];
        }
    }
}

// ---------------- scan bucket totals (one wave, NB <= 512) ----------------
__global__ __launch_bounds__(64) void scanB_k(const int* __restrict__ bcnt, int* __restrict__ bbase, int NB) {
    int t = threadIdx.x;
    int carry = 0;
    for (int base = 0; base < NB; base += 64) {
        int idx = base + t;
        int v = idx < NB ? bcnt[idx] : 0;
        int inc = v;
        #pragma unroll
        for (int ofs = 1; ofs < 64; ofs <<= 1) {
            int p = __shfl_up(inc, ofs, 64);
            if (t >= ofs) inc += p;
        }
        if (idx < NB) bbase[idx] = carry + inc - v;   // exclusive
        carry += __shfl(inc, 63, 64);
    }
}

// ---------------- pass B: per-bucket node count + scan -> off[], then scatter csr ----------------
__global__ __launch_bounds__(256) void binB_k(const int2* __restrict__ buf, const int* __restrict__ bcnt,
                                              const int* __restrict__ bbase, int* __restrict__ off,
                                              int* __restrict__ csr, int Nn, int E) {
    __shared__ int cnt[128];
    __shared__ int pre[128];
    __shared__ int cur[128];
    int t = threadIdx.x, b = blockIdx.x;
    if (t < 128) cnt[t] = 0;
    __syncthreads();
    int nb = bcnt[b];
    int base = bbase[b];
    int nodebase = b << 7;
    for (int i = t; i < nb; i += 256)
        atomicAdd(&cnt[buf[(size_t)b * BCAP + i].y - nodebase], 1);
    __syncthreads();
    if (t < 128) pre[t] = cnt[t];
    __syncthreads();
    #pragma unroll
    for (int ofs = 1; ofs < 128; ofs <<= 1) {
        int v = 0;
        if (t < 128 && t >= ofs) v = pre[t - ofs];
        __syncthreads();
        if (t < 128) pre[t] += v;
        __syncthreads();
    }
    if (t < 128) {
        int node = nodebase + t;
        int o = base + pre[t] - cnt[t];   // exclusive prefix
        if (node < Nn) off[node] = o;
        cur[t] = o;
    }
    if (b == 0 && t == 0) off[Nn] = E;
    __syncthreads();
    for (int i = t; i < nb; i += 256) {
        int2 e = buf[(size_t)b * BCAP + i];
        int p = atomicAdd(&cur[e.y - nodebase], 1);
        csr[p] = e.x;
    }
}

// ---------------- weight conversion into MFMA B-fragment layout ----------------
__global__ __launch_bounds__(256) void wconv4_k(const float* __restrict__ rw, const float* __restrict__ W1,
                                                const float* __restrict__ W2, const float* __restrict__ W3,
                                                ushortT* __restrict__ rwf, ushortT* __restrict__ W1f,
                                                ushortT* __restrict__ W2f, ushortT* __restrict__ W3f) {
    int id = blockIdx.x * 256 + threadIdx.x;
    const float* Wsrc; ushortT* Wdst; int kdiv; int lid;
    if (id < 8192)        { Wsrc = rw; Wdst = rwf; kdiv = 2; lid = id; }
    else if (id < 16384)  { Wsrc = W1; Wdst = W1f; kdiv = 2; lid = id - 8192; }
    else if (id < 32768)  { Wsrc = W2; Wdst = W2f; kdiv = 4; lid = id - 16384; }
    else if (id < 49152)  { Wsrc = W3; Wdst = W3f; kdiv = 4; lid = id - 32768; }
    else return;
    int i = lid & 7;
    int lane = (lid >> 3) & 63;
    int rest = lid >> 9;            // j*kdiv + ks
    int ks = rest % kdiv;
    int j = rest / kdiv;
    int k = ks * 32 + (lane >> 4) * 8 + i;
    int n = j * 16 + (lane & 15);
    Wdst[lid] = f2bf(Wsrc[k * HID + n]);
}

// ---------------- MFMA GEMM (x layer, K=64): inline fp32->bf16 A, dual output + attn dots ----------------
__global__ __launch_bounds__(256) void gemm_mfma_x(
        const float* __restrict__ X, const ushortT* __restrict__ rwf, const ushortT* __restrict__ W1f,
        const float* __restrict__ rb, const float* __restrict__ a_srcp, const float* __restrict__ a_dstp,
        float* __restrict__ Cres, ushortT* __restrict__ Ch,
        float* __restrict__ als, float* __restrict__ ald, int M) {
    int t = threadIdx.x;
    int wave = t >> 6, lane = t & 63;
    int row0 = blockIdx.x * 64 + wave * 16;
    int cl = lane & 15, grp = lane >> 4;
    int rA = row0 + cl;
    f32x4 accR[8] = {};
    f32x4 acc1[8] = {};
    #pragma unroll
    for (int ks = 0; ks < 2; ++ks) {
        bf16x8 afr = {};
        if (rA < M) {
            const float* xr = &X[(size_t)rA * 64 + ks * 32 + grp * 8];
            float4 a0 = *(const float4*)xr;
            float4 a1 = *(const float4*)(xr + 4);
            afr[0] = (short)f2bf(a0.x); afr[1] = (short)f2bf(a0.y);
            afr[2] = (short)f2bf(a0.z); afr[3] = (short)f2bf(a0.w);
            afr[4] = (short)f2bf(a1.x); afr[5] = (short)f2bf(a1.y);
            afr[6] = (short)f2bf(a1.z); afr[7] = (short)f2bf(a1.w);
        }
        #pragma unroll
        for (int j = 0; j < 8; ++j) {
            bf16x8 br = *(const bf16x8*)&rwf[(((size_t)j * 2 + ks) * 64 + lane) * 8];
            accR[j] = __builtin_amdgcn_mfma_f32_16x16x32_bf16(afr, br, accR[j], 0, 0, 0);
            bf16x8 b1 = *(const bf16x8*)&W1f[(((size_t)j * 2 + ks) * 64 + lane) * 8];
            acc1[j] = __builtin_amdgcn_mfma_f32_16x16x32_bf16(afr, b1, acc1[j], 0, 0, 0);
        }
    }
    float asv[8], adv[8], rbv[8];
    #pragma unroll
    for (int j = 0; j < 8; ++j) {
        asv[j] = a_srcp[j * 16 + cl];
        adv[j] = a_dstp[j * 16 + cl];
        rbv[j] = rb[j * 16 + cl];
    }
    #pragma unroll
    for (int reg = 0; reg < 4; ++reg) {
        int r = row0 + grp * 4 + reg;
        bool ok = r < M;
        if (ok) {
            #pragma unroll
            for (int j = 0; j < 8; ++j) {
                Cres[(size_t)r * HID + j * 16 + cl] = accR[j][reg] + rbv[j];
                Ch[(size_t)r * HID + j * 16 + cl] = f2bf(acc1[j][reg]);
            }
        }
        float ps[4], pd[4];
        #pragma unroll
        for (int h = 0; h < 4; ++h) {
            ps[h] = acc1[2 * h][reg] * asv[2 * h] + acc1[2 * h + 1][reg] * asv[2 * h + 1];
            pd[h] = acc1[2 * h][reg] * adv[2 * h] + acc1[2 * h + 1][reg] * adv[2 * h + 1];
        }
        #pragma unroll
        for (int m = 1; m < 16; m <<= 1) {
            #pragma unroll
            for (int h = 0; h < 4; ++h) {
                ps[h] += __shfl_xor(ps[h], m, 64);
                pd[h] += __shfl_xor(pd[h], m, 64);
            }
        }
        if (cl == 0 && ok) {
            *(float4*)&als[(size_t)r * 4] = make_float4(ps[0], ps[1], ps[2], ps[3]);
            *(float4*)&ald[(size_t)r * 4] = make_float4(pd[0], pd[1], pd[2], pd[3]);
        }
    }
}

// ---------------- MFMA GEMM (hidden layers, K=128): Ch + attn dots ----------------
__global__ __launch_bounds__(256) void gemm_mfma_h(
        const ushortT* __restrict__ Ah, const ushortT* __restrict__ Wf,
        const float* __restrict__ a_srcp, const float* __restrict__ a_dstp,
        ushortT* __restrict__ Ch, float* __restrict__ als, float* __restrict__ ald, int M) {
    int t = threadIdx.x;
    int wave = t >> 6, lane = t & 63;
    int row0 = blockIdx.x * 64 + wave * 16;
    int cl = lane & 15, grp = lane >> 4;
    int rA = row0 + cl;
    f32x4 acc[8] = {};
    #pragma unroll
    for (int ks = 0; ks < 4; ++ks) {
        bf16x8 afr = {};
        if (rA < M) afr = *(const bf16x8*)&Ah[(size_t)rA * HID + ks * 32 + grp * 8];
        #pragma unroll
        for (int j = 0; j < 8; ++j) {
            bf16x8 br = *(const bf16x8*)&Wf[(((size_t)j * 4 + ks) * 64 + lane) * 8];
            acc[j] = __builtin_amdgcn_mfma_f32_16x16x32_bf16(afr, br, acc[j], 0, 0, 0);
        }
    }
    float asv[8], adv[8];
    #pragma unroll
    for (int j = 0; j < 8; ++j) {
        asv[j] = a_srcp[j * 16 + cl];
        adv[j] = a_dstp[j * 16 + cl];
    }
    #pragma unroll
    for (int reg = 0; reg < 4; ++reg) {
        int r = row0 + grp * 4 + reg;
        bool ok = r < M;
        if (ok) {
            #pragma unroll
            for (int j = 0; j < 8; ++j)
                Ch[(size_t)r * HID + j * 16 + cl] = f2bf(acc[j][reg]);
        }
        float ps[4], pd[4];
        #pragma unroll
        for (int h = 0; h < 4; ++h) {
            ps[h] = acc[2 * h][reg] * asv[2 * h] + acc[2 * h + 1][reg] * asv[2 * h + 1];
            pd[h] = acc[2 * h][reg] * adv[2 * h] + acc[2 * h + 1][reg] * adv[2 * h + 1];
        }
        #pragma unroll
        for (int m = 1; m < 16; m <<= 1) {
            #pragma unroll
            for (int h = 0; h < 4; ++h) {
                ps[h] += __shfl_xor(ps[h], m, 64);
                pd[h] += __shfl_xor(pd[h], m, 64);
            }
        }
        if (cl == 0 && ok) {
            *(float4*)&als[(size_t)r * 4] = make_float4(ps[0], ps[1], ps[2], ps[3]);
            *(float4*)&ald[(size_t)r * 4] = make_float4(pd[0], pd[1], pd[2], pd[3]);
        }
    }
}

// ---------------- fully fused GAT: single-pass online softmax + LN + ReLU + residual ----------------
// 4-edge unrolled gather (16 row-loads in flight per wave).
// If Wo != nullptr (final layer): fuse output projection, skip hres store.
__global__ __launch_bounds__(256) void gat_fused(
        const ushortT* __restrict__ xlh, const float* __restrict__ als,
        const float* __restrict__ ald, const int* __restrict__ off,
        const int* __restrict__ csr, const float* __restrict__ bias,
        const float* __restrict__ g, const float* __restrict__ be,
        float* __restrict__ hres, ushortT* __restrict__ hresh,
        const float* __restrict__ Wo, const float* __restrict__ aso, const float* __restrict__ ado,
        float* __restrict__ xlo, float* __restrict__ alsoB, float* __restrict__ aldoB, int Nn) {
    int gid = blockIdx.x * 256 + threadIdx.x;
    int wid = gid >> 6, lane = threadIdx.x & 63;
    if (wid >= Nn) return;
    int q = lane >> 4;
    int cl = lane & 15;
    int h = cl >> 2;
    float aldh = ald[wid * 4 + h];
    float eh = lrelu(als[wid * 4 + h] + aldh);   // self logit = softmax shift
    int b = off[wid], e = off[wid + 1];
    float acc[8] = {};
    float dsum = 0.f;
    int c = b + q;
    // main: 4 edges per slot iteration, loads batched before use
    for (; c + 12 < e; c += 16) {
        int s0 = csr[c];
        int s1 = csr[c + 4];
        int s2 = csr[c + 8];
        int s3 = csr[c + 12];
        float al0 = als[(size_t)s0 * 4 + h];
        float al1 = als[(size_t)s1 * 4 + h];
        float al2 = als[(size_t)s2 * 4 + h];
        float al3 = als[(size_t)s3 * 4 + h];
        uint4 hv0 = *(const uint4*)&xlh[(size_t)s0 * HID + cl * 8];
        uint4 hv1 = *(const uint4*)&xlh[(size_t)s1 * HID + cl * 8];
        uint4 hv2 = *(const uint4*)&xlh[(size_t)s2 * HID + cl * 8];
        uint4 hv3 = *(const uint4*)&xlh[(size_t)s3 * HID + cl * 8];
        float w0 = __expf(lrelu(al0 + aldh) - eh);
        float w1 = __expf(lrelu(al1 + aldh) - eh);
        float w2 = __expf(lrelu(al2 + aldh) - eh);
        float w3 = __expf(lrelu(al3 + aldh) - eh);
        dsum += (w0 + w1) + (w2 + w3);
        acc[0] = fmaf(w0, bflo(hv0.x), acc[0]); acc[1] = fmaf(w0, bfhi(hv0.x), acc[1]);
        acc[2] = fmaf(w0, bflo(hv0.y), acc[2]); acc[3] = fmaf(w0, bfhi(hv0.y), acc[3]);
        acc[4] = fmaf(w0, bflo(hv0.z), acc[4]); acc[5] = fmaf(w0, bfhi(hv0.z), acc[5]);
        acc[6] = fmaf(w0, bflo(hv0.w), acc[6]); acc[7] = fmaf(w0, bfhi(hv0.w), acc[7]);
        acc[0] = fmaf(w1, bflo(hv1.x), acc[0]); acc[1] = fmaf(w1, bfhi(hv1.x), acc[1]);
        acc[2] = fmaf(w1, bflo(hv1.y), acc[2]); acc[3] = fmaf(w1, bfhi(hv1.y), acc[3]);
        acc[4] = fmaf(w1, bflo(hv1.z), acc[4]); acc[5] = fmaf(w1, bfhi(hv1.z), acc[5]);
        acc[6] = fmaf(w1, bflo(hv1.w), acc[6]); acc[7] = fmaf(w1, bfhi(hv1.w), acc[7]);
        acc[0] = fmaf(w2, bflo(hv2.x), acc[0]); acc[1] = fmaf(w2, bfhi(hv2.x), acc[1]);
        acc[2] = fmaf(w2, bflo(hv2.y), acc[2]); acc[3] = fmaf(w2, bfhi(hv2.y), acc[3]);
        acc[4] = fmaf(w2, bflo(hv2.z), acc[4]); acc[5] = fmaf(w2, bfhi(hv2.z), acc[5]);
        acc[6] = fmaf(w2, bflo(hv2.w), acc[6]); acc[7] = fmaf(w2, bfhi(hv2.w), acc[7]);
        acc[0] = fmaf(w3, bflo(hv3.x), acc[0]); acc[1] = fmaf(w3, bfhi(hv3.x), acc[1]);
        acc[2] = fmaf(w3, bflo(hv3.y), acc[2]); acc[3] = fmaf(w3, bfhi(hv3.y), acc[3]);
        acc[4] = fmaf(w3, bflo(hv3.z), acc[4]); acc[5] = fmaf(w3, bfhi(hv3.z), acc[5]);
        acc[6] = fmaf(w3, bflo(hv3.w), acc[6]); acc[7] = fmaf(w3, bfhi(hv3.w), acc[7]);
    }
    for (; c < e; c += 4) {
        int s = csr[c];
        float al = als[(size_t)s * 4 + h];
        uint4 hv = *(const uint4*)&xlh[(size_t)s * HID + cl * 8];
        float w = __expf(lrelu(al + aldh) - eh);
        dsum += w;
        acc[0] = fmaf(w, bflo(hv.x), acc[0]); acc[1] = fmaf(w, bfhi(hv.x), acc[1]);
        acc[2] = fmaf(w, bflo(hv.y), acc[2]); acc[3] = fmaf(w, bfhi(hv.y), acc[3]);
        acc[4] = fmaf(w, bflo(hv.z), acc[4]); acc[5] = fmaf(w, bfhi(hv.z), acc[5]);
        acc[6] = fmaf(w, bflo(hv.w), acc[6]); acc[7] = fmaf(w, bfhi(hv.w), acc[7]);
    }
    #pragma unroll
    for (int k = 0; k < 8; ++k) {
        acc[k] += __shfl_xor(acc[k], 16, 64);
        acc[k] += __shfl_xor(acc[k], 32, 64);
    }
    dsum += __shfl_xor(dsum, 16, 64);
    dsum += __shfl_xor(dsum, 32, 64);
    float inv = 1.f / (dsum + 1.f + 1e-16f);     // self weight = exp(0) = 1
    uint4 sv = *(const uint4*)&xlh[(size_t)wid * HID + cl * 8];
    float sx[8];
    sx[0] = bflo(sv.x); sx[1] = bfhi(sv.x);
    sx[2] = bflo(sv.y); sx[3] = bfhi(sv.y);
    sx[4] = bflo(sv.z); sx[5] = bfhi(sv.z);
    sx[6] = bflo(sv.w); sx[7] = bfhi(sv.w);
    float4 bi0 = *(const float4*)&bias[cl * 8];
    float4 bi1 = *(const float4*)&bias[cl * 8 + 4];
    float o[8];
    #pragma unroll
    for (int k = 0; k < 8; ++k) {
        float bb = k < 4 ? (&bi0.x)[k] : (&bi1.x)[k - 4];
        o[k] = fmaf(acc[k] + sx[k], inv, bb);
    }
    float s1 = o[0] + o[1] + o[2] + o[3] + o[4] + o[5] + o[6] + o[7];
    #pragma unroll
    for (int m = 1; m < 16; m <<= 1) s1 += __shfl_xor(s1, m, 64);
    float mu = s1 * (1.0f / HID);
    float qv = 0.f;
    #pragma unroll
    for (int k = 0; k < 8; ++k) { float d = o[k] - mu; qv += d * d; }
    #pragma unroll
    for (int m = 1; m < 16; m <<= 1) qv += __shfl_xor(qv, m, 64);
    float rs = rsqrtf(qv * (1.0f / HID) + LN_EPS);
    if (q == 0) {
        float4 g0 = *(const float4*)&g[cl * 8];
        float4 g1 = *(const float4*)&g[cl * 8 + 4];
        float4 be0 = *(const float4*)&be[cl * 8];
        float4 be1 = *(const float4*)&be[cl * 8 + 4];
        float4 r0 = *(const float4*)&hres[(size_t)wid * HID + cl * 8];
        float4 r1 = *(const float4*)&hres[(size_t)wid * HID + cl * 8 + 4];
        float w[8];
        #pragma unroll
        for (int k = 0; k < 8; ++k) {
            float gg = k < 4 ? (&g0.x)[k] : (&g1.x)[k - 4];
            float ee = k < 4 ? (&be0.x)[k] : (&be1.x)[k - 4];
            float rr = k < 4 ? (&r0.x)[k] : (&r1.x)[k - 4];
            w[k] = fmaxf((o[k] - mu) * rs * gg + ee, 0.f) + rr;
        }
        if (Wo) {
            float p0 = 0.f, p1 = 0.f;
            #pragma unroll
            for (int k = 0; k < 8; ++k) {
                int ch = cl * 8 + k;
                p0 = fmaf(w[k], Wo[ch * 2 + 0], p0);
                p1 = fmaf(w[k], Wo[ch * 2 + 1], p1);
            }
            #pragma unroll
            for (int m = 1; m < 16; m <<= 1) {
                p0 += __shfl_xor(p0, m, 64);
                p1 += __shfl_xor(p1, m, 64);
            }
            if (cl == 0) {
                xlo[wid * 2 + 0] = p0;
                xlo[wid * 2 + 1] = p1;
                alsoB[wid] = p0 * aso[0] + p1 * aso[1];
                aldoB[wid] = p0 * ado[0] + p1 * ado[1];
            }
        } else {
            *(float4*)&hres[(size_t)wid * HID + cl * 8] = make_float4(w[0], w[1], w[2], w[3]);
            *(float4*)&hres[(size_t)wid * HID + cl * 8 + 4] = make_float4(w[4], w[5], w[6], w[7]);
            ushort4 hv0, hv1;
            hv0.x = f2bf(w[0]); hv0.y = f2bf(w[1]); hv0.z = f2bf(w[2]); hv0.w = f2bf(w[3]);
            hv1.x = f2bf(w[4]); hv1.y = f2bf(w[5]); hv1.z = f2bf(w[6]); hv1.w = f2bf(w[7]);
            *(ushort4*)&hresh[(size_t)wid * HID + cl * 8] = hv0;
            *(ushort4*)&hresh[(size_t)wid * HID + cl * 8 + 4] = hv1;
        }
    }
}

// ---------------- output aggregation ----------------
__global__ __launch_bounds__(256) void out_agg(const float* __restrict__ xlo, const float* __restrict__ also,
                                               const float* __restrict__ aldo, const int* __restrict__ off,
                                               const int* __restrict__ csr, const float* __restrict__ bo,
                                               float* __restrict__ out, int Nn) {
    int gid = blockIdx.x * 256 + threadIdx.x;
    int wid = gid >> 6, lane = threadIdx.x & 63;
    if (wid >= Nn) return;
    float aldn = aldo[wid];
    float eself = lrelu(also[wid] + aldn);
    int b = off[wid], e = off[wid + 1];
    float dl = 0.f, a0 = 0.f, a1 = 0.f;
    for (int j = b + lane; j < e; j += 64) {
        int s = csr[j];
        float w = __expf(lrelu(also[s] + aldn) - eself);
        dl += w;
        a0 += w * xlo[s * 2 + 0];
        a1 += w * xlo[s * 2 + 1];
    }
    #pragma unroll
    for (int m = 1; m < 64; m <<= 1) {
        dl += __shfl_xor(dl, m, 64);
        a0 += __shfl_xor(a0, m, 64);
        a1 += __shfl_xor(a1, m, 64);
    }
    if (lane == 0) {
        dl += 1.f;   // self weight exp(0)
        a0 += xlo[wid * 2 + 0];
        a1 += xlo[wid * 2 + 1];
        float inv = 1.f / (dl + 1e-16f);
        out[wid * 2 + 0] = a0 * inv + bo[0];
        out[wid * 2 + 1] = a1 * inv + bo[1];
    }
}

extern "C" void kernel_launch(void* const* d_in, const int* in_sizes, int n_in,
                              void* d_out, int out_size, void* d_ws, size_t ws_size,
                              hipStream_t stream) {
    const float* x   = (const float*)d_in[0];
    const int*   ei  = (const int*)d_in[1];
    const float* W1  = (const float*)d_in[2];
    const float* as1 = (const float*)d_in[3];
    const float* ad1 = (const float*)d_in[4];
    const float* b1  = (const float*)d_in[5];
    const float* g1  = (const float*)d_in[6];
    const float* be1 = (const float*)d_in[7];
    const float* rw  = (const float*)d_in[8];
    const float* rb  = (const float*)d_in[9];
    const float* W2  = (const float*)d_in[10];
    const float* as2 = (const float*)d_in[11];
    const float* ad2 = (const float*)d_in[12];
    const float* b2  = (const float*)d_in[13];
    const float* g2  = (const float*)d_in[14];
    const float* be2 = (const float*)d_in[15];
    const float* W3  = (const float*)d_in[16];
    const float* as3 = (const float*)d_in[17];
    const float* ad3 = (const float*)d_in[18];
    const float* b3  = (const float*)d_in[19];
    const float* g3  = (const float*)d_in[20];
    const float* be3 = (const float*)d_in[21];
    const float* Wo  = (const float*)d_in[22];
    const float* aso = (const float*)d_in[23];
    const float* ado = (const float*)d_in[24];
    const float* bo  = (const float*)d_in[25];

    int N = in_sizes[0] / 64;   // 50000
    int E = in_sizes[1] / 2;    // 800000
    const int* srcE = ei;
    const int* dstE = ei + E;
    int NB = (N + 127) >> 7;    // 391 buckets

    char* w = (char*)d_ws;
    auto alloc = [&](size_t b) { char* p = w; w += (b + 255) & ~(size_t)255; return p; };
    int* off    = (int*)alloc((size_t)(N + 1) * 4);
    int* gcur   = (int*)alloc((size_t)NB * 4);
    int* bbase  = (int*)alloc((size_t)NB * 4);
    int* csr    = (int*)alloc((size_t)E * 4);
    int2* bbuf  = (int2*)alloc((size_t)NB * BCAP * 8);
    float* hbuf = (float*)alloc((size_t)N * HID * 4);
    ushortT* hresh = (ushortT*)alloc((size_t)N * HID * 2);
    ushortT* xlh = (ushortT*)alloc((size_t)N * HID * 2);
    ushortT* rwf = (ushortT*)alloc(8192 * 2);
    ushortT* W1f = (ushortT*)alloc(8192 * 2);
    ushortT* W2f = (ushortT*)alloc(16384 * 2);
    ushortT* W3f = (ushortT*)alloc(16384 * 2);
    float* als  = (float*)alloc((size_t)N * HEADS * 4);
    float* ald  = (float*)alloc((size_t)N * HEADS * 4);
    float* xlo  = (float*)alloc((size_t)N * 2 * 4);
    float* alsoB = (float*)alloc((size_t)N * 4);
    float* aldoB = (float*)alloc((size_t)N * 4);

    hipMemsetAsync(gcur, 0, (size_t)NB * 4, stream);
    binA_k<<<(E + 4095) / 4096, 256, 0, stream>>>(srcE, dstE, gcur, bbuf, E, NB);
    scanB_k<<<1, 64, 0, stream>>>(gcur, bbase, NB);
    binB_k<<<NB, 256, 0, stream>>>(bbuf, gcur, bbase, off, csr, N, E);

    // weight conversion
    wconv4_k<<<192, 256, 0, stream>>>(rw, W1, W2, W3, rwf, W1f, W2f, W3f);

    int gG = (N + 63) / 64;   // MFMA gemm grid
    int gW = (N + 3) / 4;

    // ---- layer 1 (fused residual + W1 projection, MFMA, inline x->bf16) ----
    gemm_mfma_x<<<gG, 256, 0, stream>>>(x, rwf, W1f, rb, as1, ad1, hbuf, xlh, als, ald, N);
    gat_fused<<<gW, 256, 0, stream>>>(xlh, als, ald, off, csr, b1, g1, be1, hbuf, hresh,
                                      nullptr, nullptr, nullptr, nullptr, nullptr, nullptr, N);

    // ---- layer 2 ----
    gemm_mfma_h<<<gG, 256, 0, stream>>>(hresh, W2f, as2, ad2, xlh, als, ald, N);
    gat_fused<<<gW, 256, 0, stream>>>(xlh, als, ald, off, csr, b2, g2, be2, hbuf, hresh,
                                      nullptr, nullptr, nullptr, nullptr, nullptr, nullptr, N);

    // ---- layer 3 (fused output projection) ----
    gemm_mfma_h<<<gG, 256, 0, stream>>>(hresh, W3f, as3, ad3, xlh, als, ald, N);
    gat_fused<<<gW, 256, 0, stream>>>(xlh, als, ald, off, csr, b3, g3, be3, hbuf, nullptr,
                                      Wo, aso, ado, xlo, alsoB, aldoB, N);

    // ---- output aggregation ----
    out_agg<<<gW, 256, 0, stream>>>(xlo, alsoB, aldoB, off, csr, bo, (float*)d_out, N);
}

// Round 11
// 244.484 us; speedup vs baseline: 3.2856x; 1.0325x over previous
//
#include <hip/hip_runtime.h>
#include <math.h>

#define HID 128
#define HEADS 4
#define NEG_SLOPE 0.2f
#define LN_EPS 1e-5f
#define BCAP 4096   // per-bucket capacity (avg 2046 for N=50K, E=800K)

typedef unsigned short ushortT;
typedef unsigned int uintT;
typedef __attribute__((ext_vector_type(8))) short bf16x8;
typedef __attribute__((ext_vector_type(4))) float f32x4;

__device__ __forceinline__ float lrelu(float v) { return v > 0.f ? v : NEG_SLOPE * v; }
__device__ __forceinline__ float bflo(uintT v) { return __uint_as_float(v << 16); }
__device__ __forceinline__ float bfhi(uintT v) { return __uint_as_float(v & 0xffff0000u); }

__device__ __forceinline__ ushortT f2bf(float f) {
    uintT u = __float_as_uint(f);
    u += 0x7fffu + ((u >> 16) & 1u);   // round-to-nearest-even
    return (ushortT)(u >> 16);
}

// ---------------- edge binning (pass A): bin edges by dst>>7; gcur ends as per-bucket counts ----------------
__global__ __launch_bounds__(256) void binA_k(const int* __restrict__ src, const int* __restrict__ dst,
                                              int* __restrict__ gcur, int2* __restrict__ buf, int E, int NB) {
    __shared__ int hist[512];
    __shared__ int bbase[512];
    __shared__ int lcur[512];
    int t = threadIdx.x;
    for (int i = t; i < NB; i += 256) { hist[i] = 0; lcur[i] = 0; }
    __syncthreads();
    int e0 = blockIdx.x * 4096;
    int2 ed[16];
    #pragma unroll
    for (int j = 0; j < 16; ++j) {
        int idx = e0 + j * 256 + t;
        if (idx < E) {
            ed[j].x = src[idx];
            ed[j].y = dst[idx];
            atomicAdd(&hist[ed[j].y >> 7], 1);
        } else {
            ed[j].y = -1;
        }
    }
    __syncthreads();
    for (int i = t; i < NB; i += 256) {
        int c = hist[i];
        bbase[i] = c > 0 ? atomicAdd(&gcur[i], c) : 0;
    }
    __syncthreads();
    #pragma unroll
    for (int j = 0; j < 16; ++j) {
        if (ed[j].y >= 0) {
            int b = ed[j].y >> 7;
            int pos = bbase[b] + atomicAdd(&lcur[b], 1);
            buf[(size_t)b * BCAP + pos] = ed[j];
        }
    }
}

// ---------------- scan bucket totals (one wave, NB <= 512) ----------------
__global__ __launch_bounds__(64) void scanB_k(const int* __restrict__ bcnt, int* __restrict__ bbase, int NB) {
    int t = threadIdx.x;
    int carry = 0;
    for (int base = 0; base < NB; base += 64) {
        int idx = base + t;
        int v = idx < NB ? bcnt[idx] : 0;
        int inc = v;
        #pragma unroll
        for (int ofs = 1; ofs < 64; ofs <<= 1) {
            int p = __shfl_up(inc, ofs, 64);
            if (t >= ofs) inc += p;
        }
        if (idx < NB) bbase[idx] = carry + inc - v;   // exclusive
        carry += __shfl(inc, 63, 64);
    }
}

// ---------------- pass B: per-bucket node count + scan -> off[], then scatter csr ----------------
__global__ __launch_bounds__(256) void binB_k(const int2* __restrict__ buf, const int* __restrict__ bcnt,
                                              const int* __restrict__ bbase, int* __restrict__ off,
                                              int* __restrict__ csr, int Nn, int E) {
    __shared__ int cnt[128];
    __shared__ int pre[128];
    __shared__ int cur[128];
    int t = threadIdx.x, b = blockIdx.x;
    if (t < 128) cnt[t] = 0;
    __syncthreads();
    int nb = bcnt[b];
    int base = bbase[b];
    int nodebase = b << 7;
    for (int i = t; i < nb; i += 256)
        atomicAdd(&cnt[buf[(size_t)b * BCAP + i].y - nodebase], 1);
    __syncthreads();
    if (t < 128) pre[t] = cnt[t];
    __syncthreads();
    #pragma unroll
    for (int ofs = 1; ofs < 128; ofs <<= 1) {
        int v = 0;
        if (t < 128 && t >= ofs) v = pre[t - ofs];
        __syncthreads();
        if (t < 128) pre[t] += v;
        __syncthreads();
    }
    if (t < 128) {
        int node = nodebase + t;
        int o = base + pre[t] - cnt[t];   // exclusive prefix
        if (node < Nn) off[node] = o;
        cur[t] = o;
    }
    if (b == 0 && t == 0) off[Nn] = E;
    __syncthreads();
    for (int i = t; i < nb; i += 256) {
        int2 e = buf[(size_t)b * BCAP + i];
        int p = atomicAdd(&cur[e.y - nodebase], 1);
        csr[p] = e.x;
    }
}

// ---------------- weight conversion into MFMA B-fragment layout ----------------
__global__ __launch_bounds__(256) void wconv4_k(const float* __restrict__ rw, const float* __restrict__ W1,
                                                const float* __restrict__ W2, const float* __restrict__ W3,
                                                ushortT* __restrict__ rwf, ushortT* __restrict__ W1f,
                                                ushortT* __restrict__ W2f, ushortT* __restrict__ W3f) {
    int id = blockIdx.x * 256 + threadIdx.x;
    const float* Wsrc; ushortT* Wdst; int kdiv; int lid;
    if (id < 8192)        { Wsrc = rw; Wdst = rwf; kdiv = 2; lid = id; }
    else if (id < 16384)  { Wsrc = W1; Wdst = W1f; kdiv = 2; lid = id - 8192; }
    else if (id < 32768)  { Wsrc = W2; Wdst = W2f; kdiv = 4; lid = id - 16384; }
    else if (id < 49152)  { Wsrc = W3; Wdst = W3f; kdiv = 4; lid = id - 32768; }
    else return;
    int i = lid & 7;
    int lane = (lid >> 3) & 63;
    int rest = lid >> 9;            // j*kdiv + ks
    int ks = rest % kdiv;
    int j = rest / kdiv;
    int k = ks * 32 + (lane >> 4) * 8 + i;
    int n = j * 16 + (lane & 15);
    Wdst[lid] = f2bf(Wsrc[k * HID + n]);
}

// ---------------- MFMA GEMM (x layer, K=64): inline fp32->bf16 A, dual output + attn dots ----------------
__global__ __launch_bounds__(256) void gemm_mfma_x(
        const float* __restrict__ X, const ushortT* __restrict__ rwf, const ushortT* __restrict__ W1f,
        const float* __restrict__ rb, const float* __restrict__ a_srcp, const float* __restrict__ a_dstp,
        float* __restrict__ Cres, ushortT* __restrict__ Ch,
        float* __restrict__ als, float* __restrict__ ald, int M) {
    int t = threadIdx.x;
    int wave = t >> 6, lane = t & 63;
    int row0 = blockIdx.x * 64 + wave * 16;
    int cl = lane & 15, grp = lane >> 4;
    int rA = row0 + cl;
    f32x4 accR[8] = {};
    f32x4 acc1[8] = {};
    #pragma unroll
    for (int ks = 0; ks < 2; ++ks) {
        bf16x8 afr = {};
        if (rA < M) {
            const float* xr = &X[(size_t)rA * 64 + ks * 32 + grp * 8];
            float4 a0 = *(const float4*)xr;
            float4 a1 = *(const float4*)(xr + 4);
            afr[0] = (short)f2bf(a0.x); afr[1] = (short)f2bf(a0.y);
            afr[2] = (short)f2bf(a0.z); afr[3] = (short)f2bf(a0.w);
            afr[4] = (short)f2bf(a1.x); afr[5] = (short)f2bf(a1.y);
            afr[6] = (short)f2bf(a1.z); afr[7] = (short)f2bf(a1.w);
        }
        #pragma unroll
        for (int j = 0; j < 8; ++j) {
            bf16x8 br = *(const bf16x8*)&rwf[(((size_t)j * 2 + ks) * 64 + lane) * 8];
            accR[j] = __builtin_amdgcn_mfma_f32_16x16x32_bf16(afr, br, accR[j], 0, 0, 0);
            bf16x8 b1 = *(const bf16x8*)&W1f[(((size_t)j * 2 + ks) * 64 + lane) * 8];
            acc1[j] = __builtin_amdgcn_mfma_f32_16x16x32_bf16(afr, b1, acc1[j], 0, 0, 0);
        }
    }
    float asv[8], adv[8], rbv[8];
    #pragma unroll
    for (int j = 0; j < 8; ++j) {
        asv[j] = a_srcp[j * 16 + cl];
        adv[j] = a_dstp[j * 16 + cl];
        rbv[j] = rb[j * 16 + cl];
    }
    #pragma unroll
    for (int reg = 0; reg < 4; ++reg) {
        int r = row0 + grp * 4 + reg;
        bool ok = r < M;
        if (ok) {
            #pragma unroll
            for (int j = 0; j < 8; ++j) {
                Cres[(size_t)r * HID + j * 16 + cl] = accR[j][reg] + rbv[j];
                Ch[(size_t)r * HID + j * 16 + cl] = f2bf(acc1[j][reg]);
            }
        }
        float ps[4], pd[4];
        #pragma unroll
        for (int h = 0; h < 4; ++h) {
            ps[h] = acc1[2 * h][reg] * asv[2 * h] + acc1[2 * h + 1][reg] * asv[2 * h + 1];
            pd[h] = acc1[2 * h][reg] * adv[2 * h] + acc1[2 * h + 1][reg] * adv[2 * h + 1];
        }
        #pragma unroll
        for (int m = 1; m < 16; m <<= 1) {
            #pragma unroll
            for (int h = 0; h < 4; ++h) {
                ps[h] += __shfl_xor(ps[h], m, 64);
                pd[h] += __shfl_xor(pd[h], m, 64);
            }
        }
        if (cl == 0 && ok) {
            *(float4*)&als[(size_t)r * 4] = make_float4(ps[0], ps[1], ps[2], ps[3]);
            *(float4*)&ald[(size_t)r * 4] = make_float4(pd[0], pd[1], pd[2], pd[3]);
        }
    }
}

// ---------------- MFMA GEMM (hidden layers, K=128): Ch + attn dots ----------------
__global__ __launch_bounds__(256) void gemm_mfma_h(
        const ushortT* __restrict__ Ah, const ushortT* __restrict__ Wf,
        const float* __restrict__ a_srcp, const float* __restrict__ a_dstp,
        ushortT* __restrict__ Ch, float* __restrict__ als, float* __restrict__ ald, int M) {
    int t = threadIdx.x;
    int wave = t >> 6, lane = t & 63;
    int row0 = blockIdx.x * 64 + wave * 16;
    int cl = lane & 15, grp = lane >> 4;
    int rA = row0 + cl;
    f32x4 acc[8] = {};
    #pragma unroll
    for (int ks = 0; ks < 4; ++ks) {
        bf16x8 afr = {};
        if (rA < M) afr = *(const bf16x8*)&Ah[(size_t)rA * HID + ks * 32 + grp * 8];
        #pragma unroll
        for (int j = 0; j < 8; ++j) {
            bf16x8 br = *(const bf16x8*)&Wf[(((size_t)j * 4 + ks) * 64 + lane) * 8];
            acc[j] = __builtin_amdgcn_mfma_f32_16x16x32_bf16(afr, br, acc[j], 0, 0, 0);
        }
    }
    float asv[8], adv[8];
    #pragma unroll
    for (int j = 0; j < 8; ++j) {
        asv[j] = a_srcp[j * 16 + cl];
        adv[j] = a_dstp[j * 16 + cl];
    }
    #pragma unroll
    for (int reg = 0; reg < 4; ++reg) {
        int r = row0 + grp * 4 + reg;
        bool ok = r < M;
        if (ok) {
            #pragma unroll
            for (int j = 0; j < 8; ++j)
                Ch[(size_t)r * HID + j * 16 + cl] = f2bf(acc[j][reg]);
        }
        float ps[4], pd[4];
        #pragma unroll
        for (int h = 0; h < 4; ++h) {
            ps[h] = acc[2 * h][reg] * asv[2 * h] + acc[2 * h + 1][reg] * asv[2 * h + 1];
            pd[h] = acc[2 * h][reg] * adv[2 * h] + acc[2 * h + 1][reg] * adv[2 * h + 1];
        }
        #pragma unroll
        for (int m = 1; m < 16; m <<= 1) {
            #pragma unroll
            for (int h = 0; h < 4; ++h) {
                ps[h] += __shfl_xor(ps[h], m, 64);
                pd[h] += __shfl_xor(pd[h], m, 64);
            }
        }
        if (cl == 0 && ok) {
            *(float4*)&als[(size_t)r * 4] = make_float4(ps[0], ps[1], ps[2], ps[3]);
            *(float4*)&ald[(size_t)r * 4] = make_float4(pd[0], pd[1], pd[2], pd[3]);
        }
    }
}

// ---------------- fully fused GAT: single-pass online softmax + LN + ReLU + residual ----------------
// 2-edge unrolled gather (sweet spot: 8 row-loads in flight/wave at 28 VGPR; 4-deep regressed occupancy).
// If Wo != nullptr (final layer): fuse output projection, skip hres store.
__global__ __launch_bounds__(256) void gat_fused(
        const ushortT* __restrict__ xlh, const float* __restrict__ als,
        const float* __restrict__ ald, const int* __restrict__ off,
        const int* __restrict__ csr, const float* __restrict__ bias,
        const float* __restrict__ g, const float* __restrict__ be,
        float* __restrict__ hres, ushortT* __restrict__ hresh,
        const float* __restrict__ Wo, const float* __restrict__ aso, const float* __restrict__ ado,
        float* __restrict__ xlo, float* __restrict__ alsoB, float* __restrict__ aldoB, int Nn) {
    int gid = blockIdx.x * 256 + threadIdx.x;
    int wid = gid >> 6, lane = threadIdx.x & 63;
    if (wid >= Nn) return;
    int q = lane >> 4;
    int cl = lane & 15;
    int h = cl >> 2;
    float aldh = ald[wid * 4 + h];
    float eh = lrelu(als[wid * 4 + h] + aldh);   // self logit = softmax shift
    int b = off[wid], e = off[wid + 1];
    float acc[8] = {};
    float dsum = 0.f;
    int c = b + q;
    // main: 2 edges per slot iteration, loads batched before use
    for (; c + 4 < e; c += 8) {
        int s0 = csr[c];
        int s1 = csr[c + 4];
        float al0 = als[(size_t)s0 * 4 + h];
        float al1 = als[(size_t)s1 * 4 + h];
        uint4 hv0 = *(const uint4*)&xlh[(size_t)s0 * HID + cl * 8];
        uint4 hv1 = *(const uint4*)&xlh[(size_t)s1 * HID + cl * 8];
        float w0 = __expf(lrelu(al0 + aldh) - eh);
        float w1 = __expf(lrelu(al1 + aldh) - eh);
        dsum += w0 + w1;
        acc[0] = fmaf(w0, bflo(hv0.x), acc[0]);
        acc[1] = fmaf(w0, bfhi(hv0.x), acc[1]);
        acc[2] = fmaf(w0, bflo(hv0.y), acc[2]);
        acc[3] = fmaf(w0, bfhi(hv0.y), acc[3]);
        acc[4] = fmaf(w0, bflo(hv0.z), acc[4]);
        acc[5] = fmaf(w0, bfhi(hv0.z), acc[5]);
        acc[6] = fmaf(w0, bflo(hv0.w), acc[6]);
        acc[7] = fmaf(w0, bfhi(hv0.w), acc[7]);
        acc[0] = fmaf(w1, bflo(hv1.x), acc[0]);
        acc[1] = fmaf(w1, bfhi(hv1.x), acc[1]);
        acc[2] = fmaf(w1, bflo(hv1.y), acc[2]);
        acc[3] = fmaf(w1, bfhi(hv1.y), acc[3]);
        acc[4] = fmaf(w1, bflo(hv1.z), acc[4]);
        acc[5] = fmaf(w1, bfhi(hv1.z), acc[5]);
        acc[6] = fmaf(w1, bflo(hv1.w), acc[6]);
        acc[7] = fmaf(w1, bfhi(hv1.w), acc[7]);
    }
    if (c < e) {
        int s = csr[c];
        float al = als[(size_t)s * 4 + h];
        uint4 hv = *(const uint4*)&xlh[(size_t)s * HID + cl * 8];
        float w = __expf(lrelu(al + aldh) - eh);
        dsum += w;
        acc[0] = fmaf(w, bflo(hv.x), acc[0]);
        acc[1] = fmaf(w, bfhi(hv.x), acc[1]);
        acc[2] = fmaf(w, bflo(hv.y), acc[2]);
        acc[3] = fmaf(w, bfhi(hv.y), acc[3]);
        acc[4] = fmaf(w, bflo(hv.z), acc[4]);
        acc[5] = fmaf(w, bfhi(hv.z), acc[5]);
        acc[6] = fmaf(w, bflo(hv.w), acc[6]);
        acc[7] = fmaf(w, bfhi(hv.w), acc[7]);
    }
    #pragma unroll
    for (int k = 0; k < 8; ++k) {
        acc[k] += __shfl_xor(acc[k], 16, 64);
        acc[k] += __shfl_xor(acc[k], 32, 64);
    }
    dsum += __shfl_xor(dsum, 16, 64);
    dsum += __shfl_xor(dsum, 32, 64);
    float inv = 1.f / (dsum + 1.f + 1e-16f);     // self weight = exp(0) = 1
    uint4 sv = *(const uint4*)&xlh[(size_t)wid * HID + cl * 8];
    float sx[8];
    sx[0] = bflo(sv.x); sx[1] = bfhi(sv.x);
    sx[2] = bflo(sv.y); sx[3] = bfhi(sv.y);
    sx[4] = bflo(sv.z); sx[5] = bfhi(sv.z);
    sx[6] = bflo(sv.w); sx[7] = bfhi(sv.w);
    float4 bi0 = *(const float4*)&bias[cl * 8];
    float4 bi1 = *(const float4*)&bias[cl * 8 + 4];
    float o[8];
    #pragma unroll
    for (int k = 0; k < 8; ++k) {
        float bb = k < 4 ? (&bi0.x)[k] : (&bi1.x)[k - 4];
        o[k] = fmaf(acc[k] + sx[k], inv, bb);
    }
    float s1 = o[0] + o[1] + o[2] + o[3] + o[4] + o[5] + o[6] + o[7];
    #pragma unroll
    for (int m = 1; m < 16; m <<= 1) s1 += __shfl_xor(s1, m, 64);
    float mu = s1 * (1.0f / HID);
    float qv = 0.f;
    #pragma unroll
    for (int k = 0; k < 8; ++k) { float d = o[k] - mu; qv += d * d; }
    #pragma unroll
    for (int m = 1; m < 16; m <<= 1) qv += __shfl_xor(qv, m, 64);
    float rs = rsqrtf(qv * (1.0f / HID) + LN_EPS);
    if (q == 0) {
        float4 g0 = *(const float4*)&g[cl * 8];
        float4 g1 = *(const float4*)&g[cl * 8 + 4];
        float4 be0 = *(const float4*)&be[cl * 8];
        float4 be1 = *(const float4*)&be[cl * 8 + 4];
        float4 r0 = *(const float4*)&hres[(size_t)wid * HID + cl * 8];
        float4 r1 = *(const float4*)&hres[(size_t)wid * HID + cl * 8 + 4];
        float w[8];
        #pragma unroll
        for (int k = 0; k < 8; ++k) {
            float gg = k < 4 ? (&g0.x)[k] : (&g1.x)[k - 4];
            float ee = k < 4 ? (&be0.x)[k] : (&be1.x)[k - 4];
            float rr = k < 4 ? (&r0.x)[k] : (&r1.x)[k - 4];
            w[k] = fmaxf((o[k] - mu) * rs * gg + ee, 0.f) + rr;
        }
        if (Wo) {
            float p0 = 0.f, p1 = 0.f;
            #pragma unroll
            for (int k = 0; k < 8; ++k) {
                int ch = cl * 8 + k;
                p0 = fmaf(w[k], Wo[ch * 2 + 0], p0);
                p1 = fmaf(w[k], Wo[ch * 2 + 1], p1);
            }
            #pragma unroll
            for (int m = 1; m < 16; m <<= 1) {
                p0 += __shfl_xor(p0, m, 64);
                p1 += __shfl_xor(p1, m, 64);
            }
            if (cl == 0) {
                xlo[wid * 2 + 0] = p0;
                xlo[wid * 2 + 1] = p1;
                alsoB[wid] = p0 * aso[0] + p1 * aso[1];
                aldoB[wid] = p0 * ado[0] + p1 * ado[1];
            }
        } else {
            *(float4*)&hres[(size_t)wid * HID + cl * 8] = make_float4(w[0], w[1], w[2], w[3]);
            *(float4*)&hres[(size_t)wid * HID + cl * 8 + 4] = make_float4(w[4], w[5], w[6], w[7]);
            ushort4 hv0, hv1;
            hv0.x = f2bf(w[0]); hv0.y = f2bf(w[1]); hv0.z = f2bf(w[2]); hv0.w = f2bf(w[3]);
            hv1.x = f2bf(w[4]); hv1.y = f2bf(w[5]); hv1.z = f2bf(w[6]); hv1.w = f2bf(w[7]);
            *(ushort4*)&hresh[(size_t)wid * HID + cl * 8] = hv0;
            *(ushort4*)&hresh[(size_t)wid * HID + cl * 8 + 4] = hv1;
        }
    }
}

// ---------------- output aggregation ----------------
__global__ __launch_bounds__(256) void out_agg(const float* __restrict__ xlo, const float* __restrict__ also,
                                               const float* __restrict__ aldo, const int* __restrict__ off,
                                               const int* __restrict__ csr, const float* __restrict__ bo,
                                               float* __restrict__ out, int Nn) {
    int gid = blockIdx.x * 256 + threadIdx.x;
    int wid = gid >> 6, lane = threadIdx.x & 63;
    if (wid >= Nn) return;
    float aldn = aldo[wid];
    float eself = lrelu(also[wid] + aldn);
    int b = off[wid], e = off[wid + 1];
    float dl = 0.f, a0 = 0.f, a1 = 0.f;
    for (int j = b + lane; j < e; j += 64) {
        int s = csr[j];
        float w = __expf(lrelu(also[s] + aldn) - eself);
        dl += w;
        a0 += w * xlo[s * 2 + 0];
        a1 += w * xlo[s * 2 + 1];
    }
    #pragma unroll
    for (int m = 1; m < 64; m <<= 1) {
        dl += __shfl_xor(dl, m, 64);
        a0 += __shfl_xor(a0, m, 64);
        a1 += __shfl_xor(a1, m, 64);
    }
    if (lane == 0) {
        dl += 1.f;   // self weight exp(0)
        a0 += xlo[wid * 2 + 0];
        a1 += xlo[wid * 2 + 1];
        float inv = 1.f / (dl + 1e-16f);
        out[wid * 2 + 0] = a0 * inv + bo[0];
        out[wid * 2 + 1] = a1 * inv + bo[1];
    }
}

extern "C" void kernel_launch(void* const* d_in, const int* in_sizes, int n_in,
                              void* d_out, int out_size, void* d_ws, size_t ws_size,
                              hipStream_t stream) {
    const float* x   = (const float*)d_in[0];
    const int*   ei  = (const int*)d_in[1];
    const float* W1  = (const float*)d_in[2];
    const float* as1 = (const float*)d_in[3];
    const float* ad1 = (const float*)d_in[4];
    const float* b1  = (const float*)d_in[5];
    const float* g1  = (const float*)d_in[6];
    const float* be1 = (const float*)d_in[7];
    const float* rw  = (const float*)d_in[8];
    const float* rb  = (const float*)d_in[9];
    const float* W2  = (const float*)d_in[10];
    const float* as2 = (const float*)d_in[11];
    const float* ad2 = (const float*)d_in[12];
    const float* b2  = (const float*)d_in[13];
    const float* g2  = (const float*)d_in[14];
    const float* be2 = (const float*)d_in[15];
    const float* W3  = (const float*)d_in[16];
    const float* as3 = (const float*)d_in[17];
    const float* ad3 = (const float*)d_in[18];
    const float* b3  = (const float*)d_in[19];
    const float* g3  = (const float*)d_in[20];
    const float* be3 = (const float*)d_in[21];
    const float* Wo  = (const float*)d_in[22];
    const float* aso = (const float*)d_in[23];
    const float* ado = (const float*)d_in[24];
    const float* bo  = (const float*)d_in[25];

    int N = in_sizes[0] / 64;   // 50000
    int E = in_sizes[1] / 2;    // 800000
    const int* srcE = ei;
    const int* dstE = ei + E;
    int NB = (N + 127) >> 7;    // 391 buckets

    char* w = (char*)d_ws;
    auto alloc = [&](size_t b) { char* p = w; w += (b + 255) & ~(size_t)255; return p; };
    int* off    = (int*)alloc((size_t)(N + 1) * 4);
    int* gcur   = (int*)alloc((size_t)NB * 4);
    int* bbase  = (int*)alloc((size_t)NB * 4);
    int* csr    = (int*)alloc((size_t)E * 4);
    int2* bbuf  = (int2*)alloc((size_t)NB * BCAP * 8);
    float* hbuf = (float*)alloc((size_t)N * HID * 4);
    ushortT* hresh = (ushortT*)alloc((size_t)N * HID * 2);
    ushortT* xlh = (ushortT*)alloc((size_t)N * HID * 2);
    ushortT* rwf = (ushortT*)alloc(8192 * 2);
    ushortT* W1f = (ushortT*)alloc(8192 * 2);
    ushortT* W2f = (ushortT*)alloc(16384 * 2);
    ushortT* W3f = (ushortT*)alloc(16384 * 2);
    float* als  = (float*)alloc((size_t)N * HEADS * 4);
    float* ald  = (float*)alloc((size_t)N * HEADS * 4);
    float* xlo  = (float*)alloc((size_t)N * 2 * 4);
    float* alsoB = (float*)alloc((size_t)N * 4);
    float* aldoB = (float*)alloc((size_t)N * 4);

    hipMemsetAsync(gcur, 0, (size_t)NB * 4, stream);
    binA_k<<<(E + 4095) / 4096, 256, 0, stream>>>(srcE, dstE, gcur, bbuf, E, NB);
    scanB_k<<<1, 64, 0, stream>>>(gcur, bbase, NB);
    binB_k<<<NB, 256, 0, stream>>>(bbuf, gcur, bbase, off, csr, N, E);

    // weight conversion
    wconv4_k<<<192, 256, 0, stream>>>(rw, W1, W2, W3, rwf, W1f, W2f, W3f);

    int gG = (N + 63) / 64;   // MFMA gemm grid
    int gW = (N + 3) / 4;

    // ---- layer 1 (fused residual + W1 projection, MFMA, inline x->bf16) ----
    gemm_mfma_x<<<gG, 256, 0, stream>>>(x, rwf, W1f, rb, as1, ad1, hbuf, xlh, als, ald, N);
    gat_fused<<<gW, 256, 0, stream>>>(xlh, als, ald, off, csr, b1, g1, be1, hbuf, hresh,
                                      nullptr, nullptr, nullptr, nullptr, nullptr, nullptr, N);

    // ---- layer 2 ----
    gemm_mfma_h<<<gG, 256, 0, stream>>>(hresh, W2f, as2, ad2, xlh, als, ald, N);
    gat_fused<<<gW, 256, 0, stream>>>(xlh, als, ald, off, csr, b2, g2, be2, hbuf, hresh,
                                      nullptr, nullptr, nullptr, nullptr, nullptr, nullptr, N);

    // ---- layer 3 (fused output projection) ----
    gemm_mfma_h<<<gG, 256, 0, stream>>>(hresh, W3f, as3, ad3, xlh, als, ald, N);
    gat_fused<<<gW, 256, 0, stream>>>(xlh, als, ald, off, csr, b3, g3, be3, hbuf, nullptr,
                                      Wo, aso, ado, xlo, alsoB, aldoB, N);

    // ---- output aggregation ----
    out_agg<<<gW, 256, 0, stream>>>(xlo, alsoB, aldoB, off, csr, bo, (float*)d_out, N);
}

// Round 12
// 224.808 us; speedup vs baseline: 3.5732x; 1.0875x over previous
//
#include <hip/hip_runtime.h>
#include <math.h>

#define HID 128
#define HEADS 4
#define NEG_SLOPE 0.2f
#define LN_EPS 1e-5f
#define LOG2E 1.44269504088896f
#define BCAP 4096   // per-bucket capacity (avg 2046 for N=50K, E=800K)

typedef unsigned short ushortT;
typedef unsigned int uintT;
typedef __attribute__((ext_vector_type(8))) short bf16x8;
typedef __attribute__((ext_vector_type(4))) float f32x4;

__device__ __forceinline__ float lrelu(float v) { return v > 0.f ? v : NEG_SLOPE * v; }
__device__ __forceinline__ float bflo(uintT v) { return __uint_as_float(v << 16); }
__device__ __forceinline__ float bfhi(uintT v) { return __uint_as_float(v & 0xffff0000u); }

__device__ __forceinline__ ushortT f2bf(float f) {
    uintT u = __float_as_uint(f);
    u += 0x7fffu + ((u >> 16) & 1u);   // round-to-nearest-even
    return (ushortT)(u >> 16);
}

// ---------------- edge binning (pass A): bin edges by dst>>7; gcur ends as per-bucket counts ----------------
__global__ __launch_bounds__(256) void binA_k(const int* __restrict__ src, const int* __restrict__ dst,
                                              int* __restrict__ gcur, int2* __restrict__ buf, int E, int NB) {
    __shared__ int hist[512];
    __shared__ int bbase[512];
    __shared__ int lcur[512];
    int t = threadIdx.x;
    for (int i = t; i < NB; i += 256) { hist[i] = 0; lcur[i] = 0; }
    __syncthreads();
    int e0 = blockIdx.x * 4096;
    int2 ed[16];
    #pragma unroll
    for (int j = 0; j < 16; ++j) {
        int idx = e0 + j * 256 + t;
        if (idx < E) {
            ed[j].x = src[idx];
            ed[j].y = dst[idx];
            atomicAdd(&hist[ed[j].y >> 7], 1);
        } else {
            ed[j].y = -1;
        }
    }
    __syncthreads();
    for (int i = t; i < NB; i += 256) {
        int c = hist[i];
        bbase[i] = c > 0 ? atomicAdd(&gcur[i], c) : 0;
    }
    __syncthreads();
    #pragma unroll
    for (int j = 0; j < 16; ++j) {
        if (ed[j].y >= 0) {
            int b = ed[j].y >> 7;
            int pos = bbase[b] + atomicAdd(&lcur[b], 1);
            buf[(size_t)b * BCAP + pos] = ed[j];
        }
    }
}

// ---------------- pass B: compute own bucket base (sum of bcnt[0..b)), per-node count+scan -> off, scatter csr ----------------
__global__ __launch_bounds__(256) void binB_k(const int2* __restrict__ buf, const int* __restrict__ bcnt,
                                              int* __restrict__ off, int* __restrict__ csr, int Nn, int E) {
    __shared__ int cnt[128];
    __shared__ int pre[128];
    __shared__ int cur[128];
    __shared__ int sbase;
    int t = threadIdx.x, b = blockIdx.x;
    if (t == 0) sbase = 0;
    if (t < 128) cnt[t] = 0;
    __syncthreads();
    // partial base sums (all threads) in parallel with histogram
    int bacc = 0;
    for (int i = t; i < b; i += 256) bacc += bcnt[i];
    #pragma unroll
    for (int m = 1; m < 64; m <<= 1) bacc += __shfl_xor(bacc, m, 64);
    if ((t & 63) == 0 && bacc != 0) atomicAdd(&sbase, bacc);
    int nb = bcnt[b];
    int nodebase = b << 7;
    for (int i = t; i < nb; i += 256)
        atomicAdd(&cnt[buf[(size_t)b * BCAP + i].y - nodebase], 1);
    __syncthreads();
    if (t < 128) pre[t] = cnt[t];
    __syncthreads();
    #pragma unroll
    for (int ofs = 1; ofs < 128; ofs <<= 1) {
        int v = 0;
        if (t < 128 && t >= ofs) v = pre[t - ofs];
        __syncthreads();
        if (t < 128) pre[t] += v;
        __syncthreads();
    }
    if (t < 128) {
        int node = nodebase + t;
        int o = sbase + pre[t] - cnt[t];   // exclusive prefix
        if (node < Nn) off[node] = o;
        cur[t] = o;
    }
    if (b == 0 && t == 0) off[Nn] = E;
    __syncthreads();
    for (int i = t; i < nb; i += 256) {
        int2 e = buf[(size_t)b * BCAP + i];
        int p = atomicAdd(&cur[e.y - nodebase], 1);
        csr[p] = e.x;
    }
}

// ---------------- weight conversion into MFMA B-fragment layout (+ zero gcur) ----------------
__global__ __launch_bounds__(256) void wconv4_k(const float* __restrict__ rw, const float* __restrict__ W1,
                                                const float* __restrict__ W2, const float* __restrict__ W3,
                                                ushortT* __restrict__ rwf, ushortT* __restrict__ W1f,
                                                ushortT* __restrict__ W2f, ushortT* __restrict__ W3f,
                                                int* __restrict__ gcur, int NB) {
    int id = blockIdx.x * 256 + threadIdx.x;
    if (id < NB) gcur[id] = 0;
    const float* Wsrc; ushortT* Wdst; int kdiv; int lid;
    if (id < 8192)        { Wsrc = rw; Wdst = rwf; kdiv = 2; lid = id; }
    else if (id < 16384)  { Wsrc = W1; Wdst = W1f; kdiv = 2; lid = id - 8192; }
    else if (id < 32768)  { Wsrc = W2; Wdst = W2f; kdiv = 4; lid = id - 16384; }
    else if (id < 49152)  { Wsrc = W3; Wdst = W3f; kdiv = 4; lid = id - 32768; }
    else return;
    int i = lid & 7;
    int lane = (lid >> 3) & 63;
    int rest = lid >> 9;            // j*kdiv + ks
    int ks = rest % kdiv;
    int j = rest / kdiv;
    int k = ks * 32 + (lane >> 4) * 8 + i;
    int n = j * 16 + (lane & 15);
    Wdst[lid] = f2bf(Wsrc[k * HID + n]);
}

// ---------------- MFMA GEMM (x layer, K=64): inline fp32->bf16 A, bf16 residual + xl + attn dots (x log2e) ----------------
__global__ __launch_bounds__(256) void gemm_mfma_x(
        const float* __restrict__ X, const ushortT* __restrict__ rwf, const ushortT* __restrict__ W1f,
        const float* __restrict__ rb, const float* __restrict__ a_srcp, const float* __restrict__ a_dstp,
        ushortT* __restrict__ Resh, ushortT* __restrict__ Ch,
        float* __restrict__ als, float* __restrict__ ald, int M) {
    int t = threadIdx.x;
    int wave = t >> 6, lane = t & 63;
    int row0 = blockIdx.x * 64 + wave * 16;
    int cl = lane & 15, grp = lane >> 4;
    int rA = row0 + cl;
    f32x4 accR[8] = {};
    f32x4 acc1[8] = {};
    #pragma unroll
    for (int ks = 0; ks < 2; ++ks) {
        bf16x8 afr = {};
        if (rA < M) {
            const float* xr = &X[(size_t)rA * 64 + ks * 32 + grp * 8];
            float4 a0 = *(const float4*)xr;
            float4 a1 = *(const float4*)(xr + 4);
            afr[0] = (short)f2bf(a0.x); afr[1] = (short)f2bf(a0.y);
            afr[2] = (short)f2bf(a0.z); afr[3] = (short)f2bf(a0.w);
            afr[4] = (short)f2bf(a1.x); afr[5] = (short)f2bf(a1.y);
            afr[6] = (short)f2bf(a1.z); afr[7] = (short)f2bf(a1.w);
        }
        #pragma unroll
        for (int j = 0; j < 8; ++j) {
            bf16x8 br = *(const bf16x8*)&rwf[(((size_t)j * 2 + ks) * 64 + lane) * 8];
            accR[j] = __builtin_amdgcn_mfma_f32_16x16x32_bf16(afr, br, accR[j], 0, 0, 0);
            bf16x8 b1 = *(const bf16x8*)&W1f[(((size_t)j * 2 + ks) * 64 + lane) * 8];
            acc1[j] = __builtin_amdgcn_mfma_f32_16x16x32_bf16(afr, b1, acc1[j], 0, 0, 0);
        }
    }
    float asv[8], adv[8], rbv[8];
    #pragma unroll
    for (int j = 0; j < 8; ++j) {
        asv[j] = a_srcp[j * 16 + cl] * LOG2E;
        adv[j] = a_dstp[j * 16 + cl] * LOG2E;
        rbv[j] = rb[j * 16 + cl];
    }
    #pragma unroll
    for (int reg = 0; reg < 4; ++reg) {
        int r = row0 + grp * 4 + reg;
        bool ok = r < M;
        if (ok) {
            #pragma unroll
            for (int j = 0; j < 8; ++j) {
                Resh[(size_t)r * HID + j * 16 + cl] = f2bf(accR[j][reg] + rbv[j]);
                Ch[(size_t)r * HID + j * 16 + cl] = f2bf(acc1[j][reg]);
            }
        }
        float ps[4], pd[4];
        #pragma unroll
        for (int h = 0; h < 4; ++h) {
            ps[h] = acc1[2 * h][reg] * asv[2 * h] + acc1[2 * h + 1][reg] * asv[2 * h + 1];
            pd[h] = acc1[2 * h][reg] * adv[2 * h] + acc1[2 * h + 1][reg] * adv[2 * h + 1];
        }
        #pragma unroll
        for (int m = 1; m < 16; m <<= 1) {
            #pragma unroll
            for (int h = 0; h < 4; ++h) {
                ps[h] += __shfl_xor(ps[h], m, 64);
                pd[h] += __shfl_xor(pd[h], m, 64);
            }
        }
        if (cl == 0 && ok) {
            *(float4*)&als[(size_t)r * 4] = make_float4(ps[0], ps[1], ps[2], ps[3]);
            *(float4*)&ald[(size_t)r * 4] = make_float4(pd[0], pd[1], pd[2], pd[3]);
        }
    }
}

// ---------------- MFMA GEMM (hidden layers, K=128): Ch + attn dots (x log2e) ----------------
__global__ __launch_bounds__(256) void gemm_mfma_h(
        const ushortT* __restrict__ Ah, const ushortT* __restrict__ Wf,
        const float* __restrict__ a_srcp, const float* __restrict__ a_dstp,
        ushortT* __restrict__ Ch, float* __restrict__ als, float* __restrict__ ald, int M) {
    int t = threadIdx.x;
    int wave = t >> 6, lane = t & 63;
    int row0 = blockIdx.x * 64 + wave * 16;
    int cl = lane & 15, grp = lane >> 4;
    int rA = row0 + cl;
    f32x4 acc[8] = {};
    #pragma unroll
    for (int ks = 0; ks < 4; ++ks) {
        bf16x8 afr = {};
        if (rA < M) afr = *(const bf16x8*)&Ah[(size_t)rA * HID + ks * 32 + grp * 8];
        #pragma unroll
        for (int j = 0; j < 8; ++j) {
            bf16x8 br = *(const bf16x8*)&Wf[(((size_t)j * 4 + ks) * 64 + lane) * 8];
            acc[j] = __builtin_amdgcn_mfma_f32_16x16x32_bf16(afr, br, acc[j], 0, 0, 0);
        }
    }
    float asv[8], adv[8];
    #pragma unroll
    for (int j = 0; j < 8; ++j) {
        asv[j] = a_srcp[j * 16 + cl] * LOG2E;
        adv[j] = a_dstp[j * 16 + cl] * LOG2E;
    }
    #pragma unroll
    for (int reg = 0; reg < 4; ++reg) {
        int r = row0 + grp * 4 + reg;
        bool ok = r < M;
        if (ok) {
            #pragma unroll
            for (int j = 0; j < 8; ++j)
                Ch[(size_t)r * HID + j * 16 + cl] = f2bf(acc[j][reg]);
        }
        float ps[4], pd[4];
        #pragma unroll
        for (int h = 0; h < 4; ++h) {
            ps[h] = acc[2 * h][reg] * asv[2 * h] + acc[2 * h + 1][reg] * asv[2 * h + 1];
            pd[h] = acc[2 * h][reg] * adv[2 * h] + acc[2 * h + 1][reg] * adv[2 * h + 1];
        }
        #pragma unroll
        for (int m = 1; m < 16; m <<= 1) {
            #pragma unroll
            for (int h = 0; h < 4; ++h) {
                ps[h] += __shfl_xor(ps[h], m, 64);
                pd[h] += __shfl_xor(pd[h], m, 64);
            }
        }
        if (cl == 0 && ok) {
            *(float4*)&als[(size_t)r * 4] = make_float4(ps[0], ps[1], ps[2], ps[3]);
            *(float4*)&ald[(size_t)r * 4] = make_float4(pd[0], pd[1], pd[2], pd[3]);
        }
    }
}

// ---------------- fully fused GAT: single-pass online softmax (exp2, shift = self logit) + LN + ReLU + residual ----------------
// 2-edge unrolled gather; residual held in bf16 (in-place).
// If Wo != nullptr (final layer): fuse output projection into packed xpack=(p0,p1,also*log2e,aldo*log2e).
__global__ __launch_bounds__(256) void gat_fused(
        const ushortT* __restrict__ xlh, const float* __restrict__ als,
        const float* __restrict__ ald, const int* __restrict__ off,
        const int* __restrict__ csr, const float* __restrict__ bias,
        const float* __restrict__ g, const float* __restrict__ be,
        ushortT* __restrict__ resio,
        const float* __restrict__ Wo, const float* __restrict__ aso, const float* __restrict__ ado,
        float4* __restrict__ xpack, int Nn) {
    int gid = blockIdx.x * 256 + threadIdx.x;
    int wid = gid >> 6, lane = threadIdx.x & 63;
    if (wid >= Nn) return;
    int q = lane >> 4;
    int cl = lane & 15;
    int h = cl >> 2;
    float aldh = ald[wid * 4 + h];
    float eh = lrelu(als[wid * 4 + h] + aldh);   // self logit (log2-scaled) = softmax shift
    int b = off[wid], e = off[wid + 1];
    float acc[8] = {};
    float dsum = 0.f;
    int c = b + q;
    // main: 2 edges per slot iteration, loads batched before use
    for (; c + 4 < e; c += 8) {
        int s0 = csr[c];
        int s1 = csr[c + 4];
        float al0 = als[(size_t)s0 * 4 + h];
        float al1 = als[(size_t)s1 * 4 + h];
        uint4 hv0 = *(const uint4*)&xlh[(size_t)s0 * HID + cl * 8];
        uint4 hv1 = *(const uint4*)&xlh[(size_t)s1 * HID + cl * 8];
        float w0 = exp2f(lrelu(al0 + aldh) - eh);
        float w1 = exp2f(lrelu(al1 + aldh) - eh);
        dsum += w0 + w1;
        acc[0] = fmaf(w0, bflo(hv0.x), acc[0]);
        acc[1] = fmaf(w0, bfhi(hv0.x), acc[1]);
        acc[2] = fmaf(w0, bflo(hv0.y), acc[2]);
        acc[3] = fmaf(w0, bfhi(hv0.y), acc[3]);
        acc[4] = fmaf(w0, bflo(hv0.z), acc[4]);
        acc[5] = fmaf(w0, bfhi(hv0.z), acc[5]);
        acc[6] = fmaf(w0, bflo(hv0.w), acc[6]);
        acc[7] = fmaf(w0, bfhi(hv0.w), acc[7]);
        acc[0] = fmaf(w1, bflo(hv1.x), acc[0]);
        acc[1] = fmaf(w1, bfhi(hv1.x), acc[1]);
        acc[2] = fmaf(w1, bflo(hv1.y), acc[2]);
        acc[3] = fmaf(w1, bfhi(hv1.y), acc[3]);
        acc[4] = fmaf(w1, bflo(hv1.z), acc[4]);
        acc[5] = fmaf(w1, bfhi(hv1.z), acc[5]);
        acc[6] = fmaf(w1, bflo(hv1.w), acc[6]);
        acc[7] = fmaf(w1, bfhi(hv1.w), acc[7]);
    }
    if (c < e) {
        int s = csr[c];
        float al = als[(size_t)s * 4 + h];
        uint4 hv = *(const uint4*)&xlh[(size_t)s * HID + cl * 8];
        float w = exp2f(lrelu(al + aldh) - eh);
        dsum += w;
        acc[0] = fmaf(w, bflo(hv.x), acc[0]);
        acc[1] = fmaf(w, bfhi(hv.x), acc[1]);
        acc[2] = fmaf(w, bflo(hv.y), acc[2]);
        acc[3] = fmaf(w, bfhi(hv.y), acc[3]);
        acc[4] = fmaf(w, bflo(hv.z), acc[4]);
        acc[5] = fmaf(w, bfhi(hv.z), acc[5]);
        acc[6] = fmaf(w, bflo(hv.w), acc[6]);
        acc[7] = fmaf(w, bfhi(hv.w), acc[7]);
    }
    #pragma unroll
    for (int k = 0; k < 8; ++k) {
        acc[k] += __shfl_xor(acc[k], 16, 64);
        acc[k] += __shfl_xor(acc[k], 32, 64);
    }
    dsum += __shfl_xor(dsum, 16, 64);
    dsum += __shfl_xor(dsum, 32, 64);
    float inv = 1.f / (dsum + 1.f + 1e-16f);     // self weight = exp2(0) = 1
    uint4 sv = *(const uint4*)&xlh[(size_t)wid * HID + cl * 8];
    float sx[8];
    sx[0] = bflo(sv.x); sx[1] = bfhi(sv.x);
    sx[2] = bflo(sv.y); sx[3] = bfhi(sv.y);
    sx[4] = bflo(sv.z); sx[5] = bfhi(sv.z);
    sx[6] = bflo(sv.w); sx[7] = bfhi(sv.w);
    float4 bi0 = *(const float4*)&bias[cl * 8];
    float4 bi1 = *(const float4*)&bias[cl * 8 + 4];
    float o[8];
    #pragma unroll
    for (int k = 0; k < 8; ++k) {
        float bb = k < 4 ? (&bi0.x)[k] : (&bi1.x)[k - 4];
        o[k] = fmaf(acc[k] + sx[k], inv, bb);
    }
    float s1 = o[0] + o[1] + o[2] + o[3] + o[4] + o[5] + o[6] + o[7];
    #pragma unroll
    for (int m = 1; m < 16; m <<= 1) s1 += __shfl_xor(s1, m, 64);
    float mu = s1 * (1.0f / HID);
    float qv = 0.f;
    #pragma unroll
    for (int k = 0; k < 8; ++k) { float d = o[k] - mu; qv += d * d; }
    #pragma unroll
    for (int m = 1; m < 16; m <<= 1) qv += __shfl_xor(qv, m, 64);
    float rs = rsqrtf(qv * (1.0f / HID) + LN_EPS);
    if (q == 0) {
        float4 g0 = *(const float4*)&g[cl * 8];
        float4 g1 = *(const float4*)&g[cl * 8 + 4];
        float4 be0 = *(const float4*)&be[cl * 8];
        float4 be1 = *(const float4*)&be[cl * 8 + 4];
        uint4 rv = *(const uint4*)&resio[(size_t)wid * HID + cl * 8];
        float rr[8];
        rr[0] = bflo(rv.x); rr[1] = bfhi(rv.x);
        rr[2] = bflo(rv.y); rr[3] = bfhi(rv.y);
        rr[4] = bflo(rv.z); rr[5] = bfhi(rv.z);
        rr[6] = bflo(rv.w); rr[7] = bfhi(rv.w);
        float w[8];
        #pragma unroll
        for (int k = 0; k < 8; ++k) {
            float gg = k < 4 ? (&g0.x)[k] : (&g1.x)[k - 4];
            float ee = k < 4 ? (&be0.x)[k] : (&be1.x)[k - 4];
            w[k] = fmaxf((o[k] - mu) * rs * gg + ee, 0.f) + rr[k];
        }
        if (Wo) {
            float p0 = 0.f, p1 = 0.f;
            #pragma unroll
            for (int k = 0; k < 8; ++k) {
                int ch = cl * 8 + k;
                p0 = fmaf(w[k], Wo[ch * 2 + 0], p0);
                p1 = fmaf(w[k], Wo[ch * 2 + 1], p1);
            }
            #pragma unroll
            for (int m = 1; m < 16; m <<= 1) {
                p0 += __shfl_xor(p0, m, 64);
                p1 += __shfl_xor(p1, m, 64);
            }
            if (cl == 0) {
                float a_s = (p0 * aso[0] + p1 * aso[1]) * LOG2E;
                float a_d = (p0 * ado[0] + p1 * ado[1]) * LOG2E;
                xpack[wid] = make_float4(p0, p1, a_s, a_d);
            }
        } else {
            ushort4 hv0, hv1;
            hv0.x = f2bf(w[0]); hv0.y = f2bf(w[1]); hv0.z = f2bf(w[2]); hv0.w = f2bf(w[3]);
            hv1.x = f2bf(w[4]); hv1.y = f2bf(w[5]); hv1.z = f2bf(w[6]); hv1.w = f2bf(w[7]);
            *(ushort4*)&resio[(size_t)wid * HID + cl * 8] = hv0;
            *(ushort4*)&resio[(size_t)wid * HID + cl * 8 + 4] = hv1;
        }
    }
}

// ---------------- output aggregation (packed float4 per node: p0,p1,also2,aldo2) ----------------
__global__ __launch_bounds__(256) void out_agg(const float4* __restrict__ xpack, const int* __restrict__ off,
                                               const int* __restrict__ csr, const float* __restrict__ bo,
                                               float* __restrict__ out, int Nn) {
    int gid = blockIdx.x * 256 + threadIdx.x;
    int wid = gid >> 6, lane = threadIdx.x & 63;
    if (wid >= Nn) return;
    float4 self = xpack[wid];
    float aldn = self.w;
    float eself = lrelu(self.z + aldn);
    int b = off[wid], e = off[wid + 1];
    float dl = 0.f, a0 = 0.f, a1 = 0.f;
    for (int j = b + lane; j < e; j += 64) {
        float4 v = xpack[csr[j]];
        float w = exp2f(lrelu(v.z + aldn) - eself);
        dl += w;
        a0 += w * v.x;
        a1 += w * v.y;
    }
    #pragma unroll
    for (int m = 1; m < 64; m <<= 1) {
        dl += __shfl_xor(dl, m, 64);
        a0 += __shfl_xor(a0, m, 64);
        a1 += __shfl_xor(a1, m, 64);
    }
    if (lane == 0) {
        dl += 1.f;   // self weight exp2(0)
        a0 += self.x;
        a1 += self.y;
        float inv = 1.f / (dl + 1e-16f);
        out[wid * 2 + 0] = a0 * inv + bo[0];
        out[wid * 2 + 1] = a1 * inv + bo[1];
    }
}

extern "C" void kernel_launch(void* const* d_in, const int* in_sizes, int n_in,
                              void* d_out, int out_size, void* d_ws, size_t ws_size,
                              hipStream_t stream) {
    const float* x   = (const float*)d_in[0];
    const int*   ei  = (const int*)d_in[1];
    const float* W1  = (const float*)d_in[2];
    const float* as1 = (const float*)d_in[3];
    const float* ad1 = (const float*)d_in[4];
    const float* b1  = (const float*)d_in[5];
    const float* g1  = (const float*)d_in[6];
    const float* be1 = (const float*)d_in[7];
    const float* rw  = (const float*)d_in[8];
    const float* rb  = (const float*)d_in[9];
    const float* W2  = (const float*)d_in[10];
    const float* as2 = (const float*)d_in[11];
    const float* ad2 = (const float*)d_in[12];
    const float* b2  = (const float*)d_in[13];
    const float* g2  = (const float*)d_in[14];
    const float* be2 = (const float*)d_in[15];
    const float* W3  = (const float*)d_in[16];
    const float* as3 = (const float*)d_in[17];
    const float* ad3 = (const float*)d_in[18];
    const float* b3  = (const float*)d_in[19];
    const float* g3  = (const float*)d_in[20];
    const float* be3 = (const float*)d_in[21];
    const float* Wo  = (const float*)d_in[22];
    const float* aso = (const float*)d_in[23];
    const float* ado = (const float*)d_in[24];
    const float* bo  = (const float*)d_in[25];

    int N = in_sizes[0] / 64;   // 50000
    int E = in_sizes[1] / 2;    // 800000
    const int* srcE = ei;
    const int* dstE = ei + E;
    int NB = (N + 127) >> 7;    // 391 buckets

    char* w = (char*)d_ws;
    auto alloc = [&](size_t b) { char* p = w; w += (b + 255) & ~(size_t)255; return p; };
    int* off    = (int*)alloc((size_t)(N + 1) * 4);
    int* gcur   = (int*)alloc((size_t)NB * 4);
    int* csr    = (int*)alloc((size_t)E * 4);
    int2* bbuf  = (int2*)alloc((size_t)NB * BCAP * 8);
    ushortT* hresh = (ushortT*)alloc((size_t)N * HID * 2);
    ushortT* xlh = (ushortT*)alloc((size_t)N * HID * 2);
    ushortT* rwf = (ushortT*)alloc(8192 * 2);
    ushortT* W1f = (ushortT*)alloc(8192 * 2);
    ushortT* W2f = (ushortT*)alloc(16384 * 2);
    ushortT* W3f = (ushortT*)alloc(16384 * 2);
    float* als  = (float*)alloc((size_t)N * HEADS * 4);
    float* ald  = (float*)alloc((size_t)N * HEADS * 4);
    float4* xpack = (float4*)alloc((size_t)N * 16);

    // weight conversion (+ zeroes gcur for binA)
    wconv4_k<<<192, 256, 0, stream>>>(rw, W1, W2, W3, rwf, W1f, W2f, W3f, gcur, NB);
    binA_k<<<(E + 4095) / 4096, 256, 0, stream>>>(srcE, dstE, gcur, bbuf, E, NB);
    binB_k<<<NB, 256, 0, stream>>>(bbuf, gcur, off, csr, N, E);

    int gG = (N + 63) / 64;   // MFMA gemm grid
    int gW = (N + 3) / 4;

    // ---- layer 1 (fused residual + W1 projection, MFMA, inline x->bf16) ----
    gemm_mfma_x<<<gG, 256, 0, stream>>>(x, rwf, W1f, rb, as1, ad1, hresh, xlh, als, ald, N);
    gat_fused<<<gW, 256, 0, stream>>>(xlh, als, ald, off, csr, b1, g1, be1, hresh,
                                      nullptr, nullptr, nullptr, nullptr, N);

    // ---- layer 2 ----
    gemm_mfma_h<<<gG, 256, 0, stream>>>(hresh, W2f, as2, ad2, xlh, als, ald, N);
    gat_fused<<<gW, 256, 0, stream>>>(xlh, als, ald, off, csr, b2, g2, be2, hresh,
                                      nullptr, nullptr, nullptr, nullptr, N);

    // ---- layer 3 (fused output projection) ----
    gemm_mfma_h<<<gG, 256, 0, stream>>>(hresh, W3f, as3, ad3, xlh, als, ald, N);
    gat_fused<<<gW, 256, 0, stream>>>(xlh, als, ald, off, csr, b3, g3, be3, hresh,
                                      Wo, aso, ado, xpack, N);

    // ---- output aggregation ----
    out_agg<<<gW, 256, 0, stream>>>(xpack, off, csr, bo, (float*)d_out, N);
}

// Round 13
// 211.844 us; speedup vs baseline: 3.7919x; 1.0612x over previous
//
#include <hip/hip_runtime.h>
#include <math.h>

#define HID 128
#define HEADS 4
#define NEG_SLOPE 0.2f
#define LN_EPS 1e-5f
#define LOG2E 1.44269504088896f
#define BCAP 4096   // per-bucket capacity (avg 2046 for N=50K, E=800K)

typedef unsigned short ushortT;
typedef unsigned int uintT;
typedef __attribute__((ext_vector_type(8))) short bf16x8;
typedef __attribute__((ext_vector_type(4))) float f32x4;

__device__ __forceinline__ float lrelu(float v) { return v > 0.f ? v : NEG_SLOPE * v; }
__device__ __forceinline__ float bflo(uintT v) { return __uint_as_float(v << 16); }
__device__ __forceinline__ float bfhi(uintT v) { return __uint_as_float(v & 0xffff0000u); }

__device__ __forceinline__ ushortT f2bf(float f) {
    uintT u = __float_as_uint(f);
    u += 0x7fffu + ((u >> 16) & 1u);   // round-to-nearest-even
    return (ushortT)(u >> 16);
}

// ---------------- edge binning (pass A): bin edges by dst>>7; gcur ends as per-bucket counts ----------------
__global__ __launch_bounds__(256) void binA_k(const int* __restrict__ src, const int* __restrict__ dst,
                                              int* __restrict__ gcur, int2* __restrict__ buf, int E, int NB) {
    __shared__ int hist[512];
    __shared__ int bbase[512];
    __shared__ int lcur[512];
    int t = threadIdx.x;
    for (int i = t; i < NB; i += 256) { hist[i] = 0; lcur[i] = 0; }
    __syncthreads();
    int e0 = blockIdx.x * 4096;
    int2 ed[16];
    #pragma unroll
    for (int j = 0; j < 16; ++j) {
        int idx = e0 + j * 256 + t;
        if (idx < E) {
            ed[j].x = src[idx];
            ed[j].y = dst[idx];
            atomicAdd(&hist[ed[j].y >> 7], 1);
        } else {
            ed[j].y = -1;
        }
    }
    __syncthreads();
    for (int i = t; i < NB; i += 256) {
        int c = hist[i];
        bbase[i] = c > 0 ? atomicAdd(&gcur[i], c) : 0;
    }
    __syncthreads();
    #pragma unroll
    for (int j = 0; j < 16; ++j) {
        if (ed[j].y >= 0) {
            int b = ed[j].y >> 7;
            int pos = bbase[b] + atomicAdd(&lcur[b], 1);
            buf[(size_t)b * BCAP + pos] = ed[j];
        }
    }
}

// ---------------- pass B: compute own bucket base (sum of bcnt[0..b)), per-node count+scan -> off, scatter csr ----------------
__global__ __launch_bounds__(256) void binB_k(const int2* __restrict__ buf, const int* __restrict__ bcnt,
                                              int* __restrict__ off, int* __restrict__ csr, int Nn, int E) {
    __shared__ int cnt[128];
    __shared__ int pre[128];
    __shared__ int cur[128];
    __shared__ int sbase;
    int t = threadIdx.x, b = blockIdx.x;
    if (t == 0) sbase = 0;
    if (t < 128) cnt[t] = 0;
    __syncthreads();
    int bacc = 0;
    for (int i = t; i < b; i += 256) bacc += bcnt[i];
    #pragma unroll
    for (int m = 1; m < 64; m <<= 1) bacc += __shfl_xor(bacc, m, 64);
    if ((t & 63) == 0 && bacc != 0) atomicAdd(&sbase, bacc);
    int nb = bcnt[b];
    int nodebase = b << 7;
    for (int i = t; i < nb; i += 256)
        atomicAdd(&cnt[buf[(size_t)b * BCAP + i].y - nodebase], 1);
    __syncthreads();
    if (t < 128) pre[t] = cnt[t];
    __syncthreads();
    #pragma unroll
    for (int ofs = 1; ofs < 128; ofs <<= 1) {
        int v = 0;
        if (t < 128 && t >= ofs) v = pre[t - ofs];
        __syncthreads();
        if (t < 128) pre[t] += v;
        __syncthreads();
    }
    if (t < 128) {
        int node = nodebase + t;
        int o = sbase + pre[t] - cnt[t];
        if (node < Nn) off[node] = o;
        cur[t] = o;
    }
    if (b == 0 && t == 0) off[Nn] = E;
    __syncthreads();
    for (int i = t; i < nb; i += 256) {
        int2 e = buf[(size_t)b * BCAP + i];
        int p = atomicAdd(&cur[e.y - nodebase], 1);
        csr[p] = e.x;
    }
}

// ---------------- weight conversion into MFMA B-fragment layout (+ zero gcur) ----------------
__global__ __launch_bounds__(256) void wconv4_k(const float* __restrict__ rw, const float* __restrict__ W1,
                                                const float* __restrict__ W2, const float* __restrict__ W3,
                                                ushortT* __restrict__ rwf, ushortT* __restrict__ W1f,
                                                ushortT* __restrict__ W2f, ushortT* __restrict__ W3f,
                                                int* __restrict__ gcur, int NB) {
    int id = blockIdx.x * 256 + threadIdx.x;
    if (id < NB) gcur[id] = 0;
    const float* Wsrc; ushortT* Wdst; int kdiv; int lid;
    if (id < 8192)        { Wsrc = rw; Wdst = rwf; kdiv = 2; lid = id; }
    else if (id < 16384)  { Wsrc = W1; Wdst = W1f; kdiv = 2; lid = id - 8192; }
    else if (id < 32768)  { Wsrc = W2; Wdst = W2f; kdiv = 4; lid = id - 16384; }
    else if (id < 49152)  { Wsrc = W3; Wdst = W3f; kdiv = 4; lid = id - 32768; }
    else return;
    int i = lid & 7;
    int lane = (lid >> 3) & 63;
    int rest = lid >> 9;            // j*kdiv + ks
    int ks = rest % kdiv;
    int j = rest / kdiv;
    int k = ks * 32 + (lane >> 4) * 8 + i;
    int n = j * 16 + (lane & 15);
    Wdst[lid] = f2bf(Wsrc[k * HID + n]);
}

// ---------------- MFMA GEMM (x layer, K=64): inline fp32->bf16 A, bf16 residual + xl + attn dots (x log2e) ----------------
__global__ __launch_bounds__(256) void gemm_mfma_x(
        const float* __restrict__ X, const ushortT* __restrict__ rwf, const ushortT* __restrict__ W1f,
        const float* __restrict__ rb, const float* __restrict__ a_srcp, const float* __restrict__ a_dstp,
        ushortT* __restrict__ Resh, ushortT* __restrict__ Ch,
        float* __restrict__ als, float* __restrict__ ald, int M) {
    int t = threadIdx.x;
    int wave = t >> 6, lane = t & 63;
    int row0 = blockIdx.x * 64 + wave * 16;
    int cl = lane & 15, grp = lane >> 4;
    int rA = row0 + cl;
    f32x4 accR[8] = {};
    f32x4 acc1[8] = {};
    #pragma unroll
    for (int ks = 0; ks < 2; ++ks) {
        bf16x8 afr = {};
        if (rA < M) {
            const float* xr = &X[(size_t)rA * 64 + ks * 32 + grp * 8];
            float4 a0 = *(const float4*)xr;
            float4 a1 = *(const float4*)(xr + 4);
            afr[0] = (short)f2bf(a0.x); afr[1] = (short)f2bf(a0.y);
            afr[2] = (short)f2bf(a0.z); afr[3] = (short)f2bf(a0.w);
            afr[4] = (short)f2bf(a1.x); afr[5] = (short)f2bf(a1.y);
            afr[6] = (short)f2bf(a1.z); afr[7] = (short)f2bf(a1.w);
        }
        #pragma unroll
        for (int j = 0; j < 8; ++j) {
            bf16x8 br = *(const bf16x8*)&rwf[(((size_t)j * 2 + ks) * 64 + lane) * 8];
            accR[j] = __builtin_amdgcn_mfma_f32_16x16x32_bf16(afr, br, accR[j], 0, 0, 0);
            bf16x8 b1 = *(const bf16x8*)&W1f[(((size_t)j * 2 + ks) * 64 + lane) * 8];
            acc1[j] = __builtin_amdgcn_mfma_f32_16x16x32_bf16(afr, b1, acc1[j], 0, 0, 0);
        }
    }
    float asv[8], adv[8], rbv[8];
    #pragma unroll
    for (int j = 0; j < 8; ++j) {
        asv[j] = a_srcp[j * 16 + cl] * LOG2E;
        adv[j] = a_dstp[j * 16 + cl] * LOG2E;
        rbv[j] = rb[j * 16 + cl];
    }
    #pragma unroll
    for (int reg = 0; reg < 4; ++reg) {
        int r = row0 + grp * 4 + reg;
        bool ok = r < M;
        if (ok) {
            #pragma unroll
            for (int j = 0; j < 8; ++j) {
                Resh[(size_t)r * HID + j * 16 + cl] = f2bf(accR[j][reg] + rbv[j]);
                Ch[(size_t)r * HID + j * 16 + cl] = f2bf(acc1[j][reg]);
            }
        }
        float ps[4], pd[4];
        #pragma unroll
        for (int h = 0; h < 4; ++h) {
            ps[h] = acc1[2 * h][reg] * asv[2 * h] + acc1[2 * h + 1][reg] * asv[2 * h + 1];
            pd[h] = acc1[2 * h][reg] * adv[2 * h] + acc1[2 * h + 1][reg] * adv[2 * h + 1];
        }
        #pragma unroll
        for (int m = 1; m < 16; m <<= 1) {
            #pragma unroll
            for (int h = 0; h < 4; ++h) {
                ps[h] += __shfl_xor(ps[h], m, 64);
                pd[h] += __shfl_xor(pd[h], m, 64);
            }
        }
        if (cl == 0 && ok) {
            *(float4*)&als[(size_t)r * 4] = make_float4(ps[0], ps[1], ps[2], ps[3]);
            *(float4*)&ald[(size_t)r * 4] = make_float4(pd[0], pd[1], pd[2], pd[3]);
        }
    }
}

// ---------------- MFMA GEMM (hidden layers, K=128): Ch + attn dots (x log2e) ----------------
__global__ __launch_bounds__(256) void gemm_mfma_h(
        const ushortT* __restrict__ Ah, const ushortT* __restrict__ Wf,
        const float* __restrict__ a_srcp, const float* __restrict__ a_dstp,
        ushortT* __restrict__ Ch, float* __restrict__ als, float* __restrict__ ald, int M) {
    int t = threadIdx.x;
    int wave = t >> 6, lane = t & 63;
    int row0 = blockIdx.x * 64 + wave * 16;
    int cl = lane & 15, grp = lane >> 4;
    int rA = row0 + cl;
    f32x4 acc[8] = {};
    #pragma unroll
    for (int ks = 0; ks < 4; ++ks) {
        bf16x8 afr = {};
        if (rA < M) afr = *(const bf16x8*)&Ah[(size_t)rA * HID + ks * 32 + grp * 8];
        #pragma unroll
        for (int j = 0; j < 8; ++j) {
            bf16x8 br = *(const bf16x8*)&Wf[(((size_t)j * 4 + ks) * 64 + lane) * 8];
            acc[j] = __builtin_amdgcn_mfma_f32_16x16x32_bf16(afr, br, acc[j], 0, 0, 0);
        }
    }
    float asv[8], adv[8];
    #pragma unroll
    for (int j = 0; j < 8; ++j) {
        asv[j] = a_srcp[j * 16 + cl] * LOG2E;
        adv[j] = a_dstp[j * 16 + cl] * LOG2E;
    }
    #pragma unroll
    for (int reg = 0; reg < 4; ++reg) {
        int r = row0 + grp * 4 + reg;
        bool ok = r < M;
        if (ok) {
            #pragma unroll
            for (int j = 0; j < 8; ++j)
                Ch[(size_t)r * HID + j * 16 + cl] = f2bf(acc[j][reg]);
        }
        float ps[4], pd[4];
        #pragma unroll
        for (int h = 0; h < 4; ++h) {
            ps[h] = acc[2 * h][reg] * asv[2 * h] + acc[2 * h + 1][reg] * asv[2 * h + 1];
            pd[h] = acc[2 * h][reg] * adv[2 * h] + acc[2 * h + 1][reg] * adv[2 * h + 1];
        }
        #pragma unroll
        for (int m = 1; m < 16; m <<= 1) {
            #pragma unroll
            for (int h = 0; h < 4; ++h) {
                ps[h] += __shfl_xor(ps[h], m, 64);
                pd[h] += __shfl_xor(pd[h], m, 64);
            }
        }
        if (cl == 0 && ok) {
            *(float4*)&als[(size_t)r * 4] = make_float4(ps[0], ps[1], ps[2], ps[3]);
            *(float4*)&ald[(size_t)r * 4] = make_float4(pd[0], pd[1], pd[2], pd[3]);
        }
    }
}

// ---------------- fully fused GAT: single-pass online softmax (exp2) + LN + ReLU + bf16 residual ----------------
// 2-edge unrolled gather with csr/als software pipelining (indices+attrs prefetched 1 iter ahead,
// so only the xlh row load sits on the per-iteration critical path).
__global__ __launch_bounds__(256) void gat_fused(
        const ushortT* __restrict__ xlh, const float* __restrict__ als,
        const float* __restrict__ ald, const int* __restrict__ off,
        const int* __restrict__ csr, const float* __restrict__ bias,
        const float* __restrict__ g, const float* __restrict__ be,
        ushortT* __restrict__ resio,
        const float* __restrict__ Wo, const float* __restrict__ aso, const float* __restrict__ ado,
        float4* __restrict__ xpack, int Nn) {
    int gid = blockIdx.x * 256 + threadIdx.x;
    int wid = gid >> 6, lane = threadIdx.x & 63;
    if (wid >= Nn) return;
    int q = lane >> 4;
    int cl = lane & 15;
    int h = cl >> 2;
    float aldh = ald[wid * 4 + h];
    float eh = lrelu(als[wid * 4 + h] + aldh);   // self logit (log2-scaled) = softmax shift
    int b = off[wid], e = off[wid + 1];
    float acc[8] = {};
    float dsum = 0.f;
    int c = b + q;
    // pipeline prologue
    int s0n = 0, s1n = 0;
    if (c < e) s0n = csr[c];
    if (c + 4 < e) s1n = csr[c + 4];
    float al0n = als[(size_t)s0n * 4 + h];
    float al1n = als[(size_t)s1n * 4 + h];
    for (; c + 4 < e; c += 8) {
        int s0 = s0n, s1 = s1n;
        float al0 = al0n, al1 = al1n;
        uint4 hv0 = *(const uint4*)&xlh[(size_t)s0 * HID + cl * 8];
        uint4 hv1 = *(const uint4*)&xlh[(size_t)s1 * HID + cl * 8];
        if (c + 8 < e) s0n = csr[c + 8];
        if (c + 12 < e) s1n = csr[c + 12];
        al0n = als[(size_t)s0n * 4 + h];
        al1n = als[(size_t)s1n * 4 + h];
        float w0 = exp2f(lrelu(al0 + aldh) - eh);
        float w1 = exp2f(lrelu(al1 + aldh) - eh);
        dsum += w0 + w1;
        acc[0] = fmaf(w0, bflo(hv0.x), acc[0]);
        acc[1] = fmaf(w0, bfhi(hv0.x), acc[1]);
        acc[2] = fmaf(w0, bflo(hv0.y), acc[2]);
        acc[3] = fmaf(w0, bfhi(hv0.y), acc[3]);
        acc[4] = fmaf(w0, bflo(hv0.z), acc[4]);
        acc[5] = fmaf(w0, bfhi(hv0.z), acc[5]);
        acc[6] = fmaf(w0, bflo(hv0.w), acc[6]);
        acc[7] = fmaf(w0, bfhi(hv0.w), acc[7]);
        acc[0] = fmaf(w1, bflo(hv1.x), acc[0]);
        acc[1] = fmaf(w1, bfhi(hv1.x), acc[1]);
        acc[2] = fmaf(w1, bflo(hv1.y), acc[2]);
        acc[3] = fmaf(w1, bfhi(hv1.y), acc[3]);
        acc[4] = fmaf(w1, bflo(hv1.z), acc[4]);
        acc[5] = fmaf(w1, bfhi(hv1.z), acc[5]);
        acc[6] = fmaf(w1, bflo(hv1.w), acc[6]);
        acc[7] = fmaf(w1, bfhi(hv1.w), acc[7]);
    }
    if (c < e) {
        // pipeline invariant: s0n == csr[c], al0n == als[s0n*4+h]
        uint4 hv = *(const uint4*)&xlh[(size_t)s0n * HID + cl * 8];
        float w = exp2f(lrelu(al0n + aldh) - eh);
        dsum += w;
        acc[0] = fmaf(w, bflo(hv.x), acc[0]);
        acc[1] = fmaf(w, bfhi(hv.x), acc[1]);
        acc[2] = fmaf(w, bflo(hv.y), acc[2]);
        acc[3] = fmaf(w, bfhi(hv.y), acc[3]);
        acc[4] = fmaf(w, bflo(hv.z), acc[4]);
        acc[5] = fmaf(w, bfhi(hv.z), acc[5]);
        acc[6] = fmaf(w, bflo(hv.w), acc[6]);
        acc[7] = fmaf(w, bfhi(hv.w), acc[7]);
    }
    #pragma unroll
    for (int k = 0; k < 8; ++k) {
        acc[k] += __shfl_xor(acc[k], 16, 64);
        acc[k] += __shfl_xor(acc[k], 32, 64);
    }
    dsum += __shfl_xor(dsum, 16, 64);
    dsum += __shfl_xor(dsum, 32, 64);
    float inv = 1.f / (dsum + 1.f + 1e-16f);     // self weight = exp2(0) = 1
    uint4 sv = *(const uint4*)&xlh[(size_t)wid * HID + cl * 8];
    float sx[8];
    sx[0] = bflo(sv.x); sx[1] = bfhi(sv.x);
    sx[2] = bflo(sv.y); sx[3] = bfhi(sv.y);
    sx[4] = bflo(sv.z); sx[5] = bfhi(sv.z);
    sx[6] = bflo(sv.w); sx[7] = bfhi(sv.w);
    float4 bi0 = *(const float4*)&bias[cl * 8];
    float4 bi1 = *(const float4*)&bias[cl * 8 + 4];
    float o[8];
    #pragma unroll
    for (int k = 0; k < 8; ++k) {
        float bb = k < 4 ? (&bi0.x)[k] : (&bi1.x)[k - 4];
        o[k] = fmaf(acc[k] + sx[k], inv, bb);
    }
    float s1 = o[0] + o[1] + o[2] + o[3] + o[4] + o[5] + o[6] + o[7];
    #pragma unroll
    for (int m = 1; m < 16; m <<= 1) s1 += __shfl_xor(s1, m, 64);
    float mu = s1 * (1.0f / HID);
    float qv = 0.f;
    #pragma unroll
    for (int k = 0; k < 8; ++k) { float d = o[k] - mu; qv += d * d; }
    #pragma unroll
    for (int m = 1; m < 16; m <<= 1) qv += __shfl_xor(qv, m, 64);
    float rs = rsqrtf(qv * (1.0f / HID) + LN_EPS);
    if (q == 0) {
        float4 g0 = *(const float4*)&g[cl * 8];
        float4 g1 = *(const float4*)&g[cl * 8 + 4];
        float4 be0 = *(const float4*)&be[cl * 8];
        float4 be1 = *(const float4*)&be[cl * 8 + 4];
        uint4 rv = *(const uint4*)&resio[(size_t)wid * HID + cl * 8];
        float rr[8];
        rr[0] = bflo(rv.x); rr[1] = bfhi(rv.x);
        rr[2] = bflo(rv.y); rr[3] = bfhi(rv.y);
        rr[4] = bflo(rv.z); rr[5] = bfhi(rv.z);
        rr[6] = bflo(rv.w); rr[7] = bfhi(rv.w);
        float w[8];
        #pragma unroll
        for (int k = 0; k < 8; ++k) {
            float gg = k < 4 ? (&g0.x)[k] : (&g1.x)[k - 4];
            float ee = k < 4 ? (&be0.x)[k] : (&be1.x)[k - 4];
            w[k] = fmaxf((o[k] - mu) * rs * gg + ee, 0.f) + rr[k];
        }
        if (Wo) {
            float p0 = 0.f, p1 = 0.f;
            #pragma unroll
            for (int k = 0; k < 8; ++k) {
                int ch = cl * 8 + k;
                p0 = fmaf(w[k], Wo[ch * 2 + 0], p0);
                p1 = fmaf(w[k], Wo[ch * 2 + 1], p1);
            }
            #pragma unroll
            for (int m = 1; m < 16; m <<= 1) {
                p0 += __shfl_xor(p0, m, 64);
                p1 += __shfl_xor(p1, m, 64);
            }
            if (cl == 0) {
                float a_s = (p0 * aso[0] + p1 * aso[1]) * LOG2E;
                float a_d = (p0 * ado[0] + p1 * ado[1]) * LOG2E;
                xpack[wid] = make_float4(p0, p1, a_s, a_d);
            }
        } else {
            ushort4 hv0, hv1;
            hv0.x = f2bf(w[0]); hv0.y = f2bf(w[1]); hv0.z = f2bf(w[2]); hv0.w = f2bf(w[3]);
            hv1.x = f2bf(w[4]); hv1.y = f2bf(w[5]); hv1.z = f2bf(w[6]); hv1.w = f2bf(w[7]);
            *(ushort4*)&resio[(size_t)wid * HID + cl * 8] = hv0;
            *(ushort4*)&resio[(size_t)wid * HID + cl * 8 + 4] = hv1;
        }
    }
}

// ---------------- output aggregation: 16 lanes/node, 4 nodes/wave ----------------
__global__ __launch_bounds__(256) void out_agg(const float4* __restrict__ xpack, const int* __restrict__ off,
                                               const int* __restrict__ csr, const float* __restrict__ bo,
                                               float* __restrict__ out, int Nn) {
    int gid = blockIdx.x * 256 + threadIdx.x;
    int wid = gid >> 4;
    int l = threadIdx.x & 15;
    if (wid >= Nn) return;
    float4 self = xpack[wid];
    float aldn = self.w;
    float eself = lrelu(self.z + aldn);
    int b = off[wid], e = off[wid + 1];
    float dl = 0.f, a0 = 0.f, a1 = 0.f;
    for (int j = b + l; j < e; j += 16) {
        float4 v = xpack[csr[j]];
        float w = exp2f(lrelu(v.z + aldn) - eself);
        dl += w;
        a0 += w * v.x;
        a1 += w * v.y;
    }
    #pragma unroll
    for (int m = 1; m < 16; m <<= 1) {
        dl += __shfl_xor(dl, m, 64);
        a0 += __shfl_xor(a0, m, 64);
        a1 += __shfl_xor(a1, m, 64);
    }
    if (l == 0) {
        dl += 1.f;   // self weight exp2(0)
        a0 += self.x;
        a1 += self.y;
        float inv = 1.f / (dl + 1e-16f);
        out[wid * 2 + 0] = a0 * inv + bo[0];
        out[wid * 2 + 1] = a1 * inv + bo[1];
    }
}

extern "C" void kernel_launch(void* const* d_in, const int* in_sizes, int n_in,
                              void* d_out, int out_size, void* d_ws, size_t ws_size,
                              hipStream_t stream) {
    const float* x   = (const float*)d_in[0];
    const int*   ei  = (const int*)d_in[1];
    const float* W1  = (const float*)d_in[2];
    const float* as1 = (const float*)d_in[3];
    const float* ad1 = (const float*)d_in[4];
    const float* b1  = (const float*)d_in[5];
    const float* g1  = (const float*)d_in[6];
    const float* be1 = (const float*)d_in[7];
    const float* rw  = (const float*)d_in[8];
    const float* rb  = (const float*)d_in[9];
    const float* W2  = (const float*)d_in[10];
    const float* as2 = (const float*)d_in[11];
    const float* ad2 = (const float*)d_in[12];
    const float* b2  = (const float*)d_in[13];
    const float* g2  = (const float*)d_in[14];
    const float* be2 = (const float*)d_in[15];
    const float* W3  = (const float*)d_in[16];
    const float* as3 = (const float*)d_in[17];
    const float* ad3 = (const float*)d_in[18];
    const float* b3  = (const float*)d_in[19];
    const float* g3  = (const float*)d_in[20];
    const float* be3 = (const float*)d_in[21];
    const float* Wo  = (const float*)d_in[22];
    const float* aso = (const float*)d_in[23];
    const float* ado = (const float*)d_in[24];
    const float* bo  = (const float*)d_in[25];

    int N = in_sizes[0] / 64;   // 50000
    int E = in_sizes[1] / 2;    // 800000
    const int* srcE = ei;
    const int* dstE = ei + E;
    int NB = (N + 127) >> 7;    // 391 buckets

    char* w = (char*)d_ws;
    auto alloc = [&](size_t b) { char* p = w; w += (b + 255) & ~(size_t)255; return p; };
    int* off    = (int*)alloc((size_t)(N + 1) * 4);
    int* gcur   = (int*)alloc((size_t)NB * 4);
    int* csr    = (int*)alloc((size_t)E * 4);
    int2* bbuf  = (int2*)alloc((size_t)NB * BCAP * 8);
    ushortT* hresh = (ushortT*)alloc((size_t)N * HID * 2);
    ushortT* xlh = (ushortT*)alloc((size_t)N * HID * 2);
    ushortT* rwf = (ushortT*)alloc(8192 * 2);
    ushortT* W1f = (ushortT*)alloc(8192 * 2);
    ushortT* W2f = (ushortT*)alloc(16384 * 2);
    ushortT* W3f = (ushortT*)alloc(16384 * 2);
    float* als  = (float*)alloc((size_t)N * HEADS * 4);
    float* ald  = (float*)alloc((size_t)N * HEADS * 4);
    float4* xpack = (float4*)alloc((size_t)N * 16);

    // weight conversion (+ zeroes gcur for binA)
    wconv4_k<<<192, 256, 0, stream>>>(rw, W1, W2, W3, rwf, W1f, W2f, W3f, gcur, NB);
    binA_k<<<(E + 4095) / 4096, 256, 0, stream>>>(srcE, dstE, gcur, bbuf, E, NB);
    binB_k<<<NB, 256, 0, stream>>>(bbuf, gcur, off, csr, N, E);

    int gG = (N + 63) / 64;   // MFMA gemm grid
    int gW = (N + 3) / 4;     // wave-per-node grid
    int gO = (N * 16 + 255) / 256;   // 16 lanes/node grid

    // ---- layer 1 (fused residual + W1 projection, MFMA, inline x->bf16) ----
    gemm_mfma_x<<<gG, 256, 0, stream>>>(x, rwf, W1f, rb, as1, ad1, hresh, xlh, als, ald, N);
    gat_fused<<<gW, 256, 0, stream>>>(xlh, als, ald, off, csr, b1, g1, be1, hresh,
                                      nullptr, nullptr, nullptr, nullptr, N);

    // ---- layer 2 ----
    gemm_mfma_h<<<gG, 256, 0, stream>>>(hresh, W2f, as2, ad2, xlh, als, ald, N);
    gat_fused<<<gW, 256, 0, stream>>>(xlh, als, ald, off, csr, b2, g2, be2, hresh,
                                      nullptr, nullptr, nullptr, nullptr, N);

    // ---- layer 3 (fused output projection) ----
    gemm_mfma_h<<<gG, 256, 0, stream>>>(hresh, W3f, as3, ad3, xlh, als, ald, N);
    gat_fused<<<gW, 256, 0, stream>>>(xlh, als, ald, off, csr, b3, g3, be3, hresh,
                                      Wo, aso, ado, xpack, N);

    // ---- output aggregation ----
    out_agg<<<gO, 256, 0, stream>>>(xpack, off, csr, bo, (float*)d_out, N);
}